// Round 14
// 1977.118 us; speedup vs baseline: 30.3724x; 1.0651x over previous
//
#include <hip/hip_runtime.h>
#include <hip/hip_bf16.h>

typedef long long i64;
typedef __hip_bfloat16 bf16;
using short8 = __attribute__((ext_vector_type(8))) short;
using f32x4  = __attribute__((ext_vector_type(4))) float;

#define SEQ    16384
#define DM     512
#define NHEAD  8
#define DH     64
#define LMK    256
#define LSUB   64      // SEQ / LMK
#define Q3     1536
#define FFD    2048
#define BATCH  2
#define ROWS   (BATCH * SEQ)

__device__ __forceinline__ float cvt(float v) { return v; }
__device__ __forceinline__ float cvt(bf16 v) { return __bfloat162float(v); }
__device__ __forceinline__ void stc(float* p, float v) { *p = v; }
__device__ __forceinline__ void stc(bf16* p, float v) { *p = __float2bfloat16(v); }

__device__ __forceinline__ float4 ld4(const float* p) { return *(const float4*)p; }
__device__ __forceinline__ float4 ld4(const bf16* p) {
    union { short s[4]; } u; *(int2*)u.s = *(const int2*)p;
    float4 v;
    v.x = cvt(((const bf16*)u.s)[0]); v.y = cvt(((const bf16*)u.s)[1]);
    v.z = cvt(((const bf16*)u.s)[2]); v.w = cvt(((const bf16*)u.s)[3]);
    return v;
}
__device__ __forceinline__ void ld8f(const bf16* p, float* d) {
    union { short8 v; bf16 e[8]; } u;
    u.v = *(const short8*)p;
#pragma unroll
    for (int j = 0; j < 8; j++) d[j] = cvt(u.e[j]);
}

#define LDS_U32(p) ((__attribute__((address_space(3))) uint32_t*)(p))
#define GLB_U32(p) ((const __attribute__((address_space(1))) uint32_t*)(p))

// ============================ MFMA bf16 GEMM (batched strides, swizzled global_load_lds staging) ============================
// XCD-aware bijective block remap. DSUB: C = diag(beta) - alpha*A@Bt^T (primary).
// TMODE: 0 none; 1 also write Ct[n][m] = v; 2 also write Ct[n][m] = (m==n?betaT:0) - v.
template<int FM, int FN, int ACT, bool RESID, bool DSUB, int TMODE, typename TC>
__global__ __launch_bounds__(256)
void mfma_gemm_kernel(const bf16* __restrict__ Abase, const bf16* __restrict__ Btbase,
                      TC* __restrict__ Cbase, bf16* __restrict__ Ctbase,
                      const float* __restrict__ bias,
                      int M, int N, int K, int lda, int ldb, int ldc,
                      i64 sAb, i64 sAh, i64 sBb, i64 sBh, i64 sCb, i64 sCh,
                      int nh, float alpha, float beta, float betaT)
{
    constexpr int BM = FM * 32;
    constexpr int BN = FN * 32;
    constexpr int ASL = BM / 8;          // A slabs (8 rows each)
    constexpr int NSL = (BM + BN) / 8;   // total slabs
    constexpr int NIT = NSL / 4;         // per-wave slab iterations (compile-time)
    __shared__ bf16 Al[BM][64];
    __shared__ bf16 Bl[BN][64];

    int nwg  = gridDim.x * gridDim.y * gridDim.z;
    int orig = (blockIdx.z * gridDim.y + blockIdx.y) * gridDim.x + blockIdx.x;
    int qq = nwg >> 3, rr = nwg & 7;
    int xcd = orig & 7, loc = orig >> 3;
    int wid = (xcd < rr ? xcd * (qq + 1) : rr * (qq + 1) + (xcd - rr) * qq) + loc;
    int bx = wid % gridDim.x;
    int t1 = wid / gridDim.x;
    int by = t1 % gridDim.y;
    int bz = t1 / gridDim.y;

    int bb = bz / nh, hh = bz % nh;
    const bf16* A  = Abase  + bb * sAb + hh * sAh;
    const bf16* Bt = Btbase + bb * sBb + hh * sBh;
    TC*         C  = Cbase  + bb * sCb + hh * sCh;
    bf16* Ct = nullptr;
    if (TMODE) Ct = Ctbase + bb * sCb + hh * sCh;

    int tid = threadIdx.x;
    int wave = tid >> 6, lane = tid & 63;
    int wm = (wave >> 1) * (FM * 16), wn = (wave & 1) * (FN * 16);
    int m0 = by * BM, n0 = bx * BN;
    int lr = lane & 15, lq = lane >> 4;
    int srow = lane >> 3;
    int scol = ((lane & 7) ^ srow) * 8;

    // hoist per-slab global source pointers and LDS destinations
    const bf16* gsrc[NIT];
    uint32_t* ldst[NIT];
#pragma unroll
    for (int s = 0; s < NIT; s++) {
        int op = wave + s * 4;
        if (op < ASL) {
            gsrc[s] = A + (i64)(m0 + op * 8 + srow) * lda + scol;
            ldst[s] = (uint32_t*)&Al[op * 8][0];
        } else {
            int o2 = op - ASL;
            gsrc[s] = Bt + (i64)(n0 + o2 * 8 + srow) * ldb + scol;
            ldst[s] = (uint32_t*)&Bl[o2 * 8][0];
        }
    }

    f32x4 acc[FM][FN];
#pragma unroll
    for (int i = 0; i < FM; i++)
#pragma unroll
        for (int j = 0; j < FN; j++) acc[i][j] = (f32x4){0.f, 0.f, 0.f, 0.f};

    int c0 = (lq ^ (lr & 7)) * 8;
    int c1 = ((4 | lq) ^ (lr & 7)) * 8;

    for (int k0 = 0; k0 < K; k0 += 64) {
#pragma unroll
        for (int s = 0; s < NIT; s++)
            __builtin_amdgcn_global_load_lds(GLB_U32(gsrc[s] + k0),
                (__attribute__((address_space(3))) uint32_t*)ldst[s], 16, 0, 0);
        __syncthreads();
        {
            short8 af[FM], bfr[FN];
#pragma unroll
            for (int i = 0; i < FM; i++) af[i]  = *(const short8*)&Al[wm + i * 16 + lr][c0];
#pragma unroll
            for (int j = 0; j < FN; j++) bfr[j] = *(const short8*)&Bl[wn + j * 16 + lr][c0];
#pragma unroll
            for (int i = 0; i < FM; i++)
#pragma unroll
                for (int j = 0; j < FN; j++)
                    acc[i][j] = __builtin_amdgcn_mfma_f32_16x16x32_bf16(af[i], bfr[j], acc[i][j], 0, 0, 0);
        }
        {
            short8 af[FM], bfr[FN];
#pragma unroll
            for (int i = 0; i < FM; i++) af[i]  = *(const short8*)&Al[wm + i * 16 + lr][c1];
#pragma unroll
            for (int j = 0; j < FN; j++) bfr[j] = *(const short8*)&Bl[wn + j * 16 + lr][c1];
#pragma unroll
            for (int i = 0; i < FM; i++)
#pragma unroll
                for (int j = 0; j < FN; j++)
                    acc[i][j] = __builtin_amdgcn_mfma_f32_16x16x32_bf16(af[i], bfr[j], acc[i][j], 0, 0, 0);
        }
        __syncthreads();
    }

#pragma unroll
    for (int i = 0; i < FM; i++)
#pragma unroll
        for (int r = 0; r < 4; r++) {
            int m = m0 + wm + i * 16 + lq * 4 + r;
            TC* crow = C + (i64)m * ldc;
#pragma unroll
            for (int j = 0; j < FN; j++) {
                int n = n0 + wn + j * 16 + lr;
                float v = acc[i][j][r] * alpha;
                if (DSUB) v = ((m == n) ? beta : 0.f) - v;
                if (bias) v += bias[n];
                if (ACT == 1) v = fmaxf(v, 0.f);
                else if (ACT == 2) v = 0.5f * v * (1.f + erff(v * 0.70710678118654752f));
                else if (ACT == 3) v = tanhf(v);
                if (RESID) v += cvt(crow[n]);
                stc(&crow[n], v);
                if (TMODE == 1) Ct[(i64)n * ldc + m] = __float2bfloat16(v);
                else if (TMODE == 2) Ct[(i64)n * ldc + m] = __float2bfloat16(((m == n) ? betaT : 0.f) - v);
            }
        }
}

template<int FM, int FN, int ACT, bool RES, typename TC>
static inline void ml(hipStream_t st, const bf16* A, const bf16* Bt, TC* C, const float* bias,
                      int M, int N, int K, int lda, int ldb, int ldc,
                      i64 sAb = 0, i64 sAh = 0, i64 sBb = 0, i64 sBh = 0, i64 sCb = 0, i64 sCh = 0,
                      int nb = 1, int nh = 1, float alpha = 1.f)
{
    dim3 g(N / (FN * 32), M / (FM * 32), nb * nh);
    mfma_gemm_kernel<FM, FN, ACT, RES, false, 0, TC><<<g, 256, 0, st>>>(
        A, Bt, C, nullptr, bias, M, N, K, lda, ldb, ldc, sAb, sAh, sBb, sBh, sCb, sCh, nh, alpha, 0.f, 0.f);
}

// pinv MFMA helper: 256x256x256, 16 batches, bf16 out
template<int TMODE, bool DSUB>
static inline void mlp2(hipStream_t st, bf16* C, bf16* Ct, const bf16* A, const bf16* Bt,
                        float alpha, float beta = 0.f, float betaT = 0.f)
{
    dim3 g(4, 4, 16);
    mfma_gemm_kernel<2, 2, 0, false, DSUB, TMODE, bf16><<<g, 256, 0, st>>>(
        A, Bt, C, Ct, nullptr, 256, 256, 256, 256, 256, 256,
        0, 65536, 0, 65536, 0, 65536, 16, alpha, beta, betaT);
}

// ============================ fused attn3 (flash-style split-KV) ============================
__global__ __launch_bounds__(256)
void attn3_fused_kernel(const bf16* __restrict__ qkv, const bf16* __restrict__ q_lb,
                        const bf16* __restrict__ vTall,
                        float* __restrict__ obuf, float* __restrict__ mbuf,
                        float* __restrict__ sbuf2)
{
    __shared__ bf16 qs[256][64];
    __shared__ bf16 ks[64][64];
    __shared__ bf16 vs[64][64];
    __shared__ bf16 Ps[4][64][64];

    int ch = blockIdx.x, bh = blockIdx.y;
    int b = bh >> 3, hh = bh & 7;
    const bf16* qg = q_lb + (i64)bh * (LMK * DH);
    const bf16* kg = qkv + (i64)b * SEQ * Q3 + DM + hh * DH;
    const bf16* vg = vTall + ((i64)b * NHEAD + hh) * ((i64)DH * SEQ);

    int tid = threadIdx.x;
    int wave = tid >> 6, lane = tid & 63;
    int lr = lane & 15, lq = lane >> 4;
    int srow = lane >> 3;
    int scol = ((lane & 7) ^ srow) * 8;
    int c0 = (lq ^ (lr & 7)) * 8;
    int c1 = ((4 | lq) ^ (lr & 7)) * 8;
    int qb = wave * 64;

    for (int sl = wave; sl < 32; sl += 4)
        __builtin_amdgcn_global_load_lds(GLB_U32(qg + (i64)(sl * 8 + srow) * 64 + scol),
                                         LDS_U32(&qs[sl * 8][0]), 16, 0, 0);

    f32x4 O[4][4];
    float m[4][4], s[4][4];
#pragma unroll
    for (int i = 0; i < 4; i++)
#pragma unroll
        for (int r = 0; r < 4; r++) { m[i][r] = -3.0e38f; s[i][r] = 0.f; }
#pragma unroll
    for (int i = 0; i < 4; i++)
#pragma unroll
        for (int j = 0; j < 4; j++) O[i][j] = (f32x4){0.f, 0.f, 0.f, 0.f};

    int k0g = ch * 1024;
    for (int t = 0; t < 16; t++) {
        int kk0 = k0g + t * 64;
        for (int sl = wave; sl < 8; sl += 4)
            __builtin_amdgcn_global_load_lds(GLB_U32(kg + (i64)(kk0 + sl * 8 + srow) * Q3 + scol),
                                             LDS_U32(&ks[sl * 8][0]), 16, 0, 0);
        for (int sl = wave; sl < 8; sl += 4)
            __builtin_amdgcn_global_load_lds(GLB_U32(vg + (i64)(sl * 8 + srow) * SEQ + kk0 + scol),
                                             LDS_U32(&vs[sl * 8][0]), 16, 0, 0);
        __syncthreads();

        f32x4 S[4][4];
#pragma unroll
        for (int i = 0; i < 4; i++)
#pragma unroll
            for (int j = 0; j < 4; j++) S[i][j] = (f32x4){0.f, 0.f, 0.f, 0.f};
        {
            short8 af[4], bk[4];
#pragma unroll
            for (int i = 0; i < 4; i++) af[i] = *(const short8*)&qs[qb + i * 16 + lr][c0];
#pragma unroll
            for (int j = 0; j < 4; j++) bk[j] = *(const short8*)&ks[j * 16 + lr][c0];
#pragma unroll
            for (int i = 0; i < 4; i++)
#pragma unroll
                for (int j = 0; j < 4; j++)
                    S[i][j] = __builtin_amdgcn_mfma_f32_16x16x32_bf16(af[i], bk[j], S[i][j], 0, 0, 0);
#pragma unroll
            for (int i = 0; i < 4; i++) af[i] = *(const short8*)&qs[qb + i * 16 + lr][c1];
#pragma unroll
            for (int j = 0; j < 4; j++) bk[j] = *(const short8*)&ks[j * 16 + lr][c1];
#pragma unroll
            for (int i = 0; i < 4; i++)
#pragma unroll
                for (int j = 0; j < 4; j++)
                    S[i][j] = __builtin_amdgcn_mfma_f32_16x16x32_bf16(af[i], bk[j], S[i][j], 0, 0, 0);
        }

#pragma unroll
        for (int i = 0; i < 4; i++)
#pragma unroll
            for (int r = 0; r < 4; r++) {
                float tm = -3.0e38f;
#pragma unroll
                for (int j = 0; j < 4; j++) {
                    S[i][j][r] *= 0.125f;
                    tm = fmaxf(tm, S[i][j][r]);
                }
                tm = fmaxf(tm, __shfl_xor(tm, 1)); tm = fmaxf(tm, __shfl_xor(tm, 2));
                tm = fmaxf(tm, __shfl_xor(tm, 4)); tm = fmaxf(tm, __shfl_xor(tm, 8));
                float mn = fmaxf(m[i][r], tm);
                float f = expf(m[i][r] - mn);
                float ss = 0.f;
#pragma unroll
                for (int j = 0; j < 4; j++) {
                    float e = expf(S[i][j][r] - mn);
                    S[i][j][r] = e;
                    ss += e;
                }
                ss += __shfl_xor(ss, 1); ss += __shfl_xor(ss, 2);
                ss += __shfl_xor(ss, 4); ss += __shfl_xor(ss, 8);
                s[i][r] = s[i][r] * f + ss;
                m[i][r] = mn;
#pragma unroll
                for (int j2 = 0; j2 < 4; j2++) O[i][j2][r] *= f;
            }

#pragma unroll
        for (int i = 0; i < 4; i++)
#pragma unroll
            for (int j = 0; j < 4; j++)
#pragma unroll
                for (int r = 0; r < 4; r++) {
                    int row = i * 16 + lq * 4 + r;
                    int col = j * 16 + lr;
                    Ps[wave][row][(((col >> 3) ^ (row & 7)) << 3) | (col & 7)] =
                        __float2bfloat16(S[i][j][r]);
                }
        __syncthreads();

        {
            short8 a2[4], b2[4];
#pragma unroll
            for (int i = 0; i < 4; i++) a2[i] = *(const short8*)&Ps[wave][i * 16 + lr][c0];
#pragma unroll
            for (int j = 0; j < 4; j++) b2[j] = *(const short8*)&vs[j * 16 + lr][c0];
#pragma unroll
            for (int i = 0; i < 4; i++)
#pragma unroll
                for (int j = 0; j < 4; j++)
                    O[i][j] = __builtin_amdgcn_mfma_f32_16x16x32_bf16(a2[i], b2[j], O[i][j], 0, 0, 0);
#pragma unroll
            for (int i = 0; i < 4; i++) a2[i] = *(const short8*)&Ps[wave][i * 16 + lr][c1];
#pragma unroll
            for (int j = 0; j < 4; j++) b2[j] = *(const short8*)&vs[j * 16 + lr][c1];
#pragma unroll
            for (int i = 0; i < 4; i++)
#pragma unroll
                for (int j = 0; j < 4; j++)
                    O[i][j] = __builtin_amdgcn_mfma_f32_16x16x32_bf16(a2[i], b2[j], O[i][j], 0, 0, 0);
        }
        __syncthreads();
    }

    i64 base = (i64)(bh * 16 + ch) * 256 * 64;
#pragma unroll
    for (int i = 0; i < 4; i++)
#pragma unroll
        for (int j2 = 0; j2 < 4; j2++)
#pragma unroll
            for (int r = 0; r < 4; r++) {
                int row = qb + i * 16 + lq * 4 + r;
                int d = j2 * 16 + lr;
                obuf[base + (i64)row * 64 + d] = O[i][j2][r];
            }
    if (lr == 0) {
#pragma unroll
        for (int i = 0; i < 4; i++)
#pragma unroll
            for (int r = 0; r < 4; r++) {
                int idx = (bh * 16 + ch) * 256 + qb + i * 16 + lq * 4 + r;
                mbuf[idx] = m[i][r];
                sbuf2[idx] = s[i][r];
            }
    }
}

// combine split-KV partials -> a3v^T (bf16, [bh][d][row]) for the yT MFMA
__global__ __launch_bounds__(256)
void attn3_combine_kernel(const float* __restrict__ obuf, const float* __restrict__ mbuf,
                          const float* __restrict__ sbuf2, bf16* __restrict__ a3vT)
{
    int gid = blockIdx.x * 4 + (threadIdx.x >> 6);   // 4096 rows
    int lane = threadIdx.x & 63;
    int bh = gid >> 8, row = gid & 255;
    float mv[16];
    float M = -3.0e38f;
#pragma unroll
    for (int c = 0; c < 16; c++) {
        mv[c] = mbuf[(bh * 16 + c) * 256 + row];
        M = fmaxf(M, mv[c]);
    }
    float denom = 0.f, w[16];
#pragma unroll
    for (int c = 0; c < 16; c++) {
        w[c] = expf(mv[c] - M);
        denom += sbuf2[(bh * 16 + c) * 256 + row] * w[c];
    }
    float acc = 0.f;
#pragma unroll
    for (int c = 0; c < 16; c++)
        acc += obuf[((i64)(bh * 16 + c) * 256 + row) * 64 + lane] * w[c];
    a3vT[(i64)bh * (DH * LMK) + lane * 256 + row] = __float2bfloat16(acc / denom);
}

// ============================ fused attn1: S=q@klb^T -> softmax(256) -> @y^T -> xn ============================
__global__ __launch_bounds__(256)
void attn1_fused_kernel(const bf16* __restrict__ qkv, const bf16* __restrict__ klb_all,
                        const bf16* __restrict__ yTb_all, bf16* __restrict__ xn)
{
    __shared__ bf16 stage[24576];
    __shared__ bf16 Ps[128][256];
    __shared__ float maxb[2][128];
    __shared__ float sumb[2][128];
    bf16 (*qs)[64]  = (bf16(*)[64])&stage[0];
    bf16 (*ks)[64]  = (bf16(*)[64])&stage[8192];
    bf16 (*yts)[256]= (bf16(*)[256])&stage[0];

    int hh = blockIdx.y;
    i64 g0 = (i64)blockIdx.x * 128;
    int b  = (int)(g0 >> 14);
    const bf16* qg = qkv + (i64)b * SEQ * Q3 + (g0 & (SEQ - 1)) * Q3 + hh * DH;
    const bf16* kg = klb_all + (i64)(b * NHEAD + hh) * (LMK * DH);
    const bf16* yg = yTb_all + (i64)(b * NHEAD + hh) * (DH * LMK);

    int tid = threadIdx.x;
    int wave = tid >> 6, lane = tid & 63;
    int lr = lane & 15, lq = lane >> 4;
    int srow = lane >> 3;
    int scol = ((lane & 7) ^ srow) * 8;

    for (int sl = wave; sl < 16; sl += 4)
        __builtin_amdgcn_global_load_lds(GLB_U32(qg + (i64)(sl * 8 + srow) * Q3 + scol),
                                         LDS_U32(&qs[sl * 8][0]), 16, 0, 0);
    for (int sl = wave; sl < 32; sl += 4)
        __builtin_amdgcn_global_load_lds(GLB_U32(kg + (i64)(sl * 8 + srow) * 64 + scol),
                                         LDS_U32(&ks[sl * 8][0]), 16, 0, 0);
    __syncthreads();

    int wm = (wave >> 1) * 64, wn = (wave & 1) * 128;
    f32x4 acc[4][8];
#pragma unroll
    for (int i = 0; i < 4; i++)
#pragma unroll
        for (int j = 0; j < 8; j++) acc[i][j] = (f32x4){0.f, 0.f, 0.f, 0.f};

    int c0 = (lq ^ (lr & 7)) * 8;
    int c1 = ((4 | lq) ^ (lr & 7)) * 8;
    {
        short8 af[4], bfr[8];
#pragma unroll
        for (int i = 0; i < 4; i++) af[i]  = *(const short8*)&qs[wm + i * 16 + lr][c0];
#pragma unroll
        for (int j = 0; j < 8; j++) bfr[j] = *(const short8*)&ks[wn + j * 16 + lr][c0];
#pragma unroll
        for (int i = 0; i < 4; i++)
#pragma unroll
            for (int j = 0; j < 8; j++)
                acc[i][j] = __builtin_amdgcn_mfma_f32_16x16x32_bf16(af[i], bfr[j], acc[i][j], 0, 0, 0);
    }
    {
        short8 af[4], bfr[8];
#pragma unroll
        for (int i = 0; i < 4; i++) af[i]  = *(const short8*)&qs[wm + i * 16 + lr][c1];
#pragma unroll
        for (int j = 0; j < 8; j++) bfr[j] = *(const short8*)&ks[wn + j * 16 + lr][c1];
#pragma unroll
        for (int i = 0; i < 4; i++)
#pragma unroll
            for (int j = 0; j < 8; j++)
                acc[i][j] = __builtin_amdgcn_mfma_f32_16x16x32_bf16(af[i], bfr[j], acc[i][j], 0, 0, 0);
    }

#pragma unroll
    for (int i = 0; i < 4; i++)
#pragma unroll
        for (int j = 0; j < 8; j++)
#pragma unroll
            for (int r = 0; r < 4; r++) acc[i][j][r] *= 0.125f;
#pragma unroll
    for (int i = 0; i < 4; i++)
#pragma unroll
        for (int r = 0; r < 4; r++) {
            float m = acc[i][0][r];
#pragma unroll
            for (int j = 1; j < 8; j++) m = fmaxf(m, acc[i][j][r]);
            m = fmaxf(m, __shfl_xor(m, 1)); m = fmaxf(m, __shfl_xor(m, 2));
            m = fmaxf(m, __shfl_xor(m, 4)); m = fmaxf(m, __shfl_xor(m, 8));
            if (lr == 0) maxb[wave & 1][wm + i * 16 + lq * 4 + r] = m;
        }
    __syncthreads();

    {
        int r2 = lane >> 5, c32 = lane & 31;
        for (int sl = wave; sl < 32; sl += 4) {
            int row = sl * 2 + r2;
            const bf16* g = yg + (i64)row * 256 + ((c32 ^ (row & 7)) * 8);
            __builtin_amdgcn_global_load_lds(GLB_U32(g), LDS_U32(&yts[sl * 2][0]), 16, 0, 0);
        }
    }

#pragma unroll
    for (int i = 0; i < 4; i++)
#pragma unroll
        for (int r = 0; r < 4; r++) {
            int row = wm + i * 16 + lq * 4 + r;
            float fm = fmaxf(maxb[0][row], maxb[1][row]);
            float ss = 0.f;
#pragma unroll
            for (int j = 0; j < 8; j++) {
                float e = expf(acc[i][j][r] - fm);
                acc[i][j][r] = e;
                ss += e;
            }
            ss += __shfl_xor(ss, 1); ss += __shfl_xor(ss, 2);
            ss += __shfl_xor(ss, 4); ss += __shfl_xor(ss, 8);
            if (lr == 0) sumb[wave & 1][row] = ss;
        }
#pragma unroll
    for (int i = 0; i < 4; i++)
#pragma unroll
        for (int j = 0; j < 8; j++)
#pragma unroll
            for (int r = 0; r < 4; r++) {
                int row = wm + i * 16 + lq * 4 + r;
                int col = wn + j * 16 + lr;
                Ps[row][(((col >> 3) ^ (row & 7)) << 3) | (col & 7)] = __float2bfloat16(acc[i][j][r]);
            }
    __syncthreads();

    float s[4][4];
#pragma unroll
    for (int i = 0; i < 4; i++)
#pragma unroll
        for (int r = 0; r < 4; r++) {
            int row = wm + i * 16 + lq * 4 + r;
            s[i][r] = sumb[0][row] + sumb[1][row];
        }

    int wn2 = (wave & 1) * 32;
    f32x4 acc2[4][2];
#pragma unroll
    for (int i = 0; i < 4; i++)
#pragma unroll
        for (int j = 0; j < 2; j++) acc2[i][j] = (f32x4){0.f, 0.f, 0.f, 0.f};
#pragma unroll
    for (int kk = 0; kk < 8; kk++) {
        int cc = ((kk * 4 + lq) ^ (lr & 7)) * 8;
        short8 a2[4], b2[2];
#pragma unroll
        for (int i = 0; i < 4; i++) a2[i] = *(const short8*)&Ps[wm + i * 16 + lr][cc];
#pragma unroll
        for (int j = 0; j < 2; j++) b2[j] = *(const short8*)&yts[wn2 + j * 16 + lr][cc];
#pragma unroll
        for (int i = 0; i < 4; i++)
#pragma unroll
            for (int j = 0; j < 2; j++)
                acc2[i][j] = __builtin_amdgcn_mfma_f32_16x16x32_bf16(a2[i], b2[j], acc2[i][j], 0, 0, 0);
    }

#pragma unroll
    for (int i = 0; i < 4; i++)
#pragma unroll
        for (int j = 0; j < 2; j++)
#pragma unroll
            for (int r = 0; r < 4; r++) {
                int row = wm + i * 16 + lq * 4 + r;
                int d = wn2 + j * 16 + lr;
                xn[(g0 + row) * DM + hh * DH + d] = __float2bfloat16(acc2[i][j][r] / s[i][r]);
            }
}

// ===================== weight transpose+convert: fp32 [K][N] -> bf16 [N][K] =====================
__global__ __launch_bounds__(256)
void transpose_w_kernel(const float* __restrict__ in, bf16* __restrict__ out, int K, int N)
{
    __shared__ float t[64][65];
    int k0 = blockIdx.y * 64, n0 = blockIdx.x * 64;
    int c = threadIdx.x & 63, r4 = threadIdx.x >> 6;
#pragma unroll
    for (int p = 0; p < 64; p += 4)
        t[p + r4][c] = in[(i64)(k0 + p + r4) * N + n0 + c];
    __syncthreads();
#pragma unroll
    for (int p = 0; p < 64; p += 4)
        out[(i64)(n0 + p + r4) * K + k0 + c] = __float2bfloat16(t[c][p + r4]);
}

// ===================== generic 64-col transpose -> bf16 (batched over b,h) =====================
__global__ __launch_bounds__(256)
void t64_kernel(const bf16* __restrict__ in, bf16* __restrict__ out, int ldin, int ldout,
                i64 sIb, i64 sIh, i64 sOb, i64 sOh, int nh)
{
    __shared__ bf16 t[64][72];
    int zz = blockIdx.y;
    int bb = zz / nh, hh = zz % nh;
    const bf16* ip = in + bb * sIb + hh * sIh;
    bf16* op = out + bb * sOb + hh * sOh;
    int r0 = blockIdx.x * 64;
    int c = threadIdx.x & 63, r4 = threadIdx.x >> 6;
#pragma unroll
    for (int p = 0; p < 64; p += 4)
        t[p + r4][c] = ip[(i64)(r0 + p + r4) * ldin + c];
    __syncthreads();
#pragma unroll
    for (int p = 0; p < 64; p += 4)
        op[(i64)(p + r4) * ldout + r0 + c] = t[c][p + r4];
}

// ===================== fp32 -> bf16 convert =====================
__global__ void cvt_bf16_kernel(const float* __restrict__ in, bf16* __restrict__ out, i64 n)
{
    i64 i = ((i64)blockIdx.x * 256 + threadIdx.x) * 4;
    if (i >= n) return;
    float4 v = *(const float4*)&in[i];
    out[i + 0] = __float2bfloat16(v.x);
    out[i + 1] = __float2bfloat16(v.y);
    out[i + 2] = __float2bfloat16(v.z);
    out[i + 3] = __float2bfloat16(v.w);
}

// ============================ LayerNorm (rows of 512), bf16 in -> bf16 out ============================
__global__ __launch_bounds__(256)
void ln_kernel(const bf16* __restrict__ in, bf16* __restrict__ out,
               const float* __restrict__ g, const float* __restrict__ b, int nrows)
{
    int row = blockIdx.x * 4 + (threadIdx.x >> 6);
    int lane = threadIdx.x & 63;
    if (row >= nrows) return;
    const bf16* x = in + (i64)row * DM;
    float vv[8];
    ld8f(&x[lane * 8], vv);
    float s = 0.f;
#pragma unroll
    for (int j = 0; j < 8; j++) s += vv[j];
    for (int o = 32; o > 0; o >>= 1) s += __shfl_xor(s, o);
    float mu = s * (1.f / DM);
    float dd[8];
#pragma unroll
    for (int j = 0; j < 8; j++) dd[j] = vv[j] - mu;
    float vs = 0.f;
#pragma unroll
    for (int j = 0; j < 8; j++) vs += dd[j] * dd[j];
    for (int o = 32; o > 0; o >>= 1) vs += __shfl_xor(vs, o);
    float rstd = rsqrtf(vs * (1.f / DM) + 1e-5f);
    int c = lane * 8;
    bf16* y = out + (i64)row * DM;
#pragma unroll
    for (int j = 0; j < 8; j++)
        y[c + j] = __float2bfloat16(dd[j] * rstd * g[c + j] + b[c + j]);
}

// ============================ landmark means (q and k in one launch) ============================
__global__ void landmark_kernel(const bf16* __restrict__ qkv, bf16* __restrict__ q_lb,
                                bf16* __restrict__ klb)
{
    int blk = blockIdx.x;               // [0, 2*16*LMK)
    int which = blk >> 12;              // 0 = q, 1 = k
    int blk2 = blk & 4095;
    int im = blk2 & (LMK - 1);
    int bh = blk2 >> 8;
    int b = bh >> 3, h = bh & 7;
    int d = threadIdx.x;
    int off = which ? DM : 0;
    const bf16* p = qkv + (i64)(b * SEQ + im * LSUB) * Q3 + off + h * DH + d;
    float s = 0.f;
    for (int il = 0; il < LSUB; il++) s += cvt(p[(i64)il * Q3]);
    bf16* out = which ? klb : q_lb;
    out[((i64)bh * LMK + im) * DH + d] = __float2bfloat16(s * (1.f / LSUB));
}

// ============================ softmax rows of 256, fp32 -> bf16 ============================
__global__ __launch_bounds__(256)
void softmax256_fb_kernel(const float* __restrict__ in, bf16* __restrict__ out, i64 nrows)
{
    i64 row = (i64)blockIdx.x * 4 + (threadIdx.x >> 6);
    int lane = threadIdx.x & 63;
    if (row >= nrows) return;
    const float* p = in + row * 256;
    float4 v = *(const float4*)&p[lane * 4];
    float mx = fmaxf(fmaxf(v.x, v.y), fmaxf(v.z, v.w));
    for (int o = 32; o > 0; o >>= 1) mx = fmaxf(mx, __shfl_xor(mx, o));
    v.x = expf(v.x - mx); v.y = expf(v.y - mx);
    v.z = expf(v.z - mx); v.w = expf(v.w - mx);
    float s = v.x + v.y + v.z + v.w;
    for (int o = 32; o > 0; o >>= 1) s += __shfl_xor(s, o);
    float inv = 1.f / s;
    bf16* q = out + row * 256;
    q[lane * 4 + 0] = __float2bfloat16(v.x * inv);
    q[lane * 4 + 1] = __float2bfloat16(v.y * inv);
    q[lane * 4 + 2] = __float2bfloat16(v.z * inv);
    q[lane * 4 + 3] = __float2bfloat16(v.w * inv);
}

// ============================ softmax rows of 16384 (block per row) ============================
__global__ __launch_bounds__(256)
void softmax_big_kernel(const float* __restrict__ in, float* __restrict__ out)
{
    __shared__ float buf[SEQ];
    __shared__ float red[256];
    int t = threadIdx.x;
    const float* src = in + (i64)blockIdx.x * SEQ;
    float mx = -3.0e38f;
#pragma unroll
    for (int j = 0; j < 16; j++) {
        float4 v = *(const float4*)&src[(j * 256 + t) * 4];
        *(float4*)&buf[(j * 256 + t) * 4] = v;
        mx = fmaxf(mx, fmaxf(fmaxf(v.x, v.y), fmaxf(v.z, v.w)));
    }
    red[t] = mx; __syncthreads();
    for (int s = 128; s > 0; s >>= 1) { if (t < s) red[t] = fmaxf(red[t], red[t + s]); __syncthreads(); }
    mx = red[0];
    __syncthreads();
    float sum = 0.f;
#pragma unroll
    for (int j = 0; j < 16; j++) {
        float4 v = *(float4*)&buf[(j * 256 + t) * 4];
        v.x = expf(v.x - mx); v.y = expf(v.y - mx);
        v.z = expf(v.z - mx); v.w = expf(v.w - mx);
        *(float4*)&buf[(j * 256 + t) * 4] = v;
        sum += v.x + v.y + v.z + v.w;
    }
    red[t] = sum; __syncthreads();
    for (int s = 128; s > 0; s >>= 1) { if (t < s) red[t] += red[t + s]; __syncthreads(); }
    float inv = 1.f / red[0];
    float* dst = out + (i64)blockIdx.x * SEQ;
#pragma unroll
    for (int j = 0; j < 16; j++) {
        float4 v = *(float4*)&buf[(j * 256 + t) * 4];
        v.x *= inv; v.y *= inv; v.z *= inv; v.w *= inv;
        *(float4*)&dst[(j * 256 + t) * 4] = v;
    }
}

// ============================ pinv helpers (bf16) ============================
__global__ void pinv_sums_kernel(const bf16* __restrict__ x, float* __restrict__ scal)
{
    int bh = blockIdx.x;
    const bf16* p = x + (i64)bh * 65536;
    int t = threadIdx.x;
    float cs = 0.f, rs = 0.f;
    for (int i = 0; i < 256; i++) cs += fabsf(cvt(p[i * 256 + t]));
    for (int j = 0; j < 256; j++) rs += fabsf(cvt(p[t * 256 + j]));
    __shared__ float rc[256], rr[256];
    rc[t] = cs; rr[t] = rs; __syncthreads();
    for (int s = 128; s > 0; s >>= 1) {
        if (t < s) { rc[t] = fmaxf(rc[t], rc[t + s]); rr[t] = fmaxf(rr[t], rr[t + s]); }
        __syncthreads();
    }
    if (t == 0) {
        atomicMax(reinterpret_cast<int*>(&scal[0]), __float_as_int(rc[0]));
        atomicMax(reinterpret_cast<int*>(&scal[1]), __float_as_int(rr[0]));
    }
}

__global__ void pinv_init_kernel(const bf16* __restrict__ x, const float* __restrict__ scal,
                                 bf16* __restrict__ z, bf16* __restrict__ zT)
{
    i64 idx = (i64)blockIdx.x * 256 + threadIdx.x;
    int j = (int)(idx & 255); int i = (int)((idx >> 8) & 255); i64 bh = idx >> 16;
    float inv = 1.f / (scal[0] * scal[1]);
    float xv = cvt(x[idx]) * inv;
    zT[idx] = __float2bfloat16(xv);
    z[(bh << 16) + ((i64)j << 8) + i] = __float2bfloat16(xv);
}

// ============================ depthwise conv residual added onto xn (bf16, 8-wide vectorized) ============================
__global__ __launch_bounds__(256)
void conv_add_kernel(const bf16* __restrict__ qkv, const float* __restrict__ w,
                     bf16* __restrict__ xn)
{
    union U8 { short8 v; bf16 e[8]; };
    i64 idx = (i64)blockIdx.x * 256 + threadIdx.x;
    int cg = (int)(idx & 63);
    i64 bn = idx >> 6;
    int n = (int)(bn & (SEQ - 1));
    int b = (int)(bn >> 14);
    int c = cg * 8;
    int h = c >> 6;

    U8 xin; xin.v = *(const short8*)&xn[(bn << 9) + c];
    float acc[8];
#pragma unroll
    for (int j = 0; j < 8; j++) acc[j] = cvt(xin.e[j]);

    const float* wk = w + h * 33;
    const bf16* vb = qkv + (i64)b * SEQ * Q3 + 2 * DM + c;
#pragma unroll
    for (int t = 0; t < 33; t++) {
        int nn = n + t - 16;
        if (nn >= 0 && nn < SEQ) {
            U8 vv; vv.v = *(const short8*)&vb[(i64)nn * Q3];
            float wt = wk[t];
#pragma unroll
            for (int j = 0; j < 8; j++) acc[j] = fmaf(wt, cvt(vv.e[j]), acc[j]);
        }
    }
    U8 o;
#pragma unroll
    for (int j = 0; j < 8; j++) o.e[j] = __float2bfloat16(acc[j]);
    *(short8*)&xn[(bn << 9) + c] = o.v;
}

// ============================ pooling ============================
__global__ void pool_score_kernel(const float* __restrict__ t, const float* __restrict__ w,
                                  const float* __restrict__ b2, float* __restrict__ s)
{
    int row = blockIdx.x * 4 + (threadIdx.x >> 6);
    int lane = threadIdx.x & 63;
    float acc = t[(i64)row * 128 + lane] * w[lane] + t[(i64)row * 128 + 64 + lane] * w[64 + lane];
    for (int o = 32; o > 0; o >>= 1) acc += __shfl_xor(acc, o);
    if (lane == 0) s[row] = acc + b2[0];
}

__global__ __launch_bounds__(256)
void pool_z_kernel(const float* __restrict__ a, const bf16* __restrict__ h, float* __restrict__ z)
{
    int bb = blockIdx.x >> 7, cg = blockIdx.x & 127;
    int c4 = cg * 4;
    int t = threadIdx.x;
    const float* ab = a + (i64)bb * SEQ;
    const bf16* hb = h + (i64)bb * SEQ * DM;
    float4 acc = {0.f, 0.f, 0.f, 0.f};
    for (int r = t; r < SEQ; r += 256) {
        float av = ab[r];
        float4 hv = ld4(&hb[(i64)r * DM + c4]);
        acc.x += av * hv.x; acc.y += av * hv.y; acc.z += av * hv.z; acc.w += av * hv.w;
    }
    __shared__ float4 red[256];
    red[t] = acc; __syncthreads();
    for (int s = 128; s > 0; s >>= 1) {
        if (t < s) {
            float4 o = red[t + s];
            red[t].x += o.x; red[t].y += o.y; red[t].z += o.z; red[t].w += o.w;
        }
        __syncthreads();
    }
    if (t == 0) *(float4*)&z[bb * DM + c4] = red[0];
}

__global__ void head_kernel(const float* __restrict__ z, const float* __restrict__ w,
                            const float* __restrict__ b, float* __restrict__ out)
{
    int t = threadIdx.x;
    int wv = t >> 6, lane = t & 63;
    int bb = wv >> 1, cls = wv & 1;
    float acc = 0.f;
#pragma unroll
    for (int j = 0; j < 8; j++) { int k = lane * 8 + j; acc += z[bb * DM + k] * w[k * 2 + cls]; }
    for (int o = 32; o > 0; o >>= 1) acc += __shfl_xor(acc, o);
    __shared__ float lg[4];
    if (lane == 0) lg[wv] = acc + b[cls];
    __syncthreads();
    if (t == 0) {
        for (int bi = 0; bi < 2; bi++) {
            float l0 = lg[bi * 2], l1 = lg[bi * 2 + 1];
            out[bi * 2 + 0] = l0; out[bi * 2 + 1] = l1;
            float m = fmaxf(l0, l1);
            float e0 = expf(l0 - m), e1 = expf(l1 - m);
            float inv = 1.f / (e0 + e1);
            out[4 + bi * 2 + 0] = e0 * inv; out[4 + bi * 2 + 1] = e1 * inv;
        }
    }
}

// ============================ host orchestration ============================
extern "C" void kernel_launch(void* const* d_in, const int* in_sizes, int n_in,
                              void* d_out, int out_size, void* d_ws, size_t ws_size,
                              hipStream_t stream)
{
    const float* x      = (const float*)d_in[0];
    const float* fc1_w  = (const float*)d_in[1];
    const float* fc1_b  = (const float*)d_in[2];
    const float* ln1_g  = (const float*)d_in[3];
    const float* ln1_b  = (const float*)d_in[4];
    const float* qkv_w  = (const float*)d_in[5];
    const float* out_w  = (const float*)d_in[6];
    const float* out_b  = (const float*)d_in[7];
    const float* conv_w = (const float*)d_in[8];
    const float* ln2_g  = (const float*)d_in[9];
    const float* ln2_b  = (const float*)d_in[10];
    const float* ff1_w  = (const float*)d_in[11];
    const float* ff1_b  = (const float*)d_in[12];
    const float* ff2_w  = (const float*)d_in[13];
    const float* ff2_b  = (const float*)d_in[14];
    const float* att1_w = (const float*)d_in[15];
    const float* att1_b = (const float*)d_in[16];
    const float* att2_w = (const float*)d_in[17];
    const float* att2_b = (const float*)d_in[18];
    const float* fc2_w  = (const float*)d_in[19];
    const float* fc2_b  = (const float*)d_in[20];
    float* out = (float*)d_out;
    float* ws  = (float*)d_ws;

    // ---- workspace layout (float units), same region sizes as passing round-13 layout ----
    i64 off = 0;
    bf16*  h    = (bf16*)(ws + off); off += (i64)ROWS * DM;      // A: bf16 residual
    bf16*  xn   = (bf16*)(ws + off); off += (i64)ROWS * DM / 2;  // B: bf16 act / attn-out
    bf16*  qkv  = (bf16*)(ws + off); off += (i64)ROWS * Q3 / 2;  // C: bf16 qkv / xb / ffc(+D)
    float* sbuf = ws + off; off += (i64)2 * LMK * SEQ;           // D: wT / vTall / MIL scores / ffc tail
    float* attn2= ws + off; off += 16 * 65536;                   // E: attn2f -> wTf1
    float* zA   = ws + off; off += 16 * 65536;                   // F: attn2b+XZ -> zF -> wTf2
    float* zB   = ws + off; off += 16 * 65536;                   // G┐
    float* xz   = ws + off; off += 16 * 65536;                   // H│ pinv pings | attn3 obuf
    float* wbuf = ws + off; off += 16 * 65536;                   // I│
    float* tbuf = ws + off; off += 16 * 65536;                   // J┘
    float* regK = ws + off; off += 16 * LMK * DH;                // K: q_lb + klb (bf16)
    float* regL = ws + off; off += 16 * LMK * DH;                // L: yTb + wTa (bf16)
    float* a3v  = ws + off; off += 16 * LMK * DH;                // M: a3vTb (bf16)
    float* ybuf = ws + off; off += 16 * LMK * DH;                // N: mbuf + sbuf2
    float* scor = ws + off; off += ROWS;
    float* zpool= ws + off; off += BATCH * DM;
    float* scal = ws + off; off += 16;
    if (ws_size < (size_t)off * sizeof(float)) return;

    bf16*  wT   = (bf16*)sbuf;
    bf16*  xb   = qkv;
    float* attn2f = attn2;
    bf16*  attn2b = (bf16*)zA;                 // F.0
    bf16*  XZ     = (bf16*)(zA + 524288);      // F.1
    bf16*  zG     = (bf16*)zB;
    bf16*  zGT    = (bf16*)(zB + 524288);
    bf16*  zH     = (bf16*)xz;
    bf16*  zHT    = (bf16*)(xz + 524288);
    bf16*  W1     = (bf16*)wbuf;               // I.0
    bf16*  W2     = (bf16*)(wbuf + 524288);    // I.1
    bf16*  zF     = attn2b;
    bf16*  vTall = (bf16*)sbuf;                // [2][8][64][16384] bf16 = D exactly
    float* obuf  = zB;                         // attn3 O partials: G..J exactly
    float* mbuf  = ybuf;
    float* sbuf2 = ybuf + 65536;
    bf16*  a3vTb = (bf16*)a3v;                 // [16][64][256] bf16
    bf16*  q_lb = (bf16*)regK;
    bf16*  klb  = (bf16*)(regK + 131072);
    bf16*  yTb  = (bf16*)regL;
    bf16*  wTa  = (bf16*)(regL + 131072);
    bf16*  wTf1 = (bf16*)attn2;
    bf16*  wTf2 = (bf16*)zA;
    bf16*  ffc  = qkv;

    const i64 sQKVb = (i64)SEQ * Q3;
    const i64 sLMh  = (i64)LMK * DH;

    // fc1 + ReLU via MFMA (h bf16)
    cvt_bf16_kernel<<<(ROWS * 1024 / 4 + 255) / 256, 256, 0, stream>>>(x, xb, (i64)ROWS * 1024);
    transpose_w_kernel<<<dim3(DM / 64, 1024 / 64), 256, 0, stream>>>(fc1_w, wT, 1024, DM);
    ml<4, 2, 1, false>(stream, xb, wT, h, fc1_b, ROWS, DM, 1024, 1024, 1024, DM);

    for (int L = 0; L < 2; L++) {
        const float* qw  = qkv_w + (i64)L * DM * Q3;
        const float* ow  = out_w + (i64)L * DM * DM;
        const float* ob  = out_b + (i64)L * DM;
        const float* cw  = conv_w + (i64)L * NHEAD * 33;
        const float* f1w = ff1_w + (i64)L * DM * FFD;
        const float* f1b = ff1_b + (i64)L * FFD;
        const float* f2w = ff2_w + (i64)L * FFD * DM;
        const float* f2b = ff2_b + (i64)L * DM;

        // LN1 -> xn (bf16); qkv = xn @ qw (MFMA)
        ln_kernel<<<ROWS/4, 256, 0, stream>>>(h, xn, ln1_g + L*DM, ln1_b + L*DM, ROWS);
        transpose_w_kernel<<<dim3(Q3 / 64, DM / 64), 256, 0, stream>>>(qw, wT, DM, Q3);
        ml<4, 2, 0, false>(stream, xn, wT, qkv, nullptr, ROWS, Q3, DM, DM, DM, Q3);

        // landmarks (q and k in one launch)
        landmark_kernel<<<2*16*LMK, 64, 0, stream>>>(qkv, q_lb, klb);

        // attn2 = softmax(0.125 * q_l @ k_l^T) via MFMA -> bf16
        ml<2, 2, 0, false>(stream, q_lb, klb, attn2f, nullptr,
            LMK, LMK, DH, DH, DH, LMK, 0, sLMh, 0, sLMh, 0, 65536, 1, 16, 0.125f);
        softmax256_fb_kernel<<<16*LMK/4, 256, 0, stream>>>(attn2f, attn2b, (i64)16*LMK);

        // pinv (Newton-Schulz, 6 iters, 4 MFMA launches/iter via dual-output epilogue)
        hipMemsetAsync(scal, 0, 2*sizeof(float), stream);
        pinv_sums_kernel<<<16, 256, 0, stream>>>(attn2b, scal);
        pinv_init_kernel<<<16*65536/256, 256, 0, stream>>>(attn2b, scal, zG, zGT);
        {
            bf16 *zp = zG, *zpT = zGT, *zq = zH, *zqT = zHT;
            for (int it = 0; it < 6; it++) {
                bool last = (it == 5);
                mlp2<2, false>(stream, XZ, W1, attn2b, zpT, 1.f, 0.f, 7.f);
                mlp2<0, true >(stream, W2, nullptr, W1, XZ, 1.f, 15.f);
                mlp2<0, true >(stream, W1, nullptr, W2, XZ, 1.f, 13.f);
                if (!last) {
                    mlp2<1, false>(stream, zq, zqT, zp, W1, 0.25f);
                    bf16* t1 = zp; zp = zq; zq = t1;
                    bf16* t2 = zpT; zpT = zqT; zqT = t2;
                } else {
                    mlp2<0, false>(stream, zF, nullptr, zp, W1, 0.25f);
                }
            }
        }
        // final pinv z at zF. D and G..J free now.

        // attn3: batched vT -> fused flash split-KV -> combine (writes a3v^T bf16)
        t64_kernel<<<dim3(SEQ/64, BATCH*NHEAD), 256, 0, stream>>>(
            qkv + 2*DM, vTall, Q3, SEQ,
            sQKVb, (i64)DH, (i64)NHEAD*DH*SEQ, (i64)DH*SEQ, NHEAD);
        attn3_fused_kernel<<<dim3(16, 16), 256, 0, stream>>>(qkv, q_lb, vTall, obuf, mbuf, sbuf2);
        attn3_combine_kernel<<<16*LMK/4, 256, 0, stream>>>(obuf, mbuf, sbuf2, a3vTb);

        // yT = a3v^T @ z^T  (one MFMA launch -> yTb bf16)
        ml<2, 4, 0, false>(stream, a3vTb, zF, yTb, nullptr,
            DH, LMK, LMK, LMK, LMK, LMK, 0, (i64)DH*LMK, 0, 65536, 0, (i64)DH*LMK, 1, 16, 1.f);

        // attn1: fused QK + softmax + PV, all heads, one launch -> xn
        attn1_fused_kernel<<<dim3(ROWS/128, NHEAD), 256, 0, stream>>>(qkv, klb, yTb, xn);

        // xn += depthwise conv(v); h += xn @ out_w + out_b (MFMA, bf16 resid)
        conv_add_kernel<<<(i64)ROWS*64/256, 256, 0, stream>>>(qkv, cw, xn);
        transpose_w_kernel<<<dim3(DM / 64, DM / 64), 256, 0, stream>>>(ow, wT, DM, DM);
        ml<4, 2, 0, true>(stream, xn, wT, h, ob, ROWS, DM, DM, DM, DM, DM);

        // FF block (MFMA; single pass, ffc spans C+D)
        ln_kernel<<<ROWS/4, 256, 0, stream>>>(h, xn, ln2_g + L*DM, ln2_b + L*DM, ROWS);
        transpose_w_kernel<<<dim3(FFD / 64, DM / 64), 256, 0, stream>>>(f1w, wTf1, DM, FFD);
        transpose_w_kernel<<<dim3(DM / 64, FFD / 64), 256, 0, stream>>>(f2w, wTf2, FFD, DM);
        ml<4, 2, 2, false>(stream, xn, wTf1, ffc, f1b, ROWS, FFD, DM, DM, DM, FFD);
        ml<4, 2, 0, true >(stream, ffc, wTf2, h, f2b, ROWS, DM, FFD, FFD, FFD, DM);
    }

    // gated-attention MIL pooling: tanh(h @ att1_w + b) via MFMA (h bf16)
    transpose_w_kernel<<<dim3(128 / 64, DM / 64), 256, 0, stream>>>(att1_w, wTa, DM, 128);
    ml<4, 2, 3, false>(stream, h, wTa, sbuf, att1_b, ROWS, 128, DM, DM, DM, 128);
    pool_score_kernel<<<ROWS/4, 256, 0, stream>>>(sbuf, att2_w, att2_b, scor);
    softmax_big_kernel<<<BATCH, 256, 0, stream>>>(scor, out + 8);
    pool_z_kernel<<<BATCH * 128, 256, 0, stream>>>(out + 8, h, zpool);
    head_kernel<<<1, 256, 0, stream>>>(zpool, fc2_w, fc2_b, out);
}

// Round 15
// 1948.958 us; speedup vs baseline: 30.8112x; 1.0144x over previous
//
#include <hip/hip_runtime.h>
#include <hip/hip_bf16.h>

typedef long long i64;
typedef __hip_bfloat16 bf16;
using short8 = __attribute__((ext_vector_type(8))) short;
using f32x4  = __attribute__((ext_vector_type(4))) float;

#define SEQ    16384
#define DM     512
#define NHEAD  8
#define DH     64
#define LMK    256
#define LSUB   64      // SEQ / LMK
#define Q3     1536
#define FFD    2048
#define BATCH  2
#define ROWS   (BATCH * SEQ)

__device__ __forceinline__ float cvt(float v) { return v; }
__device__ __forceinline__ float cvt(bf16 v) { return __bfloat162float(v); }
__device__ __forceinline__ void stc(float* p, float v) { *p = v; }
__device__ __forceinline__ void stc(bf16* p, float v) { *p = __float2bfloat16(v); }

__device__ __forceinline__ float4 ld4(const float* p) { return *(const float4*)p; }
__device__ __forceinline__ float4 ld4(const bf16* p) {
    union { short s[4]; } u; *(int2*)u.s = *(const int2*)p;
    float4 v;
    v.x = cvt(((const bf16*)u.s)[0]); v.y = cvt(((const bf16*)u.s)[1]);
    v.z = cvt(((const bf16*)u.s)[2]); v.w = cvt(((const bf16*)u.s)[3]);
    return v;
}
__device__ __forceinline__ void ld8f(const bf16* p, float* d) {
    union { short8 v; bf16 e[8]; } u;
    u.v = *(const short8*)p;
#pragma unroll
    for (int j = 0; j < 8; j++) d[j] = cvt(u.e[j]);
}

// fast GELU (tanh form, hw exp+rcp): gelu(v) ~= v * e / (e + 1), e = exp(2a(v + b v^3))
__device__ __forceinline__ float gelu_fast(float v) {
    float u = v * (1.5957691216057308f + 0.07135370154f * v * v);
    float e = __expf(fminf(u, 80.f));
    return v * e * __builtin_amdgcn_rcpf(e + 1.f);
}
// exact tanh via hw exp+rcp
__device__ __forceinline__ float tanh_fast(float v) {
    float e = __expf(fminf(2.f * v, 80.f));
    return 1.f - 2.f * __builtin_amdgcn_rcpf(e + 1.f);
}

#define LDS_U32(p) ((__attribute__((address_space(3))) uint32_t*)(p))
#define GLB_U32(p) ((const __attribute__((address_space(1))) uint32_t*)(p))

// ============================ MFMA bf16 GEMM (batched strides, swizzled global_load_lds staging) ============================
// XCD-aware bijective block remap. DSUB: C = diag(beta) - alpha*A@Bt^T (primary).
// TMODE: 0 none; 1 also write Ct[n][m] = v; 2 also write Ct[n][m] = (m==n?betaT:0) - v.
template<int FM, int FN, int ACT, bool RESID, bool DSUB, int TMODE, typename TC>
__global__ __launch_bounds__(256)
void mfma_gemm_kernel(const bf16* __restrict__ Abase, const bf16* __restrict__ Btbase,
                      TC* __restrict__ Cbase, bf16* __restrict__ Ctbase,
                      const float* __restrict__ bias,
                      int M, int N, int K, int lda, int ldb, int ldc,
                      i64 sAb, i64 sAh, i64 sBb, i64 sBh, i64 sCb, i64 sCh,
                      int nh, float alpha, float beta, float betaT)
{
    constexpr int BM = FM * 32;
    constexpr int BN = FN * 32;
    constexpr int ASL = BM / 8;          // A slabs (8 rows each)
    constexpr int NSL = (BM + BN) / 8;   // total slabs
    constexpr int NIT = NSL / 4;         // per-wave slab iterations (compile-time)
    __shared__ bf16 Al[BM][64];
    __shared__ bf16 Bl[BN][64];

    int nwg  = gridDim.x * gridDim.y * gridDim.z;
    int orig = (blockIdx.z * gridDim.y + blockIdx.y) * gridDim.x + blockIdx.x;
    int qq = nwg >> 3, rr = nwg & 7;
    int xcd = orig & 7, loc = orig >> 3;
    int wid = (xcd < rr ? xcd * (qq + 1) : rr * (qq + 1) + (xcd - rr) * qq) + loc;
    int bx = wid % gridDim.x;
    int t1 = wid / gridDim.x;
    int by = t1 % gridDim.y;
    int bz = t1 / gridDim.y;

    int bb = bz / nh, hh = bz % nh;
    const bf16* A  = Abase  + bb * sAb + hh * sAh;
    const bf16* Bt = Btbase + bb * sBb + hh * sBh;
    TC*         C  = Cbase  + bb * sCb + hh * sCh;
    bf16* Ct = nullptr;
    if (TMODE) Ct = Ctbase + bb * sCb + hh * sCh;

    int tid = threadIdx.x;
    int wave = tid >> 6, lane = tid & 63;
    int wm = (wave >> 1) * (FM * 16), wn = (wave & 1) * (FN * 16);
    int m0 = by * BM, n0 = bx * BN;
    int lr = lane & 15, lq = lane >> 4;
    int srow = lane >> 3;
    int scol = ((lane & 7) ^ srow) * 8;

    // hoist per-slab global source pointers and LDS destinations
    const bf16* gsrc[NIT];
    uint32_t* ldst[NIT];
#pragma unroll
    for (int s = 0; s < NIT; s++) {
        int op = wave + s * 4;
        if (op < ASL) {
            gsrc[s] = A + (i64)(m0 + op * 8 + srow) * lda + scol;
            ldst[s] = (uint32_t*)&Al[op * 8][0];
        } else {
            int o2 = op - ASL;
            gsrc[s] = Bt + (i64)(n0 + o2 * 8 + srow) * ldb + scol;
            ldst[s] = (uint32_t*)&Bl[o2 * 8][0];
        }
    }

    f32x4 acc[FM][FN];
#pragma unroll
    for (int i = 0; i < FM; i++)
#pragma unroll
        for (int j = 0; j < FN; j++) acc[i][j] = (f32x4){0.f, 0.f, 0.f, 0.f};

    int c0 = (lq ^ (lr & 7)) * 8;
    int c1 = ((4 | lq) ^ (lr & 7)) * 8;

    for (int k0 = 0; k0 < K; k0 += 64) {
#pragma unroll
        for (int s = 0; s < NIT; s++)
            __builtin_amdgcn_global_load_lds(GLB_U32(gsrc[s] + k0),
                (__attribute__((address_space(3))) uint32_t*)ldst[s], 16, 0, 0);
        __syncthreads();
        {
            short8 af[FM], bfr[FN];
#pragma unroll
            for (int i = 0; i < FM; i++) af[i]  = *(const short8*)&Al[wm + i * 16 + lr][c0];
#pragma unroll
            for (int j = 0; j < FN; j++) bfr[j] = *(const short8*)&Bl[wn + j * 16 + lr][c0];
#pragma unroll
            for (int i = 0; i < FM; i++)
#pragma unroll
                for (int j = 0; j < FN; j++)
                    acc[i][j] = __builtin_amdgcn_mfma_f32_16x16x32_bf16(af[i], bfr[j], acc[i][j], 0, 0, 0);
        }
        {
            short8 af[FM], bfr[FN];
#pragma unroll
            for (int i = 0; i < FM; i++) af[i]  = *(const short8*)&Al[wm + i * 16 + lr][c1];
#pragma unroll
            for (int j = 0; j < FN; j++) bfr[j] = *(const short8*)&Bl[wn + j * 16 + lr][c1];
#pragma unroll
            for (int i = 0; i < FM; i++)
#pragma unroll
                for (int j = 0; j < FN; j++)
                    acc[i][j] = __builtin_amdgcn_mfma_f32_16x16x32_bf16(af[i], bfr[j], acc[i][j], 0, 0, 0);
        }
        __syncthreads();
    }

#pragma unroll
    for (int i = 0; i < FM; i++)
#pragma unroll
        for (int r = 0; r < 4; r++) {
            int m = m0 + wm + i * 16 + lq * 4 + r;
            TC* crow = C + (i64)m * ldc;
#pragma unroll
            for (int j = 0; j < FN; j++) {
                int n = n0 + wn + j * 16 + lr;
                float v = acc[i][j][r] * alpha;
                if (DSUB) v = ((m == n) ? beta : 0.f) - v;
                if (bias) v += bias[n];
                if (ACT == 1) v = fmaxf(v, 0.f);
                else if (ACT == 2) v = gelu_fast(v);
                else if (ACT == 3) v = tanh_fast(v);
                if (RESID) v += cvt(crow[n]);
                stc(&crow[n], v);
                if (TMODE == 1) Ct[(i64)n * ldc + m] = __float2bfloat16(v);
                else if (TMODE == 2) Ct[(i64)n * ldc + m] = __float2bfloat16(((m == n) ? betaT : 0.f) - v);
            }
        }
}

template<int FM, int FN, int ACT, bool RES, typename TC>
static inline void ml(hipStream_t st, const bf16* A, const bf16* Bt, TC* C, const float* bias,
                      int M, int N, int K, int lda, int ldb, int ldc,
                      i64 sAb = 0, i64 sAh = 0, i64 sBb = 0, i64 sBh = 0, i64 sCb = 0, i64 sCh = 0,
                      int nb = 1, int nh = 1, float alpha = 1.f)
{
    dim3 g(N / (FN * 32), M / (FM * 32), nb * nh);
    mfma_gemm_kernel<FM, FN, ACT, RES, false, 0, TC><<<g, 256, 0, st>>>(
        A, Bt, C, nullptr, bias, M, N, K, lda, ldb, ldc, sAb, sAh, sBb, sBh, sCb, sCh, nh, alpha, 0.f, 0.f);
}

// pinv MFMA helper: 256x256x256, 16 batches, bf16 out
template<int TMODE, bool DSUB>
static inline void mlp2(hipStream_t st, bf16* C, bf16* Ct, const bf16* A, const bf16* Bt,
                        float alpha, float beta = 0.f, float betaT = 0.f)
{
    dim3 g(4, 4, 16);
    mfma_gemm_kernel<2, 2, 0, false, DSUB, TMODE, bf16><<<g, 256, 0, st>>>(
        A, Bt, C, Ct, nullptr, 256, 256, 256, 256, 256, 256,
        0, 65536, 0, 65536, 0, 65536, 16, alpha, beta, betaT);
}

// ============================ fused attn3 (flash-style split-KV) ============================
__global__ __launch_bounds__(256)
void attn3_fused_kernel(const bf16* __restrict__ qkv, const bf16* __restrict__ q_lb,
                        const bf16* __restrict__ vTall,
                        float* __restrict__ obuf, float* __restrict__ mbuf,
                        float* __restrict__ sbuf2)
{
    __shared__ bf16 qs[256][64];
    __shared__ bf16 ks[64][64];
    __shared__ bf16 vs[64][64];
    __shared__ bf16 Ps[4][64][64];

    int ch = blockIdx.x, bh = blockIdx.y;
    int b = bh >> 3, hh = bh & 7;
    const bf16* qg = q_lb + (i64)bh * (LMK * DH);
    const bf16* kg = qkv + (i64)b * SEQ * Q3 + DM + hh * DH;
    const bf16* vg = vTall + ((i64)b * NHEAD + hh) * ((i64)DH * SEQ);

    int tid = threadIdx.x;
    int wave = tid >> 6, lane = tid & 63;
    int lr = lane & 15, lq = lane >> 4;
    int srow = lane >> 3;
    int scol = ((lane & 7) ^ srow) * 8;
    int c0 = (lq ^ (lr & 7)) * 8;
    int c1 = ((4 | lq) ^ (lr & 7)) * 8;
    int qb = wave * 64;

    for (int sl = wave; sl < 32; sl += 4)
        __builtin_amdgcn_global_load_lds(GLB_U32(qg + (i64)(sl * 8 + srow) * 64 + scol),
                                         LDS_U32(&qs[sl * 8][0]), 16, 0, 0);

    f32x4 O[4][4];
    float m[4][4], s[4][4];
#pragma unroll
    for (int i = 0; i < 4; i++)
#pragma unroll
        for (int r = 0; r < 4; r++) { m[i][r] = -3.0e38f; s[i][r] = 0.f; }
#pragma unroll
    for (int i = 0; i < 4; i++)
#pragma unroll
        for (int j = 0; j < 4; j++) O[i][j] = (f32x4){0.f, 0.f, 0.f, 0.f};

    int k0g = ch * 1024;
    for (int t = 0; t < 16; t++) {
        int kk0 = k0g + t * 64;
        for (int sl = wave; sl < 8; sl += 4)
            __builtin_amdgcn_global_load_lds(GLB_U32(kg + (i64)(kk0 + sl * 8 + srow) * Q3 + scol),
                                             LDS_U32(&ks[sl * 8][0]), 16, 0, 0);
        for (int sl = wave; sl < 8; sl += 4)
            __builtin_amdgcn_global_load_lds(GLB_U32(vg + (i64)(sl * 8 + srow) * SEQ + kk0 + scol),
                                             LDS_U32(&vs[sl * 8][0]), 16, 0, 0);
        __syncthreads();

        f32x4 S[4][4];
#pragma unroll
        for (int i = 0; i < 4; i++)
#pragma unroll
            for (int j = 0; j < 4; j++) S[i][j] = (f32x4){0.f, 0.f, 0.f, 0.f};
        {
            short8 af[4], bk[4];
#pragma unroll
            for (int i = 0; i < 4; i++) af[i] = *(const short8*)&qs[qb + i * 16 + lr][c0];
#pragma unroll
            for (int j = 0; j < 4; j++) bk[j] = *(const short8*)&ks[j * 16 + lr][c0];
#pragma unroll
            for (int i = 0; i < 4; i++)
#pragma unroll
                for (int j = 0; j < 4; j++)
                    S[i][j] = __builtin_amdgcn_mfma_f32_16x16x32_bf16(af[i], bk[j], S[i][j], 0, 0, 0);
#pragma unroll
            for (int i = 0; i < 4; i++) af[i] = *(const short8*)&qs[qb + i * 16 + lr][c1];
#pragma unroll
            for (int j = 0; j < 4; j++) bk[j] = *(const short8*)&ks[j * 16 + lr][c1];
#pragma unroll
            for (int i = 0; i < 4; i++)
#pragma unroll
                for (int j = 0; j < 4; j++)
                    S[i][j] = __builtin_amdgcn_mfma_f32_16x16x32_bf16(af[i], bk[j], S[i][j], 0, 0, 0);
        }

#pragma unroll
        for (int i = 0; i < 4; i++)
#pragma unroll
            for (int r = 0; r < 4; r++) {
                float tm = -3.0e38f;
#pragma unroll
                for (int j = 0; j < 4; j++) {
                    S[i][j][r] *= 0.125f;
                    tm = fmaxf(tm, S[i][j][r]);
                }
                tm = fmaxf(tm, __shfl_xor(tm, 1)); tm = fmaxf(tm, __shfl_xor(tm, 2));
                tm = fmaxf(tm, __shfl_xor(tm, 4)); tm = fmaxf(tm, __shfl_xor(tm, 8));
                float mn = fmaxf(m[i][r], tm);
                float f = expf(m[i][r] - mn);
                float ss = 0.f;
#pragma unroll
                for (int j = 0; j < 4; j++) {
                    float e = expf(S[i][j][r] - mn);
                    S[i][j][r] = e;
                    ss += e;
                }
                ss += __shfl_xor(ss, 1); ss += __shfl_xor(ss, 2);
                ss += __shfl_xor(ss, 4); ss += __shfl_xor(ss, 8);
                s[i][r] = s[i][r] * f + ss;
                m[i][r] = mn;
#pragma unroll
                for (int j2 = 0; j2 < 4; j2++) O[i][j2][r] *= f;
            }

#pragma unroll
        for (int i = 0; i < 4; i++)
#pragma unroll
            for (int j = 0; j < 4; j++)
#pragma unroll
                for (int r = 0; r < 4; r++) {
                    int row = i * 16 + lq * 4 + r;
                    int col = j * 16 + lr;
                    Ps[wave][row][(((col >> 3) ^ (row & 7)) << 3) | (col & 7)] =
                        __float2bfloat16(S[i][j][r]);
                }
        __syncthreads();

        {
            short8 a2[4], b2[4];
#pragma unroll
            for (int i = 0; i < 4; i++) a2[i] = *(const short8*)&Ps[wave][i * 16 + lr][c0];
#pragma unroll
            for (int j = 0; j < 4; j++) b2[j] = *(const short8*)&vs[j * 16 + lr][c0];
#pragma unroll
            for (int i = 0; i < 4; i++)
#pragma unroll
                for (int j = 0; j < 4; j++)
                    O[i][j] = __builtin_amdgcn_mfma_f32_16x16x32_bf16(a2[i], b2[j], O[i][j], 0, 0, 0);
#pragma unroll
            for (int i = 0; i < 4; i++) a2[i] = *(const short8*)&Ps[wave][i * 16 + lr][c1];
#pragma unroll
            for (int j = 0; j < 4; j++) b2[j] = *(const short8*)&vs[j * 16 + lr][c1];
#pragma unroll
            for (int i = 0; i < 4; i++)
#pragma unroll
                for (int j = 0; j < 4; j++)
                    O[i][j] = __builtin_amdgcn_mfma_f32_16x16x32_bf16(a2[i], b2[j], O[i][j], 0, 0, 0);
        }
        __syncthreads();
    }

    i64 base = (i64)(bh * 16 + ch) * 256 * 64;
#pragma unroll
    for (int i = 0; i < 4; i++)
#pragma unroll
        for (int j2 = 0; j2 < 4; j2++)
#pragma unroll
            for (int r = 0; r < 4; r++) {
                int row = qb + i * 16 + lq * 4 + r;
                int d = j2 * 16 + lr;
                obuf[base + (i64)row * 64 + d] = O[i][j2][r];
            }
    if (lr == 0) {
#pragma unroll
        for (int i = 0; i < 4; i++)
#pragma unroll
            for (int r = 0; r < 4; r++) {
                int idx = (bh * 16 + ch) * 256 + qb + i * 16 + lq * 4 + r;
                mbuf[idx] = m[i][r];
                sbuf2[idx] = s[i][r];
            }
    }
}

// combine split-KV partials -> a3v^T (bf16, [bh][d][row]) for the yT MFMA
__global__ __launch_bounds__(256)
void attn3_combine_kernel(const float* __restrict__ obuf, const float* __restrict__ mbuf,
                          const float* __restrict__ sbuf2, bf16* __restrict__ a3vT)
{
    int gid = blockIdx.x * 4 + (threadIdx.x >> 6);   // 4096 rows
    int lane = threadIdx.x & 63;
    int bh = gid >> 8, row = gid & 255;
    float mv[16];
    float M = -3.0e38f;
#pragma unroll
    for (int c = 0; c < 16; c++) {
        mv[c] = mbuf[(bh * 16 + c) * 256 + row];
        M = fmaxf(M, mv[c]);
    }
    float denom = 0.f, w[16];
#pragma unroll
    for (int c = 0; c < 16; c++) {
        w[c] = expf(mv[c] - M);
        denom += sbuf2[(bh * 16 + c) * 256 + row] * w[c];
    }
    float acc = 0.f;
#pragma unroll
    for (int c = 0; c < 16; c++)
        acc += obuf[((i64)(bh * 16 + c) * 256 + row) * 64 + lane] * w[c];
    a3vT[(i64)bh * (DH * LMK) + lane * 256 + row] = __float2bfloat16(acc / denom);
}

// ============================ fused attn1: S=q@klb^T -> softmax(256) -> @y^T -> xn ============================
__global__ __launch_bounds__(256)
void attn1_fused_kernel(const bf16* __restrict__ qkv, const bf16* __restrict__ klb_all,
                        const bf16* __restrict__ yTb_all, bf16* __restrict__ xn)
{
    __shared__ bf16 stage[24576];
    __shared__ bf16 Ps[128][256];
    __shared__ float maxb[2][128];
    __shared__ float sumb[2][128];
    bf16 (*qs)[64]  = (bf16(*)[64])&stage[0];
    bf16 (*ks)[64]  = (bf16(*)[64])&stage[8192];
    bf16 (*yts)[256]= (bf16(*)[256])&stage[0];

    int hh = blockIdx.y;
    i64 g0 = (i64)blockIdx.x * 128;
    int b  = (int)(g0 >> 14);
    const bf16* qg = qkv + (i64)b * SEQ * Q3 + (g0 & (SEQ - 1)) * Q3 + hh * DH;
    const bf16* kg = klb_all + (i64)(b * NHEAD + hh) * (LMK * DH);
    const bf16* yg = yTb_all + (i64)(b * NHEAD + hh) * (DH * LMK);

    int tid = threadIdx.x;
    int wave = tid >> 6, lane = tid & 63;
    int lr = lane & 15, lq = lane >> 4;
    int srow = lane >> 3;
    int scol = ((lane & 7) ^ srow) * 8;

    for (int sl = wave; sl < 16; sl += 4)
        __builtin_amdgcn_global_load_lds(GLB_U32(qg + (i64)(sl * 8 + srow) * Q3 + scol),
                                         LDS_U32(&qs[sl * 8][0]), 16, 0, 0);
    for (int sl = wave; sl < 32; sl += 4)
        __builtin_amdgcn_global_load_lds(GLB_U32(kg + (i64)(sl * 8 + srow) * 64 + scol),
                                         LDS_U32(&ks[sl * 8][0]), 16, 0, 0);
    __syncthreads();

    int wm = (wave >> 1) * 64, wn = (wave & 1) * 128;
    f32x4 acc[4][8];
#pragma unroll
    for (int i = 0; i < 4; i++)
#pragma unroll
        for (int j = 0; j < 8; j++) acc[i][j] = (f32x4){0.f, 0.f, 0.f, 0.f};

    int c0 = (lq ^ (lr & 7)) * 8;
    int c1 = ((4 | lq) ^ (lr & 7)) * 8;
    {
        short8 af[4], bfr[8];
#pragma unroll
        for (int i = 0; i < 4; i++) af[i]  = *(const short8*)&qs[wm + i * 16 + lr][c0];
#pragma unroll
        for (int j = 0; j < 8; j++) bfr[j] = *(const short8*)&ks[wn + j * 16 + lr][c0];
#pragma unroll
        for (int i = 0; i < 4; i++)
#pragma unroll
            for (int j = 0; j < 8; j++)
                acc[i][j] = __builtin_amdgcn_mfma_f32_16x16x32_bf16(af[i], bfr[j], acc[i][j], 0, 0, 0);
    }
    {
        short8 af[4], bfr[8];
#pragma unroll
        for (int i = 0; i < 4; i++) af[i]  = *(const short8*)&qs[wm + i * 16 + lr][c1];
#pragma unroll
        for (int j = 0; j < 8; j++) bfr[j] = *(const short8*)&ks[wn + j * 16 + lr][c1];
#pragma unroll
        for (int i = 0; i < 4; i++)
#pragma unroll
            for (int j = 0; j < 8; j++)
                acc[i][j] = __builtin_amdgcn_mfma_f32_16x16x32_bf16(af[i], bfr[j], acc[i][j], 0, 0, 0);
    }

#pragma unroll
    for (int i = 0; i < 4; i++)
#pragma unroll
        for (int j = 0; j < 8; j++)
#pragma unroll
            for (int r = 0; r < 4; r++) acc[i][j][r] *= 0.125f;
#pragma unroll
    for (int i = 0; i < 4; i++)
#pragma unroll
        for (int r = 0; r < 4; r++) {
            float m = acc[i][0][r];
#pragma unroll
            for (int j = 1; j < 8; j++) m = fmaxf(m, acc[i][j][r]);
            m = fmaxf(m, __shfl_xor(m, 1)); m = fmaxf(m, __shfl_xor(m, 2));
            m = fmaxf(m, __shfl_xor(m, 4)); m = fmaxf(m, __shfl_xor(m, 8));
            if (lr == 0) maxb[wave & 1][wm + i * 16 + lq * 4 + r] = m;
        }
    __syncthreads();

    {
        int r2 = lane >> 5, c32 = lane & 31;
        for (int sl = wave; sl < 32; sl += 4) {
            int row = sl * 2 + r2;
            const bf16* g = yg + (i64)row * 256 + ((c32 ^ (row & 7)) * 8);
            __builtin_amdgcn_global_load_lds(GLB_U32(g), LDS_U32(&yts[sl * 2][0]), 16, 0, 0);
        }
    }

#pragma unroll
    for (int i = 0; i < 4; i++)
#pragma unroll
        for (int r = 0; r < 4; r++) {
            int row = wm + i * 16 + lq * 4 + r;
            float fm = fmaxf(maxb[0][row], maxb[1][row]);
            float ss = 0.f;
#pragma unroll
            for (int j = 0; j < 8; j++) {
                float e = expf(acc[i][j][r] - fm);
                acc[i][j][r] = e;
                ss += e;
            }
            ss += __shfl_xor(ss, 1); ss += __shfl_xor(ss, 2);
            ss += __shfl_xor(ss, 4); ss += __shfl_xor(ss, 8);
            if (lr == 0) sumb[wave & 1][row] = ss;
        }
#pragma unroll
    for (int i = 0; i < 4; i++)
#pragma unroll
        for (int j = 0; j < 8; j++)
#pragma unroll
            for (int r = 0; r < 4; r++) {
                int row = wm + i * 16 + lq * 4 + r;
                int col = wn + j * 16 + lr;
                Ps[row][(((col >> 3) ^ (row & 7)) << 3) | (col & 7)] = __float2bfloat16(acc[i][j][r]);
            }
    __syncthreads();

    float s[4][4];
#pragma unroll
    for (int i = 0; i < 4; i++)
#pragma unroll
        for (int r = 0; r < 4; r++) {
            int row = wm + i * 16 + lq * 4 + r;
            s[i][r] = sumb[0][row] + sumb[1][row];
        }

    int wn2 = (wave & 1) * 32;
    f32x4 acc2[4][2];
#pragma unroll
    for (int i = 0; i < 4; i++)
#pragma unroll
        for (int j = 0; j < 2; j++) acc2[i][j] = (f32x4){0.f, 0.f, 0.f, 0.f};
#pragma unroll
    for (int kk = 0; kk < 8; kk++) {
        int cc = ((kk * 4 + lq) ^ (lr & 7)) * 8;
        short8 a2[4], b2[2];
#pragma unroll
        for (int i = 0; i < 4; i++) a2[i] = *(const short8*)&Ps[wm + i * 16 + lr][cc];
#pragma unroll
        for (int j = 0; j < 2; j++) b2[j] = *(const short8*)&yts[wn2 + j * 16 + lr][cc];
#pragma unroll
        for (int i = 0; i < 4; i++)
#pragma unroll
            for (int j = 0; j < 2; j++)
                acc2[i][j] = __builtin_amdgcn_mfma_f32_16x16x32_bf16(a2[i], b2[j], acc2[i][j], 0, 0, 0);
    }

#pragma unroll
    for (int i = 0; i < 4; i++)
#pragma unroll
        for (int j = 0; j < 2; j++)
#pragma unroll
            for (int r = 0; r < 4; r++) {
                int row = wm + i * 16 + lq * 4 + r;
                int d = wn2 + j * 16 + lr;
                xn[(g0 + row) * DM + hh * DH + d] = __float2bfloat16(acc2[i][j][r] / s[i][r]);
            }
}

// ===================== weight transpose+convert: fp32 [K][N] -> bf16 [N][K] =====================
__global__ __launch_bounds__(256)
void transpose_w_kernel(const float* __restrict__ in, bf16* __restrict__ out, int K, int N)
{
    __shared__ float t[64][65];
    int k0 = blockIdx.y * 64, n0 = blockIdx.x * 64;
    int c = threadIdx.x & 63, r4 = threadIdx.x >> 6;
#pragma unroll
    for (int p = 0; p < 64; p += 4)
        t[p + r4][c] = in[(i64)(k0 + p + r4) * N + n0 + c];
    __syncthreads();
#pragma unroll
    for (int p = 0; p < 64; p += 4)
        out[(i64)(n0 + p + r4) * K + k0 + c] = __float2bfloat16(t[c][p + r4]);
}

// ===================== generic 64-col transpose -> bf16 (batched over b,h) =====================
__global__ __launch_bounds__(256)
void t64_kernel(const bf16* __restrict__ in, bf16* __restrict__ out, int ldin, int ldout,
                i64 sIb, i64 sIh, i64 sOb, i64 sOh, int nh)
{
    __shared__ bf16 t[64][72];
    int zz = blockIdx.y;
    int bb = zz / nh, hh = zz % nh;
    const bf16* ip = in + bb * sIb + hh * sIh;
    bf16* op = out + bb * sOb + hh * sOh;
    int r0 = blockIdx.x * 64;
    int c = threadIdx.x & 63, r4 = threadIdx.x >> 6;
#pragma unroll
    for (int p = 0; p < 64; p += 4)
        t[p + r4][c] = ip[(i64)(r0 + p + r4) * ldin + c];
    __syncthreads();
#pragma unroll
    for (int p = 0; p < 64; p += 4)
        op[(i64)(p + r4) * ldout + r0 + c] = t[c][p + r4];
}

// ===================== fp32 -> bf16 convert =====================
__global__ void cvt_bf16_kernel(const float* __restrict__ in, bf16* __restrict__ out, i64 n)
{
    i64 i = ((i64)blockIdx.x * 256 + threadIdx.x) * 4;
    if (i >= n) return;
    float4 v = *(const float4*)&in[i];
    out[i + 0] = __float2bfloat16(v.x);
    out[i + 1] = __float2bfloat16(v.y);
    out[i + 2] = __float2bfloat16(v.z);
    out[i + 3] = __float2bfloat16(v.w);
}

// ============================ LayerNorm (rows of 512), bf16 in -> bf16 out ============================
__global__ __launch_bounds__(256)
void ln_kernel(const bf16* __restrict__ in, bf16* __restrict__ out,
               const float* __restrict__ g, const float* __restrict__ b, int nrows)
{
    int row = blockIdx.x * 4 + (threadIdx.x >> 6);
    int lane = threadIdx.x & 63;
    if (row >= nrows) return;
    const bf16* x = in + (i64)row * DM;
    float vv[8];
    ld8f(&x[lane * 8], vv);
    float s = 0.f;
#pragma unroll
    for (int j = 0; j < 8; j++) s += vv[j];
    for (int o = 32; o > 0; o >>= 1) s += __shfl_xor(s, o);
    float mu = s * (1.f / DM);
    float dd[8];
#pragma unroll
    for (int j = 0; j < 8; j++) dd[j] = vv[j] - mu;
    float vs = 0.f;
#pragma unroll
    for (int j = 0; j < 8; j++) vs += dd[j] * dd[j];
    for (int o = 32; o > 0; o >>= 1) vs += __shfl_xor(vs, o);
    float rstd = rsqrtf(vs * (1.f / DM) + 1e-5f);
    int c = lane * 8;
    bf16* y = out + (i64)row * DM;
#pragma unroll
    for (int j = 0; j < 8; j++)
        y[c + j] = __float2bfloat16(dd[j] * rstd * g[c + j] + b[c + j]);
}

// ============================ landmark means (q and k in one launch) ============================
__global__ void landmark_kernel(const bf16* __restrict__ qkv, bf16* __restrict__ q_lb,
                                bf16* __restrict__ klb)
{
    int blk = blockIdx.x;               // [0, 2*16*LMK)
    int which = blk >> 12;              // 0 = q, 1 = k
    int blk2 = blk & 4095;
    int im = blk2 & (LMK - 1);
    int bh = blk2 >> 8;
    int b = bh >> 3, h = bh & 7;
    int d = threadIdx.x;
    int off = which ? DM : 0;
    const bf16* p = qkv + (i64)(b * SEQ + im * LSUB) * Q3 + off + h * DH + d;
    float s = 0.f;
    for (int il = 0; il < LSUB; il++) s += cvt(p[(i64)il * Q3]);
    bf16* out = which ? klb : q_lb;
    out[((i64)bh * LMK + im) * DH + d] = __float2bfloat16(s * (1.f / LSUB));
}

// ============================ softmax rows of 256, fp32 -> bf16 ============================
__global__ __launch_bounds__(256)
void softmax256_fb_kernel(const float* __restrict__ in, bf16* __restrict__ out, i64 nrows)
{
    i64 row = (i64)blockIdx.x * 4 + (threadIdx.x >> 6);
    int lane = threadIdx.x & 63;
    if (row >= nrows) return;
    const float* p = in + row * 256;
    float4 v = *(const float4*)&p[lane * 4];
    float mx = fmaxf(fmaxf(v.x, v.y), fmaxf(v.z, v.w));
    for (int o = 32; o > 0; o >>= 1) mx = fmaxf(mx, __shfl_xor(mx, o));
    v.x = expf(v.x - mx); v.y = expf(v.y - mx);
    v.z = expf(v.z - mx); v.w = expf(v.w - mx);
    float s = v.x + v.y + v.z + v.w;
    for (int o = 32; o > 0; o >>= 1) s += __shfl_xor(s, o);
    float inv = 1.f / s;
    bf16* q = out + row * 256;
    q[lane * 4 + 0] = __float2bfloat16(v.x * inv);
    q[lane * 4 + 1] = __float2bfloat16(v.y * inv);
    q[lane * 4 + 2] = __float2bfloat16(v.z * inv);
    q[lane * 4 + 3] = __float2bfloat16(v.w * inv);
}

// ============================ softmax rows of 16384 (block per row) ============================
__global__ __launch_bounds__(256)
void softmax_big_kernel(const float* __restrict__ in, float* __restrict__ out)
{
    __shared__ float buf[SEQ];
    __shared__ float red[256];
    int t = threadIdx.x;
    const float* src = in + (i64)blockIdx.x * SEQ;
    float mx = -3.0e38f;
#pragma unroll
    for (int j = 0; j < 16; j++) {
        float4 v = *(const float4*)&src[(j * 256 + t) * 4];
        *(float4*)&buf[(j * 256 + t) * 4] = v;
        mx = fmaxf(mx, fmaxf(fmaxf(v.x, v.y), fmaxf(v.z, v.w)));
    }
    red[t] = mx; __syncthreads();
    for (int s = 128; s > 0; s >>= 1) { if (t < s) red[t] = fmaxf(red[t], red[t + s]); __syncthreads(); }
    mx = red[0];
    __syncthreads();
    float sum = 0.f;
#pragma unroll
    for (int j = 0; j < 16; j++) {
        float4 v = *(float4*)&buf[(j * 256 + t) * 4];
        v.x = expf(v.x - mx); v.y = expf(v.y - mx);
        v.z = expf(v.z - mx); v.w = expf(v.w - mx);
        *(float4*)&buf[(j * 256 + t) * 4] = v;
        sum += v.x + v.y + v.z + v.w;
    }
    red[t] = sum; __syncthreads();
    for (int s = 128; s > 0; s >>= 1) { if (t < s) red[t] += red[t + s]; __syncthreads(); }
    float inv = 1.f / red[0];
    float* dst = out + (i64)blockIdx.x * SEQ;
#pragma unroll
    for (int j = 0; j < 16; j++) {
        float4 v = *(float4*)&buf[(j * 256 + t) * 4];
        v.x *= inv; v.y *= inv; v.z *= inv; v.w *= inv;
        *(float4*)&dst[(j * 256 + t) * 4] = v;
    }
}

// ============================ pinv helpers (bf16) ============================
__global__ void pinv_sums_kernel(const bf16* __restrict__ x, float* __restrict__ scal)
{
    int bh = blockIdx.x;
    const bf16* p = x + (i64)bh * 65536;
    int t = threadIdx.x;
    float cs = 0.f, rs = 0.f;
    for (int i = 0; i < 256; i++) cs += fabsf(cvt(p[i * 256 + t]));
    for (int j = 0; j < 256; j++) rs += fabsf(cvt(p[t * 256 + j]));
    __shared__ float rc[256], rr[256];
    rc[t] = cs; rr[t] = rs; __syncthreads();
    for (int s = 128; s > 0; s >>= 1) {
        if (t < s) { rc[t] = fmaxf(rc[t], rc[t + s]); rr[t] = fmaxf(rr[t], rr[t + s]); }
        __syncthreads();
    }
    if (t == 0) {
        atomicMax(reinterpret_cast<int*>(&scal[0]), __float_as_int(rc[0]));
        atomicMax(reinterpret_cast<int*>(&scal[1]), __float_as_int(rr[0]));
    }
}

__global__ void pinv_init_kernel(const bf16* __restrict__ x, const float* __restrict__ scal,
                                 bf16* __restrict__ z, bf16* __restrict__ zT)
{
    i64 idx = (i64)blockIdx.x * 256 + threadIdx.x;
    int j = (int)(idx & 255); int i = (int)((idx >> 8) & 255); i64 bh = idx >> 16;
    float inv = 1.f / (scal[0] * scal[1]);
    float xv = cvt(x[idx]) * inv;
    zT[idx] = __float2bfloat16(xv);
    z[(bh << 16) + ((i64)j << 8) + i] = __float2bfloat16(xv);
}

// ============================ depthwise conv residual added onto xn (bf16, 8-wide vectorized) ============================
__global__ __launch_bounds__(256)
void conv_add_kernel(const bf16* __restrict__ qkv, const float* __restrict__ w,
                     bf16* __restrict__ xn)
{
    union U8 { short8 v; bf16 e[8]; };
    i64 idx = (i64)blockIdx.x * 256 + threadIdx.x;
    int cg = (int)(idx & 63);
    i64 bn = idx >> 6;
    int n = (int)(bn & (SEQ - 1));
    int b = (int)(bn >> 14);
    int c = cg * 8;
    int h = c >> 6;

    U8 xin; xin.v = *(const short8*)&xn[(bn << 9) + c];
    float acc[8];
#pragma unroll
    for (int j = 0; j < 8; j++) acc[j] = cvt(xin.e[j]);

    const float* wk = w + h * 33;
    const bf16* vb = qkv + (i64)b * SEQ * Q3 + 2 * DM + c;
#pragma unroll
    for (int t = 0; t < 33; t++) {
        int nn = n + t - 16;
        if (nn >= 0 && nn < SEQ) {
            U8 vv; vv.v = *(const short8*)&vb[(i64)nn * Q3];
            float wt = wk[t];
#pragma unroll
            for (int j = 0; j < 8; j++) acc[j] = fmaf(wt, cvt(vv.e[j]), acc[j]);
        }
    }
    U8 o;
#pragma unroll
    for (int j = 0; j < 8; j++) o.e[j] = __float2bfloat16(acc[j]);
    *(short8*)&xn[(bn << 9) + c] = o.v;
}

// ============================ pooling ============================
__global__ void pool_score_kernel(const float* __restrict__ t, const float* __restrict__ w,
                                  const float* __restrict__ b2, float* __restrict__ s)
{
    int row = blockIdx.x * 4 + (threadIdx.x >> 6);
    int lane = threadIdx.x & 63;
    float acc = t[(i64)row * 128 + lane] * w[lane] + t[(i64)row * 128 + 64 + lane] * w[64 + lane];
    for (int o = 32; o > 0; o >>= 1) acc += __shfl_xor(acc, o);
    if (lane == 0) s[row] = acc + b2[0];
}

__global__ __launch_bounds__(256)
void pool_z_kernel(const float* __restrict__ a, const bf16* __restrict__ h, float* __restrict__ z)
{
    int bb = blockIdx.x >> 7, cg = blockIdx.x & 127;
    int c4 = cg * 4;
    int t = threadIdx.x;
    const float* ab = a + (i64)bb * SEQ;
    const bf16* hb = h + (i64)bb * SEQ * DM;
    float4 acc = {0.f, 0.f, 0.f, 0.f};
    for (int r = t; r < SEQ; r += 256) {
        float av = ab[r];
        float4 hv = ld4(&hb[(i64)r * DM + c4]);
        acc.x += av * hv.x; acc.y += av * hv.y; acc.z += av * hv.z; acc.w += av * hv.w;
    }
    __shared__ float4 red[256];
    red[t] = acc; __syncthreads();
    for (int s = 128; s > 0; s >>= 1) {
        if (t < s) {
            float4 o = red[t + s];
            red[t].x += o.x; red[t].y += o.y; red[t].z += o.z; red[t].w += o.w;
        }
        __syncthreads();
    }
    if (t == 0) *(float4*)&z[bb * DM + c4] = red[0];
}

__global__ void head_kernel(const float* __restrict__ z, const float* __restrict__ w,
                            const float* __restrict__ b, float* __restrict__ out)
{
    int t = threadIdx.x;
    int wv = t >> 6, lane = t & 63;
    int bb = wv >> 1, cls = wv & 1;
    float acc = 0.f;
#pragma unroll
    for (int j = 0; j < 8; j++) { int k = lane * 8 + j; acc += z[bb * DM + k] * w[k * 2 + cls]; }
    for (int o = 32; o > 0; o >>= 1) acc += __shfl_xor(acc, o);
    __shared__ float lg[4];
    if (lane == 0) lg[wv] = acc + b[cls];
    __syncthreads();
    if (t == 0) {
        for (int bi = 0; bi < 2; bi++) {
            float l0 = lg[bi * 2], l1 = lg[bi * 2 + 1];
            out[bi * 2 + 0] = l0; out[bi * 2 + 1] = l1;
            float m = fmaxf(l0, l1);
            float e0 = expf(l0 - m), e1 = expf(l1 - m);
            float inv = 1.f / (e0 + e1);
            out[4 + bi * 2 + 0] = e0 * inv; out[4 + bi * 2 + 1] = e1 * inv;
        }
    }
}

// ============================ host orchestration ============================
extern "C" void kernel_launch(void* const* d_in, const int* in_sizes, int n_in,
                              void* d_out, int out_size, void* d_ws, size_t ws_size,
                              hipStream_t stream)
{
    const float* x      = (const float*)d_in[0];
    const float* fc1_w  = (const float*)d_in[1];
    const float* fc1_b  = (const float*)d_in[2];
    const float* ln1_g  = (const float*)d_in[3];
    const float* ln1_b  = (const float*)d_in[4];
    const float* qkv_w  = (const float*)d_in[5];
    const float* out_w  = (const float*)d_in[6];
    const float* out_b  = (const float*)d_in[7];
    const float* conv_w = (const float*)d_in[8];
    const float* ln2_g  = (const float*)d_in[9];
    const float* ln2_b  = (const float*)d_in[10];
    const float* ff1_w  = (const float*)d_in[11];
    const float* ff1_b  = (const float*)d_in[12];
    const float* ff2_w  = (const float*)d_in[13];
    const float* ff2_b  = (const float*)d_in[14];
    const float* att1_w = (const float*)d_in[15];
    const float* att1_b = (const float*)d_in[16];
    const float* att2_w = (const float*)d_in[17];
    const float* att2_b = (const float*)d_in[18];
    const float* fc2_w  = (const float*)d_in[19];
    const float* fc2_b  = (const float*)d_in[20];
    float* out = (float*)d_out;
    float* ws  = (float*)d_ws;

    // ---- workspace layout (float units), same region sizes as passing round-14 layout ----
    i64 off = 0;
    bf16*  h    = (bf16*)(ws + off); off += (i64)ROWS * DM;      // A: bf16 residual
    bf16*  xn   = (bf16*)(ws + off); off += (i64)ROWS * DM / 2;  // B: bf16 act / attn-out
    bf16*  qkv  = (bf16*)(ws + off); off += (i64)ROWS * Q3 / 2;  // C: bf16 qkv / xb / ffc(+D)
    float* sbuf = ws + off; off += (i64)2 * LMK * SEQ;           // D: wT / vTall / MIL scores / ffc tail
    float* attn2= ws + off; off += 16 * 65536;                   // E: attn2f -> wTf1
    float* zA   = ws + off; off += 16 * 65536;                   // F: attn2b+XZ -> zF -> wTf2
    float* zB   = ws + off; off += 16 * 65536;                   // G┐
    float* xz   = ws + off; off += 16 * 65536;                   // H│ pinv pings | attn3 obuf
    float* wbuf = ws + off; off += 16 * 65536;                   // I│
    float* tbuf = ws + off; off += 16 * 65536;                   // J┘
    float* regK = ws + off; off += 16 * LMK * DH;                // K: q_lb + klb (bf16)
    float* regL = ws + off; off += 16 * LMK * DH;                // L: yTb + wTa (bf16)
    float* a3v  = ws + off; off += 16 * LMK * DH;                // M: a3vTb (bf16)
    float* ybuf = ws + off; off += 16 * LMK * DH;                // N: mbuf + sbuf2
    float* scor = ws + off; off += ROWS;
    float* zpool= ws + off; off += BATCH * DM;
    float* scal = ws + off; off += 16;
    if (ws_size < (size_t)off * sizeof(float)) return;

    bf16*  wT   = (bf16*)sbuf;
    bf16*  xb   = qkv;
    float* attn2f = attn2;
    bf16*  attn2b = (bf16*)zA;                 // F.0
    bf16*  XZ     = (bf16*)(zA + 524288);      // F.1
    bf16*  zG     = (bf16*)zB;
    bf16*  zGT    = (bf16*)(zB + 524288);
    bf16*  zH     = (bf16*)xz;
    bf16*  zHT    = (bf16*)(xz + 524288);
    bf16*  W1     = (bf16*)wbuf;               // I.0
    bf16*  W2     = (bf16*)(wbuf + 524288);    // I.1
    bf16*  zF     = attn2b;
    bf16*  vTall = (bf16*)sbuf;                // [2][8][64][16384] bf16 = D exactly
    float* obuf  = zB;                         // attn3 O partials: G..J exactly
    float* mbuf  = ybuf;
    float* sbuf2 = ybuf + 65536;
    bf16*  a3vTb = (bf16*)a3v;                 // [16][64][256] bf16
    bf16*  q_lb = (bf16*)regK;
    bf16*  klb  = (bf16*)(regK + 131072);
    bf16*  yTb  = (bf16*)regL;
    bf16*  wTa  = (bf16*)(regL + 131072);
    bf16*  wTf1 = (bf16*)attn2;
    bf16*  wTf2 = (bf16*)zA;
    bf16*  ffc  = qkv;

    const i64 sQKVb = (i64)SEQ * Q3;
    const i64 sLMh  = (i64)LMK * DH;

    // fc1 + ReLU via MFMA (h bf16)
    cvt_bf16_kernel<<<(ROWS * 1024 / 4 + 255) / 256, 256, 0, stream>>>(x, xb, (i64)ROWS * 1024);
    transpose_w_kernel<<<dim3(DM / 64, 1024 / 64), 256, 0, stream>>>(fc1_w, wT, 1024, DM);
    ml<4, 2, 1, false>(stream, xb, wT, h, fc1_b, ROWS, DM, 1024, 1024, 1024, DM);

    for (int L = 0; L < 2; L++) {
        const float* qw  = qkv_w + (i64)L * DM * Q3;
        const float* ow  = out_w + (i64)L * DM * DM;
        const float* ob  = out_b + (i64)L * DM;
        const float* cw  = conv_w + (i64)L * NHEAD * 33;
        const float* f1w = ff1_w + (i64)L * DM * FFD;
        const float* f1b = ff1_b + (i64)L * FFD;
        const float* f2w = ff2_w + (i64)L * FFD * DM;
        const float* f2b = ff2_b + (i64)L * DM;

        // LN1 -> xn (bf16); qkv = xn @ qw (MFMA)
        ln_kernel<<<ROWS/4, 256, 0, stream>>>(h, xn, ln1_g + L*DM, ln1_b + L*DM, ROWS);
        transpose_w_kernel<<<dim3(Q3 / 64, DM / 64), 256, 0, stream>>>(qw, wT, DM, Q3);
        ml<4, 2, 0, false>(stream, xn, wT, qkv, nullptr, ROWS, Q3, DM, DM, DM, Q3);

        // landmarks (q and k in one launch)
        landmark_kernel<<<2*16*LMK, 64, 0, stream>>>(qkv, q_lb, klb);

        // attn2 = softmax(0.125 * q_l @ k_l^T) via MFMA -> bf16
        ml<2, 2, 0, false>(stream, q_lb, klb, attn2f, nullptr,
            LMK, LMK, DH, DH, DH, LMK, 0, sLMh, 0, sLMh, 0, 65536, 1, 16, 0.125f);
        softmax256_fb_kernel<<<16*LMK/4, 256, 0, stream>>>(attn2f, attn2b, (i64)16*LMK);

        // pinv (Newton-Schulz, 6 iters, 4 MFMA launches/iter via dual-output epilogue)
        hipMemsetAsync(scal, 0, 2*sizeof(float), stream);
        pinv_sums_kernel<<<16, 256, 0, stream>>>(attn2b, scal);
        pinv_init_kernel<<<16*65536/256, 256, 0, stream>>>(attn2b, scal, zG, zGT);
        {
            bf16 *zp = zG, *zpT = zGT, *zq = zH, *zqT = zHT;
            for (int it = 0; it < 6; it++) {
                bool last = (it == 5);
                mlp2<2, false>(stream, XZ, W1, attn2b, zpT, 1.f, 0.f, 7.f);
                mlp2<0, true >(stream, W2, nullptr, W1, XZ, 1.f, 15.f);
                mlp2<0, true >(stream, W1, nullptr, W2, XZ, 1.f, 13.f);
                if (!last) {
                    mlp2<1, false>(stream, zq, zqT, zp, W1, 0.25f);
                    bf16* t1 = zp; zp = zq; zq = t1;
                    bf16* t2 = zpT; zpT = zqT; zqT = t2;
                } else {
                    mlp2<0, false>(stream, zF, nullptr, zp, W1, 0.25f);
                }
            }
        }
        // final pinv z at zF. D and G..J free now.

        // attn3: batched vT -> fused flash split-KV -> combine (writes a3v^T bf16)
        t64_kernel<<<dim3(SEQ/64, BATCH*NHEAD), 256, 0, stream>>>(
            qkv + 2*DM, vTall, Q3, SEQ,
            sQKVb, (i64)DH, (i64)NHEAD*DH*SEQ, (i64)DH*SEQ, NHEAD);
        attn3_fused_kernel<<<dim3(16, 16), 256, 0, stream>>>(qkv, q_lb, vTall, obuf, mbuf, sbuf2);
        attn3_combine_kernel<<<16*LMK/4, 256, 0, stream>>>(obuf, mbuf, sbuf2, a3vTb);

        // yT = a3v^T @ z^T  (one MFMA launch -> yTb bf16)
        ml<2, 4, 0, false>(stream, a3vTb, zF, yTb, nullptr,
            DH, LMK, LMK, LMK, LMK, LMK, 0, (i64)DH*LMK, 0, 65536, 0, (i64)DH*LMK, 1, 16, 1.f);

        // attn1: fused QK + softmax + PV, all heads, one launch -> xn
        attn1_fused_kernel<<<dim3(ROWS/128, NHEAD), 256, 0, stream>>>(qkv, klb, yTb, xn);

        // xn += depthwise conv(v); h += xn @ out_w + out_b (MFMA, bf16 resid)
        conv_add_kernel<<<(i64)ROWS*64/256, 256, 0, stream>>>(qkv, cw, xn);
        transpose_w_kernel<<<dim3(DM / 64, DM / 64), 256, 0, stream>>>(ow, wT, DM, DM);
        ml<4, 2, 0, true>(stream, xn, wT, h, ob, ROWS, DM, DM, DM, DM, DM);

        // FF block (MFMA; single pass, ffc spans C+D)
        ln_kernel<<<ROWS/4, 256, 0, stream>>>(h, xn, ln2_g + L*DM, ln2_b + L*DM, ROWS);
        transpose_w_kernel<<<dim3(FFD / 64, DM / 64), 256, 0, stream>>>(f1w, wTf1, DM, FFD);
        transpose_w_kernel<<<dim3(DM / 64, FFD / 64), 256, 0, stream>>>(f2w, wTf2, FFD, DM);
        ml<4, 2, 2, false>(stream, xn, wTf1, ffc, f1b, ROWS, FFD, DM, DM, DM, FFD);
        ml<4, 2, 0, true >(stream, ffc, wTf2, h, f2b, ROWS, DM, FFD, FFD, FFD, DM);
    }

    // gated-attention MIL pooling: tanh(h @ att1_w + b) via MFMA (h bf16)
    transpose_w_kernel<<<dim3(128 / 64, DM / 64), 256, 0, stream>>>(att1_w, wTa, DM, 128);
    ml<4, 2, 3, false>(stream, h, wTa, sbuf, att1_b, ROWS, 128, DM, DM, DM, 128);
    pool_score_kernel<<<ROWS/4, 256, 0, stream>>>(sbuf, att2_w, att2_b, scor);
    softmax_big_kernel<<<BATCH, 256, 0, stream>>>(scor, out + 8);
    pool_z_kernel<<<BATCH * 128, 256, 0, stream>>>(out + 8, h, zpool);
    head_kernel<<<1, 256, 0, stream>>>(zpool, fc2_w, fc2_b, out);
}

// Round 16
// 1852.042 us; speedup vs baseline: 32.4235x; 1.0523x over previous
//
#include <hip/hip_runtime.h>
#include <hip/hip_bf16.h>

typedef long long i64;
typedef __hip_bfloat16 bf16;
using short8 = __attribute__((ext_vector_type(8))) short;
using f32x4  = __attribute__((ext_vector_type(4))) float;

#define SEQ    16384
#define DM     512
#define NHEAD  8
#define DH     64
#define LMK    256
#define LSUB   64      // SEQ / LMK
#define Q3     1536
#define FFD    2048
#define BATCH  2
#define ROWS   (BATCH * SEQ)

__device__ __forceinline__ float cvt(float v) { return v; }
__device__ __forceinline__ float cvt(bf16 v) { return __bfloat162float(v); }
__device__ __forceinline__ void stc(float* p, float v) { *p = v; }
__device__ __forceinline__ void stc(bf16* p, float v) { *p = __float2bfloat16(v); }

__device__ __forceinline__ float4 ld4(const float* p) { return *(const float4*)p; }
__device__ __forceinline__ float4 ld4(const bf16* p) {
    union { short s[4]; } u; *(int2*)u.s = *(const int2*)p;
    float4 v;
    v.x = cvt(((const bf16*)u.s)[0]); v.y = cvt(((const bf16*)u.s)[1]);
    v.z = cvt(((const bf16*)u.s)[2]); v.w = cvt(((const bf16*)u.s)[3]);
    return v;
}
__device__ __forceinline__ void ld8f(const bf16* p, float* d) {
    union { short8 v; bf16 e[8]; } u;
    u.v = *(const short8*)p;
#pragma unroll
    for (int j = 0; j < 8; j++) d[j] = cvt(u.e[j]);
}

// fast GELU (tanh form, hw exp+rcp): gelu(v) ~= v * e / (e + 1), e = exp(2a(v + b v^3))
__device__ __forceinline__ float gelu_fast(float v) {
    float u = v * (1.5957691216057308f + 0.07135370154f * v * v);
    float e = __expf(fminf(u, 80.f));
    return v * e * __builtin_amdgcn_rcpf(e + 1.f);
}
// exact tanh via hw exp+rcp
__device__ __forceinline__ float tanh_fast(float v) {
    float e = __expf(fminf(2.f * v, 80.f));
    return 1.f - 2.f * __builtin_amdgcn_rcpf(e + 1.f);
}

#define LDS_U32(p) ((__attribute__((address_space(3))) uint32_t*)(p))
#define GLB_U32(p) ((const __attribute__((address_space(1))) uint32_t*)(p))

// ============================ MFMA bf16 GEMM (batched strides, swizzled global_load_lds staging) ============================
// XCD-aware bijective block remap. DSUB: C = diag(beta) - alpha*A@Bt^T (primary).
// TMODE: 0 none; 1 also write Ct[n][m] = v; 2 also write Ct[n][m] = (m==n?betaT:0) - v.
template<int FM, int FN, int ACT, bool RESID, bool DSUB, int TMODE, typename TC>
__global__ __launch_bounds__(256)
void mfma_gemm_kernel(const bf16* __restrict__ Abase, const bf16* __restrict__ Btbase,
                      TC* __restrict__ Cbase, bf16* __restrict__ Ctbase,
                      const float* __restrict__ bias,
                      int M, int N, int K, int lda, int ldb, int ldc,
                      i64 sAb, i64 sAh, i64 sBb, i64 sBh, i64 sCb, i64 sCh,
                      int nh, float alpha, float beta, float betaT)
{
    constexpr int BM = FM * 32;
    constexpr int BN = FN * 32;
    constexpr int ASL = BM / 8;          // A slabs (8 rows each)
    constexpr int NSL = (BM + BN) / 8;   // total slabs
    constexpr int NIT = NSL / 4;         // per-wave slab iterations (compile-time)
    __shared__ bf16 Al[BM][64];
    __shared__ bf16 Bl[BN][64];

    int nwg  = gridDim.x * gridDim.y * gridDim.z;
    int orig = (blockIdx.z * gridDim.y + blockIdx.y) * gridDim.x + blockIdx.x;
    int qq = nwg >> 3, rr = nwg & 7;
    int xcd = orig & 7, loc = orig >> 3;
    int wid = (xcd < rr ? xcd * (qq + 1) : rr * (qq + 1) + (xcd - rr) * qq) + loc;
    int bx = wid % gridDim.x;
    int t1 = wid / gridDim.x;
    int by = t1 % gridDim.y;
    int bz = t1 / gridDim.y;

    int bb = bz / nh, hh = bz % nh;
    const bf16* A  = Abase  + bb * sAb + hh * sAh;
    const bf16* Bt = Btbase + bb * sBb + hh * sBh;
    TC*         C  = Cbase  + bb * sCb + hh * sCh;
    bf16* Ct = nullptr;
    if (TMODE) Ct = Ctbase + bb * sCb + hh * sCh;

    int tid = threadIdx.x;
    int wave = tid >> 6, lane = tid & 63;
    int wm = (wave >> 1) * (FM * 16), wn = (wave & 1) * (FN * 16);
    int m0 = by * BM, n0 = bx * BN;
    int lr = lane & 15, lq = lane >> 4;
    int srow = lane >> 3;
    int scol = ((lane & 7) ^ srow) * 8;

    // hoist per-slab global source pointers and LDS destinations
    const bf16* gsrc[NIT];
    uint32_t* ldst[NIT];
#pragma unroll
    for (int s = 0; s < NIT; s++) {
        int op = wave + s * 4;
        if (op < ASL) {
            gsrc[s] = A + (i64)(m0 + op * 8 + srow) * lda + scol;
            ldst[s] = (uint32_t*)&Al[op * 8][0];
        } else {
            int o2 = op - ASL;
            gsrc[s] = Bt + (i64)(n0 + o2 * 8 + srow) * ldb + scol;
            ldst[s] = (uint32_t*)&Bl[o2 * 8][0];
        }
    }

    f32x4 acc[FM][FN];
#pragma unroll
    for (int i = 0; i < FM; i++)
#pragma unroll
        for (int j = 0; j < FN; j++) acc[i][j] = (f32x4){0.f, 0.f, 0.f, 0.f};

    int c0 = (lq ^ (lr & 7)) * 8;
    int c1 = ((4 | lq) ^ (lr & 7)) * 8;

    for (int k0 = 0; k0 < K; k0 += 64) {
#pragma unroll
        for (int s = 0; s < NIT; s++)
            __builtin_amdgcn_global_load_lds(GLB_U32(gsrc[s] + k0),
                (__attribute__((address_space(3))) uint32_t*)ldst[s], 16, 0, 0);
        __syncthreads();
        {
            short8 af[FM], bfr[FN];
#pragma unroll
            for (int i = 0; i < FM; i++) af[i]  = *(const short8*)&Al[wm + i * 16 + lr][c0];
#pragma unroll
            for (int j = 0; j < FN; j++) bfr[j] = *(const short8*)&Bl[wn + j * 16 + lr][c0];
#pragma unroll
            for (int i = 0; i < FM; i++)
#pragma unroll
                for (int j = 0; j < FN; j++)
                    acc[i][j] = __builtin_amdgcn_mfma_f32_16x16x32_bf16(af[i], bfr[j], acc[i][j], 0, 0, 0);
        }
        {
            short8 af[FM], bfr[FN];
#pragma unroll
            for (int i = 0; i < FM; i++) af[i]  = *(const short8*)&Al[wm + i * 16 + lr][c1];
#pragma unroll
            for (int j = 0; j < FN; j++) bfr[j] = *(const short8*)&Bl[wn + j * 16 + lr][c1];
#pragma unroll
            for (int i = 0; i < FM; i++)
#pragma unroll
                for (int j = 0; j < FN; j++)
                    acc[i][j] = __builtin_amdgcn_mfma_f32_16x16x32_bf16(af[i], bfr[j], acc[i][j], 0, 0, 0);
        }
        __syncthreads();
    }

#pragma unroll
    for (int i = 0; i < FM; i++)
#pragma unroll
        for (int r = 0; r < 4; r++) {
            int m = m0 + wm + i * 16 + lq * 4 + r;
            TC* crow = C + (i64)m * ldc;
#pragma unroll
            for (int j = 0; j < FN; j++) {
                int n = n0 + wn + j * 16 + lr;
                float v = acc[i][j][r] * alpha;
                if (DSUB) v = ((m == n) ? beta : 0.f) - v;
                if (bias) v += bias[n];
                if (ACT == 1) v = fmaxf(v, 0.f);
                else if (ACT == 2) v = gelu_fast(v);
                else if (ACT == 3) v = tanh_fast(v);
                if (RESID) v += cvt(crow[n]);
                stc(&crow[n], v);
                if (TMODE == 1) Ct[(i64)n * ldc + m] = __float2bfloat16(v);
                else if (TMODE == 2) Ct[(i64)n * ldc + m] = __float2bfloat16(((m == n) ? betaT : 0.f) - v);
            }
        }
}

template<int FM, int FN, int ACT, bool RES, typename TC>
static inline void ml(hipStream_t st, const bf16* A, const bf16* Bt, TC* C, const float* bias,
                      int M, int N, int K, int lda, int ldb, int ldc,
                      i64 sAb = 0, i64 sAh = 0, i64 sBb = 0, i64 sBh = 0, i64 sCb = 0, i64 sCh = 0,
                      int nb = 1, int nh = 1, float alpha = 1.f)
{
    dim3 g(N / (FN * 32), M / (FM * 32), nb * nh);
    mfma_gemm_kernel<FM, FN, ACT, RES, false, 0, TC><<<g, 256, 0, st>>>(
        A, Bt, C, nullptr, bias, M, N, K, lda, ldb, ldc, sAb, sAh, sBb, sBh, sCb, sCh, nh, alpha, 0.f, 0.f);
}

// pinv MFMA helper: 256x256x256, 16 batches, bf16 out
template<int TMODE, bool DSUB>
static inline void mlp2(hipStream_t st, bf16* C, bf16* Ct, const bf16* A, const bf16* Bt,
                        float alpha, float beta = 0.f, float betaT = 0.f)
{
    dim3 g(4, 4, 16);
    mfma_gemm_kernel<2, 2, 0, false, DSUB, TMODE, bf16><<<g, 256, 0, st>>>(
        A, Bt, C, Ct, nullptr, 256, 256, 256, 256, 256, 256,
        0, 65536, 0, 65536, 0, 65536, 16, alpha, beta, betaT);
}

// ============================ fused attn3 (flash-style split-KV) ============================
__global__ __launch_bounds__(256)
void attn3_fused_kernel(const bf16* __restrict__ qkv, const bf16* __restrict__ q_lb,
                        const bf16* __restrict__ vTall,
                        float* __restrict__ obuf, float* __restrict__ mbuf,
                        float* __restrict__ sbuf2)
{
    __shared__ bf16 qs[256][64];
    __shared__ bf16 ks[64][64];
    __shared__ bf16 vs[64][64];
    __shared__ bf16 Ps[4][64][64];

    int ch = blockIdx.x, bh = blockIdx.y;
    int b = bh >> 3, hh = bh & 7;
    const bf16* qg = q_lb + (i64)bh * (LMK * DH);
    const bf16* kg = qkv + (i64)b * SEQ * Q3 + DM + hh * DH;
    const bf16* vg = vTall + ((i64)b * NHEAD + hh) * ((i64)DH * SEQ);

    int tid = threadIdx.x;
    int wave = tid >> 6, lane = tid & 63;
    int lr = lane & 15, lq = lane >> 4;
    int srow = lane >> 3;
    int scol = ((lane & 7) ^ srow) * 8;
    int c0 = (lq ^ (lr & 7)) * 8;
    int c1 = ((4 | lq) ^ (lr & 7)) * 8;
    int qb = wave * 64;

    for (int sl = wave; sl < 32; sl += 4)
        __builtin_amdgcn_global_load_lds(GLB_U32(qg + (i64)(sl * 8 + srow) * 64 + scol),
                                         LDS_U32(&qs[sl * 8][0]), 16, 0, 0);

    f32x4 O[4][4];
    float m[4][4], s[4][4];
#pragma unroll
    for (int i = 0; i < 4; i++)
#pragma unroll
        for (int r = 0; r < 4; r++) { m[i][r] = -3.0e38f; s[i][r] = 0.f; }
#pragma unroll
    for (int i = 0; i < 4; i++)
#pragma unroll
        for (int j = 0; j < 4; j++) O[i][j] = (f32x4){0.f, 0.f, 0.f, 0.f};

    int k0g = ch * 1024;
    for (int t = 0; t < 16; t++) {
        int kk0 = k0g + t * 64;
        for (int sl = wave; sl < 8; sl += 4)
            __builtin_amdgcn_global_load_lds(GLB_U32(kg + (i64)(kk0 + sl * 8 + srow) * Q3 + scol),
                                             LDS_U32(&ks[sl * 8][0]), 16, 0, 0);
        for (int sl = wave; sl < 8; sl += 4)
            __builtin_amdgcn_global_load_lds(GLB_U32(vg + (i64)(sl * 8 + srow) * SEQ + kk0 + scol),
                                             LDS_U32(&vs[sl * 8][0]), 16, 0, 0);
        __syncthreads();

        f32x4 S[4][4];
#pragma unroll
        for (int i = 0; i < 4; i++)
#pragma unroll
            for (int j = 0; j < 4; j++) S[i][j] = (f32x4){0.f, 0.f, 0.f, 0.f};
        {
            short8 af[4], bk[4];
#pragma unroll
            for (int i = 0; i < 4; i++) af[i] = *(const short8*)&qs[qb + i * 16 + lr][c0];
#pragma unroll
            for (int j = 0; j < 4; j++) bk[j] = *(const short8*)&ks[j * 16 + lr][c0];
#pragma unroll
            for (int i = 0; i < 4; i++)
#pragma unroll
                for (int j = 0; j < 4; j++)
                    S[i][j] = __builtin_amdgcn_mfma_f32_16x16x32_bf16(af[i], bk[j], S[i][j], 0, 0, 0);
#pragma unroll
            for (int i = 0; i < 4; i++) af[i] = *(const short8*)&qs[qb + i * 16 + lr][c1];
#pragma unroll
            for (int j = 0; j < 4; j++) bk[j] = *(const short8*)&ks[j * 16 + lr][c1];
#pragma unroll
            for (int i = 0; i < 4; i++)
#pragma unroll
                for (int j = 0; j < 4; j++)
                    S[i][j] = __builtin_amdgcn_mfma_f32_16x16x32_bf16(af[i], bk[j], S[i][j], 0, 0, 0);
        }

#pragma unroll
        for (int i = 0; i < 4; i++)
#pragma unroll
            for (int r = 0; r < 4; r++) {
                float tm = -3.0e38f;
#pragma unroll
                for (int j = 0; j < 4; j++) {
                    S[i][j][r] *= 0.125f;
                    tm = fmaxf(tm, S[i][j][r]);
                }
                tm = fmaxf(tm, __shfl_xor(tm, 1)); tm = fmaxf(tm, __shfl_xor(tm, 2));
                tm = fmaxf(tm, __shfl_xor(tm, 4)); tm = fmaxf(tm, __shfl_xor(tm, 8));
                float mn = fmaxf(m[i][r], tm);
                float f = expf(m[i][r] - mn);
                float ss = 0.f;
#pragma unroll
                for (int j = 0; j < 4; j++) {
                    float e = expf(S[i][j][r] - mn);
                    S[i][j][r] = e;
                    ss += e;
                }
                ss += __shfl_xor(ss, 1); ss += __shfl_xor(ss, 2);
                ss += __shfl_xor(ss, 4); ss += __shfl_xor(ss, 8);
                s[i][r] = s[i][r] * f + ss;
                m[i][r] = mn;
#pragma unroll
                for (int j2 = 0; j2 < 4; j2++) O[i][j2][r] *= f;
            }

#pragma unroll
        for (int i = 0; i < 4; i++)
#pragma unroll
            for (int j = 0; j < 4; j++)
#pragma unroll
                for (int r = 0; r < 4; r++) {
                    int row = i * 16 + lq * 4 + r;
                    int col = j * 16 + lr;
                    Ps[wave][row][(((col >> 3) ^ (row & 7)) << 3) | (col & 7)] =
                        __float2bfloat16(S[i][j][r]);
                }
        __syncthreads();

        {
            short8 a2[4], b2[4];
#pragma unroll
            for (int i = 0; i < 4; i++) a2[i] = *(const short8*)&Ps[wave][i * 16 + lr][c0];
#pragma unroll
            for (int j = 0; j < 4; j++) b2[j] = *(const short8*)&vs[j * 16 + lr][c0];
#pragma unroll
            for (int i = 0; i < 4; i++)
#pragma unroll
                for (int j = 0; j < 4; j++)
                    O[i][j] = __builtin_amdgcn_mfma_f32_16x16x32_bf16(a2[i], b2[j], O[i][j], 0, 0, 0);
#pragma unroll
            for (int i = 0; i < 4; i++) a2[i] = *(const short8*)&Ps[wave][i * 16 + lr][c1];
#pragma unroll
            for (int j = 0; j < 4; j++) b2[j] = *(const short8*)&vs[j * 16 + lr][c1];
#pragma unroll
            for (int i = 0; i < 4; i++)
#pragma unroll
                for (int j = 0; j < 4; j++)
                    O[i][j] = __builtin_amdgcn_mfma_f32_16x16x32_bf16(a2[i], b2[j], O[i][j], 0, 0, 0);
        }
        __syncthreads();
    }

    i64 base = (i64)(bh * 16 + ch) * 256 * 64;
#pragma unroll
    for (int i = 0; i < 4; i++)
#pragma unroll
        for (int j2 = 0; j2 < 4; j2++)
#pragma unroll
            for (int r = 0; r < 4; r++) {
                int row = qb + i * 16 + lq * 4 + r;
                int d = j2 * 16 + lr;
                obuf[base + (i64)row * 64 + d] = O[i][j2][r];
            }
    if (lr == 0) {
#pragma unroll
        for (int i = 0; i < 4; i++)
#pragma unroll
            for (int r = 0; r < 4; r++) {
                int idx = (bh * 16 + ch) * 256 + qb + i * 16 + lq * 4 + r;
                mbuf[idx] = m[i][r];
                sbuf2[idx] = s[i][r];
            }
    }
}

// combine split-KV partials -> a3v^T (bf16, [bh][d][row]) for the yT MFMA
__global__ __launch_bounds__(256)
void attn3_combine_kernel(const float* __restrict__ obuf, const float* __restrict__ mbuf,
                          const float* __restrict__ sbuf2, bf16* __restrict__ a3vT)
{
    int gid = blockIdx.x * 4 + (threadIdx.x >> 6);   // 4096 rows
    int lane = threadIdx.x & 63;
    int bh = gid >> 8, row = gid & 255;
    float mv[16];
    float M = -3.0e38f;
#pragma unroll
    for (int c = 0; c < 16; c++) {
        mv[c] = mbuf[(bh * 16 + c) * 256 + row];
        M = fmaxf(M, mv[c]);
    }
    float denom = 0.f, w[16];
#pragma unroll
    for (int c = 0; c < 16; c++) {
        w[c] = expf(mv[c] - M);
        denom += sbuf2[(bh * 16 + c) * 256 + row] * w[c];
    }
    float acc = 0.f;
#pragma unroll
    for (int c = 0; c < 16; c++)
        acc += obuf[((i64)(bh * 16 + c) * 256 + row) * 64 + lane] * w[c];
    a3vT[(i64)bh * (DH * LMK) + lane * 256 + row] = __float2bfloat16(acc / denom);
}

// ============================ fused attn1 (QBLK=64): S=q@klb^T -> softmax(256) -> @y^T -> xn ============================
// grid (ROWS/64, NHEAD). LDS: stage 40KB (qs 8 + ks 32; yts 32 aliases) + Ps 32KB + red 1KB = 73KB -> 2 blocks/CU.
__global__ __launch_bounds__(256)
void attn1_fused_kernel(const bf16* __restrict__ qkv, const bf16* __restrict__ klb_all,
                        const bf16* __restrict__ yTb_all, bf16* __restrict__ xn)
{
    __shared__ bf16 stage[20480];          // qs=stage[0..4095] (64x64), ks=stage[4096..] (256x64)
    __shared__ bf16 Ps[64][256];
    __shared__ float maxb[2][64];
    __shared__ float sumb[2][64];
    bf16 (*qs)[64]  = (bf16(*)[64])&stage[0];
    bf16 (*ks)[64]  = (bf16(*)[64])&stage[4096];
    bf16 (*yts)[256]= (bf16(*)[256])&stage[0];   // 16384 elems, aliases dead q/k after QK

    int hh = blockIdx.y;
    i64 g0 = (i64)blockIdx.x * 64;
    int b  = (int)(g0 >> 14);
    const bf16* qg = qkv + (i64)b * SEQ * Q3 + (g0 & (SEQ - 1)) * Q3 + hh * DH;
    const bf16* kg = klb_all + (i64)(b * NHEAD + hh) * (LMK * DH);
    const bf16* yg = yTb_all + (i64)(b * NHEAD + hh) * (DH * LMK);

    int tid = threadIdx.x;
    int wave = tid >> 6, lane = tid & 63;
    int lr = lane & 15, lq = lane >> 4;
    int srow = lane >> 3;
    int scol = ((lane & 7) ^ srow) * 8;

    for (int sl = wave; sl < 8; sl += 4)
        __builtin_amdgcn_global_load_lds(GLB_U32(qg + (i64)(sl * 8 + srow) * Q3 + scol),
                                         LDS_U32(&qs[sl * 8][0]), 16, 0, 0);
    for (int sl = wave; sl < 32; sl += 4)
        __builtin_amdgcn_global_load_lds(GLB_U32(kg + (i64)(sl * 8 + srow) * 64 + scol),
                                         LDS_U32(&ks[sl * 8][0]), 16, 0, 0);
    __syncthreads();

    int wm = (wave >> 1) * 32, wn = (wave & 1) * 128;
    f32x4 acc[2][8];
#pragma unroll
    for (int i = 0; i < 2; i++)
#pragma unroll
        for (int j = 0; j < 8; j++) acc[i][j] = (f32x4){0.f, 0.f, 0.f, 0.f};

    int c0 = (lq ^ (lr & 7)) * 8;
    int c1 = ((4 | lq) ^ (lr & 7)) * 8;
    {
        short8 af[2], bfr[8];
#pragma unroll
        for (int i = 0; i < 2; i++) af[i]  = *(const short8*)&qs[wm + i * 16 + lr][c0];
#pragma unroll
        for (int j = 0; j < 8; j++) bfr[j] = *(const short8*)&ks[wn + j * 16 + lr][c0];
#pragma unroll
        for (int i = 0; i < 2; i++)
#pragma unroll
            for (int j = 0; j < 8; j++)
                acc[i][j] = __builtin_amdgcn_mfma_f32_16x16x32_bf16(af[i], bfr[j], acc[i][j], 0, 0, 0);
    }
    {
        short8 af[2], bfr[8];
#pragma unroll
        for (int i = 0; i < 2; i++) af[i]  = *(const short8*)&qs[wm + i * 16 + lr][c1];
#pragma unroll
        for (int j = 0; j < 8; j++) bfr[j] = *(const short8*)&ks[wn + j * 16 + lr][c1];
#pragma unroll
        for (int i = 0; i < 2; i++)
#pragma unroll
            for (int j = 0; j < 8; j++)
                acc[i][j] = __builtin_amdgcn_mfma_f32_16x16x32_bf16(af[i], bfr[j], acc[i][j], 0, 0, 0);
    }

#pragma unroll
    for (int i = 0; i < 2; i++)
#pragma unroll
        for (int j = 0; j < 8; j++)
#pragma unroll
            for (int r = 0; r < 4; r++) acc[i][j][r] *= 0.125f;
#pragma unroll
    for (int i = 0; i < 2; i++)
#pragma unroll
        for (int r = 0; r < 4; r++) {
            float m = acc[i][0][r];
#pragma unroll
            for (int j = 1; j < 8; j++) m = fmaxf(m, acc[i][j][r]);
            m = fmaxf(m, __shfl_xor(m, 1)); m = fmaxf(m, __shfl_xor(m, 2));
            m = fmaxf(m, __shfl_xor(m, 4)); m = fmaxf(m, __shfl_xor(m, 8));
            if (lr == 0) maxb[wave & 1][wm + i * 16 + lq * 4 + r] = m;
        }
    __syncthreads();

    // stage yts (32 slabs of 2 rows, ld=256) into the dead q/k region
    {
        int r2 = lane >> 5, c32 = lane & 31;
        for (int sl = wave; sl < 32; sl += 4) {
            int row = sl * 2 + r2;
            const bf16* g = yg + (i64)row * 256 + ((c32 ^ (row & 7)) * 8);
            __builtin_amdgcn_global_load_lds(GLB_U32(g), LDS_U32(&yts[sl * 2][0]), 16, 0, 0);
        }
    }

#pragma unroll
    for (int i = 0; i < 2; i++)
#pragma unroll
        for (int r = 0; r < 4; r++) {
            int row = wm + i * 16 + lq * 4 + r;
            float fm = fmaxf(maxb[0][row], maxb[1][row]);
            float ss = 0.f;
#pragma unroll
            for (int j = 0; j < 8; j++) {
                float e = expf(acc[i][j][r] - fm);
                acc[i][j][r] = e;
                ss += e;
            }
            ss += __shfl_xor(ss, 1); ss += __shfl_xor(ss, 2);
            ss += __shfl_xor(ss, 4); ss += __shfl_xor(ss, 8);
            if (lr == 0) sumb[wave & 1][row] = ss;
        }
#pragma unroll
    for (int i = 0; i < 2; i++)
#pragma unroll
        for (int j = 0; j < 8; j++)
#pragma unroll
            for (int r = 0; r < 4; r++) {
                int row = wm + i * 16 + lq * 4 + r;
                int col = wn + j * 16 + lr;
                Ps[row][(((col >> 3) ^ (row & 7)) << 3) | (col & 7)] = __float2bfloat16(acc[i][j][r]);
            }
    __syncthreads();

    float s[2][4];
#pragma unroll
    for (int i = 0; i < 2; i++)
#pragma unroll
        for (int r = 0; r < 4; r++) {
            int row = wm + i * 16 + lq * 4 + r;
            s[i][r] = sumb[0][row] + sumb[1][row];
        }

    // PV: P[64][256] @ y[256][64]; per wave 32x32 tile
    int wn2 = (wave & 1) * 32;
    f32x4 acc2[2][2];
#pragma unroll
    for (int i = 0; i < 2; i++)
#pragma unroll
        for (int j = 0; j < 2; j++) acc2[i][j] = (f32x4){0.f, 0.f, 0.f, 0.f};
#pragma unroll
    for (int kk = 0; kk < 8; kk++) {
        int cc = ((kk * 4 + lq) ^ (lr & 7)) * 8;
        short8 a2[2], b2[2];
#pragma unroll
        for (int i = 0; i < 2; i++) a2[i] = *(const short8*)&Ps[wm + i * 16 + lr][cc];
#pragma unroll
        for (int j = 0; j < 2; j++) b2[j] = *(const short8*)&yts[wn2 + j * 16 + lr][cc];
#pragma unroll
        for (int i = 0; i < 2; i++)
#pragma unroll
            for (int j = 0; j < 2; j++)
                acc2[i][j] = __builtin_amdgcn_mfma_f32_16x16x32_bf16(a2[i], b2[j], acc2[i][j], 0, 0, 0);
    }

#pragma unroll
    for (int i = 0; i < 2; i++)
#pragma unroll
        for (int j = 0; j < 2; j++)
#pragma unroll
            for (int r = 0; r < 4; r++) {
                int row = wm + i * 16 + lq * 4 + r;
                int d = wn2 + j * 16 + lr;
                xn[(g0 + row) * DM + hh * DH + d] = __float2bfloat16(acc2[i][j][r] / s[i][r]);
            }
}

// ===================== weight transpose+convert: fp32 [K][N] -> bf16 [N][K] =====================
__global__ __launch_bounds__(256)
void transpose_w_kernel(const float* __restrict__ in, bf16* __restrict__ out, int K, int N)
{
    __shared__ float t[64][65];
    int k0 = blockIdx.y * 64, n0 = blockIdx.x * 64;
    int c = threadIdx.x & 63, r4 = threadIdx.x >> 6;
#pragma unroll
    for (int p = 0; p < 64; p += 4)
        t[p + r4][c] = in[(i64)(k0 + p + r4) * N + n0 + c];
    __syncthreads();
#pragma unroll
    for (int p = 0; p < 64; p += 4)
        out[(i64)(n0 + p + r4) * K + k0 + c] = __float2bfloat16(t[c][p + r4]);
}

// ===================== generic 64-col transpose -> bf16 (batched over b,h) =====================
__global__ __launch_bounds__(256)
void t64_kernel(const bf16* __restrict__ in, bf16* __restrict__ out, int ldin, int ldout,
                i64 sIb, i64 sIh, i64 sOb, i64 sOh, int nh)
{
    __shared__ bf16 t[64][72];
    int zz = blockIdx.y;
    int bb = zz / nh, hh = zz % nh;
    const bf16* ip = in + bb * sIb + hh * sIh;
    bf16* op = out + bb * sOb + hh * sOh;
    int r0 = blockIdx.x * 64;
    int c = threadIdx.x & 63, r4 = threadIdx.x >> 6;
#pragma unroll
    for (int p = 0; p < 64; p += 4)
        t[p + r4][c] = ip[(i64)(r0 + p + r4) * ldin + c];
    __syncthreads();
#pragma unroll
    for (int p = 0; p < 64; p += 4)
        op[(i64)(p + r4) * ldout + r0 + c] = t[c][p + r4];
}

// ===================== fp32 -> bf16 convert =====================
__global__ void cvt_bf16_kernel(const float* __restrict__ in, bf16* __restrict__ out, i64 n)
{
    i64 i = ((i64)blockIdx.x * 256 + threadIdx.x) * 4;
    if (i >= n) return;
    float4 v = *(const float4*)&in[i];
    out[i + 0] = __float2bfloat16(v.x);
    out[i + 1] = __float2bfloat16(v.y);
    out[i + 2] = __float2bfloat16(v.z);
    out[i + 3] = __float2bfloat16(v.w);
}

// ============================ LayerNorm (rows of 512), bf16 in -> bf16 out ============================
__global__ __launch_bounds__(256)
void ln_kernel(const bf16* __restrict__ in, bf16* __restrict__ out,
               const float* __restrict__ g, const float* __restrict__ b, int nrows)
{
    int row = blockIdx.x * 4 + (threadIdx.x >> 6);
    int lane = threadIdx.x & 63;
    if (row >= nrows) return;
    const bf16* x = in + (i64)row * DM;
    float vv[8];
    ld8f(&x[lane * 8], vv);
    float s = 0.f;
#pragma unroll
    for (int j = 0; j < 8; j++) s += vv[j];
    for (int o = 32; o > 0; o >>= 1) s += __shfl_xor(s, o);
    float mu = s * (1.f / DM);
    float dd[8];
#pragma unroll
    for (int j = 0; j < 8; j++) dd[j] = vv[j] - mu;
    float vs = 0.f;
#pragma unroll
    for (int j = 0; j < 8; j++) vs += dd[j] * dd[j];
    for (int o = 32; o > 0; o >>= 1) vs += __shfl_xor(vs, o);
    float rstd = rsqrtf(vs * (1.f / DM) + 1e-5f);
    int c = lane * 8;
    bf16* y = out + (i64)row * DM;
#pragma unroll
    for (int j = 0; j < 8; j++)
        y[c + j] = __float2bfloat16(dd[j] * rstd * g[c + j] + b[c + j]);
}

// ============================ landmark means (q and k in one launch) ============================
__global__ void landmark_kernel(const bf16* __restrict__ qkv, bf16* __restrict__ q_lb,
                                bf16* __restrict__ klb)
{
    int blk = blockIdx.x;               // [0, 2*16*LMK)
    int which = blk >> 12;              // 0 = q, 1 = k
    int blk2 = blk & 4095;
    int im = blk2 & (LMK - 1);
    int bh = blk2 >> 8;
    int b = bh >> 3, h = bh & 7;
    int d = threadIdx.x;
    int off = which ? DM : 0;
    const bf16* p = qkv + (i64)(b * SEQ + im * LSUB) * Q3 + off + h * DH + d;
    float s = 0.f;
    for (int il = 0; il < LSUB; il++) s += cvt(p[(i64)il * Q3]);
    bf16* out = which ? klb : q_lb;
    out[((i64)bh * LMK + im) * DH + d] = __float2bfloat16(s * (1.f / LSUB));
}

// ============================ softmax rows of 256, fp32 -> bf16 ============================
__global__ __launch_bounds__(256)
void softmax256_fb_kernel(const float* __restrict__ in, bf16* __restrict__ out, i64 nrows)
{
    i64 row = (i64)blockIdx.x * 4 + (threadIdx.x >> 6);
    int lane = threadIdx.x & 63;
    if (row >= nrows) return;
    const float* p = in + row * 256;
    float4 v = *(const float4*)&p[lane * 4];
    float mx = fmaxf(fmaxf(v.x, v.y), fmaxf(v.z, v.w));
    for (int o = 32; o > 0; o >>= 1) mx = fmaxf(mx, __shfl_xor(mx, o));
    v.x = expf(v.x - mx); v.y = expf(v.y - mx);
    v.z = expf(v.z - mx); v.w = expf(v.w - mx);
    float s = v.x + v.y + v.z + v.w;
    for (int o = 32; o > 0; o >>= 1) s += __shfl_xor(s, o);
    float inv = 1.f / s;
    bf16* q = out + row * 256;
    q[lane * 4 + 0] = __float2bfloat16(v.x * inv);
    q[lane * 4 + 1] = __float2bfloat16(v.y * inv);
    q[lane * 4 + 2] = __float2bfloat16(v.z * inv);
    q[lane * 4 + 3] = __float2bfloat16(v.w * inv);
}

// ============================ softmax rows of 16384 (block per row) ============================
__global__ __launch_bounds__(256)
void softmax_big_kernel(const float* __restrict__ in, float* __restrict__ out)
{
    __shared__ float buf[SEQ];
    __shared__ float red[256];
    int t = threadIdx.x;
    const float* src = in + (i64)blockIdx.x * SEQ;
    float mx = -3.0e38f;
#pragma unroll
    for (int j = 0; j < 16; j++) {
        float4 v = *(const float4*)&src[(j * 256 + t) * 4];
        *(float4*)&buf[(j * 256 + t) * 4] = v;
        mx = fmaxf(mx, fmaxf(fmaxf(v.x, v.y), fmaxf(v.z, v.w)));
    }
    red[t] = mx; __syncthreads();
    for (int s = 128; s > 0; s >>= 1) { if (t < s) red[t] = fmaxf(red[t], red[t + s]); __syncthreads(); }
    mx = red[0];
    __syncthreads();
    float sum = 0.f;
#pragma unroll
    for (int j = 0; j < 16; j++) {
        float4 v = *(float4*)&buf[(j * 256 + t) * 4];
        v.x = expf(v.x - mx); v.y = expf(v.y - mx);
        v.z = expf(v.z - mx); v.w = expf(v.w - mx);
        *(float4*)&buf[(j * 256 + t) * 4] = v;
        sum += v.x + v.y + v.z + v.w;
    }
    red[t] = sum; __syncthreads();
    for (int s = 128; s > 0; s >>= 1) { if (t < s) red[t] += red[t + s]; __syncthreads(); }
    float inv = 1.f / red[0];
    float* dst = out + (i64)blockIdx.x * SEQ;
#pragma unroll
    for (int j = 0; j < 16; j++) {
        float4 v = *(float4*)&buf[(j * 256 + t) * 4];
        v.x *= inv; v.y *= inv; v.z *= inv; v.w *= inv;
        *(float4*)&dst[(j * 256 + t) * 4] = v;
    }
}

// ============================ pinv helpers (bf16) ============================
__global__ void pinv_sums_kernel(const bf16* __restrict__ x, float* __restrict__ scal)
{
    int bh = blockIdx.x;
    const bf16* p = x + (i64)bh * 65536;
    int t = threadIdx.x;
    float cs = 0.f, rs = 0.f;
    for (int i = 0; i < 256; i++) cs += fabsf(cvt(p[i * 256 + t]));
    for (int j = 0; j < 256; j++) rs += fabsf(cvt(p[t * 256 + j]));
    __shared__ float rc[256], rr[256];
    rc[t] = cs; rr[t] = rs; __syncthreads();
    for (int s = 128; s > 0; s >>= 1) {
        if (t < s) { rc[t] = fmaxf(rc[t], rc[t + s]); rr[t] = fmaxf(rr[t], rr[t + s]); }
        __syncthreads();
    }
    if (t == 0) {
        atomicMax(reinterpret_cast<int*>(&scal[0]), __float_as_int(rc[0]));
        atomicMax(reinterpret_cast<int*>(&scal[1]), __float_as_int(rr[0]));
    }
}

__global__ void pinv_init_kernel(const bf16* __restrict__ x, const float* __restrict__ scal,
                                 bf16* __restrict__ z, bf16* __restrict__ zT)
{
    i64 idx = (i64)blockIdx.x * 256 + threadIdx.x;
    int j = (int)(idx & 255); int i = (int)((idx >> 8) & 255); i64 bh = idx >> 16;
    float inv = 1.f / (scal[0] * scal[1]);
    float xv = cvt(x[idx]) * inv;
    zT[idx] = __float2bfloat16(xv);
    z[(bh << 16) + ((i64)j << 8) + i] = __float2bfloat16(xv);
}

// ============================ depthwise conv residual added onto xn (bf16, 8-wide vectorized) ============================
__global__ __launch_bounds__(256)
void conv_add_kernel(const bf16* __restrict__ qkv, const float* __restrict__ w,
                     bf16* __restrict__ xn)
{
    union U8 { short8 v; bf16 e[8]; };
    i64 idx = (i64)blockIdx.x * 256 + threadIdx.x;
    int cg = (int)(idx & 63);
    i64 bn = idx >> 6;
    int n = (int)(bn & (SEQ - 1));
    int b = (int)(bn >> 14);
    int c = cg * 8;
    int h = c >> 6;

    U8 xin; xin.v = *(const short8*)&xn[(bn << 9) + c];
    float acc[8];
#pragma unroll
    for (int j = 0; j < 8; j++) acc[j] = cvt(xin.e[j]);

    const float* wk = w + h * 33;
    const bf16* vb = qkv + (i64)b * SEQ * Q3 + 2 * DM + c;
#pragma unroll
    for (int t = 0; t < 33; t++) {
        int nn = n + t - 16;
        if (nn >= 0 && nn < SEQ) {
            U8 vv; vv.v = *(const short8*)&vb[(i64)nn * Q3];
            float wt = wk[t];
#pragma unroll
            for (int j = 0; j < 8; j++) acc[j] = fmaf(wt, cvt(vv.e[j]), acc[j]);
        }
    }
    U8 o;
#pragma unroll
    for (int j = 0; j < 8; j++) o.e[j] = __float2bfloat16(acc[j]);
    *(short8*)&xn[(bn << 9) + c] = o.v;
}

// ============================ pooling ============================
__global__ void pool_score_kernel(const float* __restrict__ t, const float* __restrict__ w,
                                  const float* __restrict__ b2, float* __restrict__ s)
{
    int row = blockIdx.x * 4 + (threadIdx.x >> 6);
    int lane = threadIdx.x & 63;
    float acc = t[(i64)row * 128 + lane] * w[lane] + t[(i64)row * 128 + 64 + lane] * w[64 + lane];
    for (int o = 32; o > 0; o >>= 1) acc += __shfl_xor(acc, o);
    if (lane == 0) s[row] = acc + b2[0];
}

__global__ __launch_bounds__(256)
void pool_z_kernel(const float* __restrict__ a, const bf16* __restrict__ h, float* __restrict__ z)
{
    int bb = blockIdx.x >> 7, cg = blockIdx.x & 127;
    int c4 = cg * 4;
    int t = threadIdx.x;
    const float* ab = a + (i64)bb * SEQ;
    const bf16* hb = h + (i64)bb * SEQ * DM;
    float4 acc = {0.f, 0.f, 0.f, 0.f};
    for (int r = t; r < SEQ; r += 256) {
        float av = ab[r];
        float4 hv = ld4(&hb[(i64)r * DM + c4]);
        acc.x += av * hv.x; acc.y += av * hv.y; acc.z += av * hv.z; acc.w += av * hv.w;
    }
    __shared__ float4 red[256];
    red[t] = acc; __syncthreads();
    for (int s = 128; s > 0; s >>= 1) {
        if (t < s) {
            float4 o = red[t + s];
            red[t].x += o.x; red[t].y += o.y; red[t].z += o.z; red[t].w += o.w;
        }
        __syncthreads();
    }
    if (t == 0) *(float4*)&z[bb * DM + c4] = red[0];
}

__global__ void head_kernel(const float* __restrict__ z, const float* __restrict__ w,
                            const float* __restrict__ b, float* __restrict__ out)
{
    int t = threadIdx.x;
    int wv = t >> 6, lane = t & 63;
    int bb = wv >> 1, cls = wv & 1;
    float acc = 0.f;
#pragma unroll
    for (int j = 0; j < 8; j++) { int k = lane * 8 + j; acc += z[bb * DM + k] * w[k * 2 + cls]; }
    for (int o = 32; o > 0; o >>= 1) acc += __shfl_xor(acc, o);
    __shared__ float lg[4];
    if (lane == 0) lg[wv] = acc + b[cls];
    __syncthreads();
    if (t == 0) {
        for (int bi = 0; bi < 2; bi++) {
            float l0 = lg[bi * 2], l1 = lg[bi * 2 + 1];
            out[bi * 2 + 0] = l0; out[bi * 2 + 1] = l1;
            float m = fmaxf(l0, l1);
            float e0 = expf(l0 - m), e1 = expf(l1 - m);
            float inv = 1.f / (e0 + e1);
            out[4 + bi * 2 + 0] = e0 * inv; out[4 + bi * 2 + 1] = e1 * inv;
        }
    }
}

// ============================ host orchestration ============================
extern "C" void kernel_launch(void* const* d_in, const int* in_sizes, int n_in,
                              void* d_out, int out_size, void* d_ws, size_t ws_size,
                              hipStream_t stream)
{
    const float* x      = (const float*)d_in[0];
    const float* fc1_w  = (const float*)d_in[1];
    const float* fc1_b  = (const float*)d_in[2];
    const float* ln1_g  = (const float*)d_in[3];
    const float* ln1_b  = (const float*)d_in[4];
    const float* qkv_w  = (const float*)d_in[5];
    const float* out_w  = (const float*)d_in[6];
    const float* out_b  = (const float*)d_in[7];
    const float* conv_w = (const float*)d_in[8];
    const float* ln2_g  = (const float*)d_in[9];
    const float* ln2_b  = (const float*)d_in[10];
    const float* ff1_w  = (const float*)d_in[11];
    const float* ff1_b  = (const float*)d_in[12];
    const float* ff2_w  = (const float*)d_in[13];
    const float* ff2_b  = (const float*)d_in[14];
    const float* att1_w = (const float*)d_in[15];
    const float* att1_b = (const float*)d_in[16];
    const float* att2_w = (const float*)d_in[17];
    const float* att2_b = (const float*)d_in[18];
    const float* fc2_w  = (const float*)d_in[19];
    const float* fc2_b  = (const float*)d_in[20];
    float* out = (float*)d_out;
    float* ws  = (float*)d_ws;

    // ---- workspace layout (float units), same region sizes as passing round-15 layout ----
    i64 off = 0;
    bf16*  h    = (bf16*)(ws + off); off += (i64)ROWS * DM;      // A: bf16 residual
    bf16*  xn   = (bf16*)(ws + off); off += (i64)ROWS * DM / 2;  // B: bf16 act / attn-out
    bf16*  qkv  = (bf16*)(ws + off); off += (i64)ROWS * Q3 / 2;  // C: bf16 qkv / xb / ffc(+D)
    float* sbuf = ws + off; off += (i64)2 * LMK * SEQ;           // D: wT / vTall / MIL scores / ffc tail
    float* attn2= ws + off; off += 16 * 65536;                   // E: attn2f -> wTf1
    float* zA   = ws + off; off += 16 * 65536;                   // F: attn2b+XZ -> zF -> wTf2
    float* zB   = ws + off; off += 16 * 65536;                   // G┐
    float* xz   = ws + off; off += 16 * 65536;                   // H│ pinv pings | attn3 obuf
    float* wbuf = ws + off; off += 16 * 65536;                   // I│
    float* tbuf = ws + off; off += 16 * 65536;                   // J┘
    float* regK = ws + off; off += 16 * LMK * DH;                // K: q_lb + klb (bf16)
    float* regL = ws + off; off += 16 * LMK * DH;                // L: yTb + wTa (bf16)
    float* a3v  = ws + off; off += 16 * LMK * DH;                // M: a3vTb (bf16)
    float* ybuf = ws + off; off += 16 * LMK * DH;                // N: mbuf + sbuf2
    float* scor = ws + off; off += ROWS;
    float* zpool= ws + off; off += BATCH * DM;
    float* scal = ws + off; off += 16;
    if (ws_size < (size_t)off * sizeof(float)) return;

    bf16*  wT   = (bf16*)sbuf;
    bf16*  xb   = qkv;
    float* attn2f = attn2;
    bf16*  attn2b = (bf16*)zA;                 // F.0
    bf16*  XZ     = (bf16*)(zA + 524288);      // F.1
    bf16*  zG     = (bf16*)zB;
    bf16*  zGT    = (bf16*)(zB + 524288);
    bf16*  zH     = (bf16*)xz;
    bf16*  zHT    = (bf16*)(xz + 524288);
    bf16*  W1     = (bf16*)wbuf;               // I.0
    bf16*  W2     = (bf16*)(wbuf + 524288);    // I.1
    bf16*  zF     = attn2b;
    bf16*  vTall = (bf16*)sbuf;                // [2][8][64][16384] bf16 = D exactly
    float* obuf  = zB;                         // attn3 O partials: G..J exactly
    float* mbuf  = ybuf;
    float* sbuf2 = ybuf + 65536;
    bf16*  a3vTb = (bf16*)a3v;                 // [16][64][256] bf16
    bf16*  q_lb = (bf16*)regK;
    bf16*  klb  = (bf16*)(regK + 131072);
    bf16*  yTb  = (bf16*)regL;
    bf16*  wTa  = (bf16*)(regL + 131072);
    bf16*  wTf1 = (bf16*)attn2;
    bf16*  wTf2 = (bf16*)zA;
    bf16*  ffc  = qkv;

    const i64 sQKVb = (i64)SEQ * Q3;
    const i64 sLMh  = (i64)LMK * DH;

    // fc1 + ReLU via MFMA (h bf16)
    cvt_bf16_kernel<<<(ROWS * 1024 / 4 + 255) / 256, 256, 0, stream>>>(x, xb, (i64)ROWS * 1024);
    transpose_w_kernel<<<dim3(DM / 64, 1024 / 64), 256, 0, stream>>>(fc1_w, wT, 1024, DM);
    ml<4, 2, 1, false>(stream, xb, wT, h, fc1_b, ROWS, DM, 1024, 1024, 1024, DM);

    for (int L = 0; L < 2; L++) {
        const float* qw  = qkv_w + (i64)L * DM * Q3;
        const float* ow  = out_w + (i64)L * DM * DM;
        const float* ob  = out_b + (i64)L * DM;
        const float* cw  = conv_w + (i64)L * NHEAD * 33;
        const float* f1w = ff1_w + (i64)L * DM * FFD;
        const float* f1b = ff1_b + (i64)L * FFD;
        const float* f2w = ff2_w + (i64)L * FFD * DM;
        const float* f2b = ff2_b + (i64)L * DM;

        // LN1 -> xn (bf16); qkv = xn @ qw (MFMA)
        ln_kernel<<<ROWS/4, 256, 0, stream>>>(h, xn, ln1_g + L*DM, ln1_b + L*DM, ROWS);
        transpose_w_kernel<<<dim3(Q3 / 64, DM / 64), 256, 0, stream>>>(qw, wT, DM, Q3);
        ml<4, 2, 0, false>(stream, xn, wT, qkv, nullptr, ROWS, Q3, DM, DM, DM, Q3);

        // landmarks (q and k in one launch)
        landmark_kernel<<<2*16*LMK, 64, 0, stream>>>(qkv, q_lb, klb);

        // attn2 = softmax(0.125 * q_l @ k_l^T) via MFMA -> bf16
        ml<2, 2, 0, false>(stream, q_lb, klb, attn2f, nullptr,
            LMK, LMK, DH, DH, DH, LMK, 0, sLMh, 0, sLMh, 0, 65536, 1, 16, 0.125f);
        softmax256_fb_kernel<<<16*LMK/4, 256, 0, stream>>>(attn2f, attn2b, (i64)16*LMK);

        // pinv (Newton-Schulz, 6 iters, 4 MFMA launches/iter via dual-output epilogue)
        hipMemsetAsync(scal, 0, 2*sizeof(float), stream);
        pinv_sums_kernel<<<16, 256, 0, stream>>>(attn2b, scal);
        pinv_init_kernel<<<16*65536/256, 256, 0, stream>>>(attn2b, scal, zG, zGT);
        {
            bf16 *zp = zG, *zpT = zGT, *zq = zH, *zqT = zHT;
            for (int it = 0; it < 6; it++) {
                bool last = (it == 5);
                mlp2<2, false>(stream, XZ, W1, attn2b, zpT, 1.f, 0.f, 7.f);
                mlp2<0, true >(stream, W2, nullptr, W1, XZ, 1.f, 15.f);
                mlp2<0, true >(stream, W1, nullptr, W2, XZ, 1.f, 13.f);
                if (!last) {
                    mlp2<1, false>(stream, zq, zqT, zp, W1, 0.25f);
                    bf16* t1 = zp; zp = zq; zq = t1;
                    bf16* t2 = zpT; zpT = zqT; zqT = t2;
                } else {
                    mlp2<0, false>(stream, zF, nullptr, zp, W1, 0.25f);
                }
            }
        }
        // final pinv z at zF. D and G..J free now.

        // attn3: batched vT -> fused flash split-KV -> combine (writes a3v^T bf16)
        t64_kernel<<<dim3(SEQ/64, BATCH*NHEAD), 256, 0, stream>>>(
            qkv + 2*DM, vTall, Q3, SEQ,
            sQKVb, (i64)DH, (i64)NHEAD*DH*SEQ, (i64)DH*SEQ, NHEAD);
        attn3_fused_kernel<<<dim3(16, 16), 256, 0, stream>>>(qkv, q_lb, vTall, obuf, mbuf, sbuf2);
        attn3_combine_kernel<<<16*LMK/4, 256, 0, stream>>>(obuf, mbuf, sbuf2, a3vTb);

        // yT = a3v^T @ z^T  (one MFMA launch -> yTb bf16)
        ml<2, 4, 0, false>(stream, a3vTb, zF, yTb, nullptr,
            DH, LMK, LMK, LMK, LMK, LMK, 0, (i64)DH*LMK, 0, 65536, 0, (i64)DH*LMK, 1, 16, 1.f);

        // attn1: fused QK + softmax + PV (QBLK=64), one launch -> xn
        attn1_fused_kernel<<<dim3(ROWS/64, NHEAD), 256, 0, stream>>>(qkv, klb, yTb, xn);

        // xn += depthwise conv(v); h += xn @ out_w + out_b (MFMA, bf16 resid)
        conv_add_kernel<<<(i64)ROWS*64/256, 256, 0, stream>>>(qkv, cw, xn);
        transpose_w_kernel<<<dim3(DM / 64, DM / 64), 256, 0, stream>>>(ow, wT, DM, DM);
        ml<4, 2, 0, true>(stream, xn, wT, h, ob, ROWS, DM, DM, DM, DM, DM);

        // FF block (MFMA; single pass, ffc spans C+D)
        ln_kernel<<<ROWS/4, 256, 0, stream>>>(h, xn, ln2_g + L*DM, ln2_b + L*DM, ROWS);
        transpose_w_kernel<<<dim3(FFD / 64, DM / 64), 256, 0, stream>>>(f1w, wTf1, DM, FFD);
        transpose_w_kernel<<<dim3(DM / 64, FFD / 64), 256, 0, stream>>>(f2w, wTf2, FFD, DM);
        ml<4, 2, 2, false>(stream, xn, wTf1, ffc, f1b, ROWS, FFD, DM, DM, DM, FFD);
        ml<4, 2, 0, true >(stream, ffc, wTf2, h, f2b, ROWS, DM, FFD, FFD, FFD, DM);
    }

    // gated-attention MIL pooling: tanh(h @ att1_w + b) via MFMA (h bf16)
    transpose_w_kernel<<<dim3(128 / 64, DM / 64), 256, 0, stream>>>(att1_w, wTa, DM, 128);
    ml<4, 2, 3, false>(stream, h, wTa, sbuf, att1_b, ROWS, 128, DM, DM, DM, 128);
    pool_score_kernel<<<ROWS/4, 256, 0, stream>>>(sbuf, att2_w, att2_b, scor);
    softmax_big_kernel<<<BATCH, 256, 0, stream>>>(scor, out + 8);
    pool_z_kernel<<<BATCH * 128, 256, 0, stream>>>(out + 8, h, zpool);
    head_kernel<<<1, 256, 0, stream>>>(zpool, fc2_w, fc2_b, out);
}

// Round 17
// 1757.112 us; speedup vs baseline: 34.1752x; 1.0540x over previous
//
#include <hip/hip_runtime.h>
#include <hip/hip_bf16.h>

typedef long long i64;
typedef __hip_bfloat16 bf16;
using short8 = __attribute__((ext_vector_type(8))) short;
using f32x4  = __attribute__((ext_vector_type(4))) float;

#define SEQ    16384
#define DM     512
#define NHEAD  8
#define DH     64
#define LMK    256
#define LSUB   64      // SEQ / LMK
#define Q3     1536
#define FFD    2048
#define BATCH  2
#define ROWS   (BATCH * SEQ)

__device__ __forceinline__ float cvt(float v) { return v; }
__device__ __forceinline__ float cvt(bf16 v) { return __bfloat162float(v); }
__device__ __forceinline__ void stc(float* p, float v) { *p = v; }
__device__ __forceinline__ void stc(bf16* p, float v) { *p = __float2bfloat16(v); }

__device__ __forceinline__ float4 ld4(const float* p) { return *(const float4*)p; }
__device__ __forceinline__ float4 ld4(const bf16* p) {
    union { short s[4]; } u; *(int2*)u.s = *(const int2*)p;
    float4 v;
    v.x = cvt(((const bf16*)u.s)[0]); v.y = cvt(((const bf16*)u.s)[1]);
    v.z = cvt(((const bf16*)u.s)[2]); v.w = cvt(((const bf16*)u.s)[3]);
    return v;
}
__device__ __forceinline__ void ld8f(const bf16* p, float* d) {
    union { short8 v; bf16 e[8]; } u;
    u.v = *(const short8*)p;
#pragma unroll
    for (int j = 0; j < 8; j++) d[j] = cvt(u.e[j]);
}

// fast GELU (tanh form, hw exp+rcp): gelu(v) ~= v * e / (e + 1), e = exp(2a(v + b v^3))
__device__ __forceinline__ float gelu_fast(float v) {
    float u = v * (1.5957691216057308f + 0.07135370154f * v * v);
    float e = __expf(fminf(u, 80.f));
    return v * e * __builtin_amdgcn_rcpf(e + 1.f);
}
// exact tanh via hw exp+rcp
__device__ __forceinline__ float tanh_fast(float v) {
    float e = __expf(fminf(2.f * v, 80.f));
    return 1.f - 2.f * __builtin_amdgcn_rcpf(e + 1.f);
}

#define LDS_U32(p) ((__attribute__((address_space(3))) uint32_t*)(p))
#define GLB_U32(p) ((const __attribute__((address_space(1))) uint32_t*)(p))

// ============================ MFMA bf16 GEMM (batched strides, swizzled global_load_lds staging) ============================
// XCD-aware bijective block remap. DSUB: C = diag(beta) - alpha*A@Bt^T (primary).
// TMODE: 0 none; 1 also write Ct[n][m] = v; 2 also write Ct[n][m] = (m==n?betaT:0) - v.
template<int FM, int FN, int ACT, bool RESID, bool DSUB, int TMODE, typename TC>
__global__ __launch_bounds__(256)
void mfma_gemm_kernel(const bf16* __restrict__ Abase, const bf16* __restrict__ Btbase,
                      TC* __restrict__ Cbase, bf16* __restrict__ Ctbase,
                      const float* __restrict__ bias,
                      int M, int N, int K, int lda, int ldb, int ldc,
                      i64 sAb, i64 sAh, i64 sBb, i64 sBh, i64 sCb, i64 sCh,
                      int nh, float alpha, float beta, float betaT)
{
    constexpr int BM = FM * 32;
    constexpr int BN = FN * 32;
    constexpr int ASL = BM / 8;          // A slabs (8 rows each)
    constexpr int NSL = (BM + BN) / 8;   // total slabs
    constexpr int NIT = NSL / 4;         // per-wave slab iterations (compile-time)
    __shared__ bf16 Al[BM][64];
    __shared__ bf16 Bl[BN][64];

    int nwg  = gridDim.x * gridDim.y * gridDim.z;
    int orig = (blockIdx.z * gridDim.y + blockIdx.y) * gridDim.x + blockIdx.x;
    int qq = nwg >> 3, rr = nwg & 7;
    int xcd = orig & 7, loc = orig >> 3;
    int wid = (xcd < rr ? xcd * (qq + 1) : rr * (qq + 1) + (xcd - rr) * qq) + loc;
    int bx = wid % gridDim.x;
    int t1 = wid / gridDim.x;
    int by = t1 % gridDim.y;
    int bz = t1 / gridDim.y;

    int bb = bz / nh, hh = bz % nh;
    const bf16* A  = Abase  + bb * sAb + hh * sAh;
    const bf16* Bt = Btbase + bb * sBb + hh * sBh;
    TC*         C  = Cbase  + bb * sCb + hh * sCh;
    bf16* Ct = nullptr;
    if (TMODE) Ct = Ctbase + bb * sCb + hh * sCh;

    int tid = threadIdx.x;
    int wave = tid >> 6, lane = tid & 63;
    int wm = (wave >> 1) * (FM * 16), wn = (wave & 1) * (FN * 16);
    int m0 = by * BM, n0 = bx * BN;
    int lr = lane & 15, lq = lane >> 4;
    int srow = lane >> 3;
    int scol = ((lane & 7) ^ srow) * 8;

    // hoist per-slab global source pointers and LDS destinations
    const bf16* gsrc[NIT];
    uint32_t* ldst[NIT];
#pragma unroll
    for (int s = 0; s < NIT; s++) {
        int op = wave + s * 4;
        if (op < ASL) {
            gsrc[s] = A + (i64)(m0 + op * 8 + srow) * lda + scol;
            ldst[s] = (uint32_t*)&Al[op * 8][0];
        } else {
            int o2 = op - ASL;
            gsrc[s] = Bt + (i64)(n0 + o2 * 8 + srow) * ldb + scol;
            ldst[s] = (uint32_t*)&Bl[o2 * 8][0];
        }
    }

    f32x4 acc[FM][FN];
#pragma unroll
    for (int i = 0; i < FM; i++)
#pragma unroll
        for (int j = 0; j < FN; j++) acc[i][j] = (f32x4){0.f, 0.f, 0.f, 0.f};

    int c0 = (lq ^ (lr & 7)) * 8;
    int c1 = ((4 | lq) ^ (lr & 7)) * 8;

    for (int k0 = 0; k0 < K; k0 += 64) {
#pragma unroll
        for (int s = 0; s < NIT; s++)
            __builtin_amdgcn_global_load_lds(GLB_U32(gsrc[s] + k0),
                (__attribute__((address_space(3))) uint32_t*)ldst[s], 16, 0, 0);
        __syncthreads();
        {
            short8 af[FM], bfr[FN];
#pragma unroll
            for (int i = 0; i < FM; i++) af[i]  = *(const short8*)&Al[wm + i * 16 + lr][c0];
#pragma unroll
            for (int j = 0; j < FN; j++) bfr[j] = *(const short8*)&Bl[wn + j * 16 + lr][c0];
#pragma unroll
            for (int i = 0; i < FM; i++)
#pragma unroll
                for (int j = 0; j < FN; j++)
                    acc[i][j] = __builtin_amdgcn_mfma_f32_16x16x32_bf16(af[i], bfr[j], acc[i][j], 0, 0, 0);
        }
        {
            short8 af[FM], bfr[FN];
#pragma unroll
            for (int i = 0; i < FM; i++) af[i]  = *(const short8*)&Al[wm + i * 16 + lr][c1];
#pragma unroll
            for (int j = 0; j < FN; j++) bfr[j] = *(const short8*)&Bl[wn + j * 16 + lr][c1];
#pragma unroll
            for (int i = 0; i < FM; i++)
#pragma unroll
                for (int j = 0; j < FN; j++)
                    acc[i][j] = __builtin_amdgcn_mfma_f32_16x16x32_bf16(af[i], bfr[j], acc[i][j], 0, 0, 0);
        }
        __syncthreads();
    }

#pragma unroll
    for (int i = 0; i < FM; i++)
#pragma unroll
        for (int r = 0; r < 4; r++) {
            int m = m0 + wm + i * 16 + lq * 4 + r;
            TC* crow = C + (i64)m * ldc;
#pragma unroll
            for (int j = 0; j < FN; j++) {
                int n = n0 + wn + j * 16 + lr;
                float v = acc[i][j][r] * alpha;
                if (DSUB) v = ((m == n) ? beta : 0.f) - v;
                if (bias) v += bias[n];
                if (ACT == 1) v = fmaxf(v, 0.f);
                else if (ACT == 2) v = gelu_fast(v);
                else if (ACT == 3) v = tanh_fast(v);
                if (RESID) v += cvt(crow[n]);
                stc(&crow[n], v);
                if (TMODE == 1) Ct[(i64)n * ldc + m] = __float2bfloat16(v);
                else if (TMODE == 2) Ct[(i64)n * ldc + m] = __float2bfloat16(((m == n) ? betaT : 0.f) - v);
            }
        }
}

template<int FM, int FN, int ACT, bool RES, typename TC>
static inline void ml(hipStream_t st, const bf16* A, const bf16* Bt, TC* C, const float* bias,
                      int M, int N, int K, int lda, int ldb, int ldc,
                      i64 sAb = 0, i64 sAh = 0, i64 sBb = 0, i64 sBh = 0, i64 sCb = 0, i64 sCh = 0,
                      int nb = 1, int nh = 1, float alpha = 1.f)
{
    dim3 g(N / (FN * 32), M / (FM * 32), nb * nh);
    mfma_gemm_kernel<FM, FN, ACT, RES, false, 0, TC><<<g, 256, 0, st>>>(
        A, Bt, C, nullptr, bias, M, N, K, lda, ldb, ldc, sAb, sAh, sBb, sBh, sCb, sCh, nh, alpha, 0.f, 0.f);
}

// pinv MFMA helper: 256x256x256, 16 batches, bf16 out
template<int TMODE, bool DSUB>
static inline void mlp2(hipStream_t st, bf16* C, bf16* Ct, const bf16* A, const bf16* Bt,
                        float alpha, float beta = 0.f, float betaT = 0.f)
{
    dim3 g(4, 4, 16);
    mfma_gemm_kernel<2, 2, 0, false, DSUB, TMODE, bf16><<<g, 256, 0, st>>>(
        A, Bt, C, Ct, nullptr, 256, 256, 256, 256, 256, 256,
        0, 65536, 0, 65536, 0, 65536, 16, alpha, beta, betaT);
}

// ============================ fused attn3 (flash-style split-KV, 32 chunks) ============================
// grid (32 chunks of 512 keys, 16 bh). LDS 80KB -> 2 blocks/CU. Partials: O bf16, m/s fp32.
__global__ __launch_bounds__(256)
void attn3_fused_kernel(const bf16* __restrict__ qkv, const bf16* __restrict__ q_lb,
                        const bf16* __restrict__ vTall,
                        bf16* __restrict__ obuf, float* __restrict__ mbuf,
                        float* __restrict__ sbuf2)
{
    __shared__ bf16 qs[256][64];
    __shared__ bf16 ks[64][64];
    __shared__ bf16 vs[64][64];
    __shared__ bf16 Ps[4][64][64];

    int ch = blockIdx.x, bh = blockIdx.y;
    int b = bh >> 3, hh = bh & 7;
    const bf16* qg = q_lb + (i64)bh * (LMK * DH);
    const bf16* kg = qkv + (i64)b * SEQ * Q3 + DM + hh * DH;
    const bf16* vg = vTall + ((i64)b * NHEAD + hh) * ((i64)DH * SEQ);

    int tid = threadIdx.x;
    int wave = tid >> 6, lane = tid & 63;
    int lr = lane & 15, lq = lane >> 4;
    int srow = lane >> 3;
    int scol = ((lane & 7) ^ srow) * 8;
    int c0 = (lq ^ (lr & 7)) * 8;
    int c1 = ((4 | lq) ^ (lr & 7)) * 8;
    int qb = wave * 64;

    for (int sl = wave; sl < 32; sl += 4)
        __builtin_amdgcn_global_load_lds(GLB_U32(qg + (i64)(sl * 8 + srow) * 64 + scol),
                                         LDS_U32(&qs[sl * 8][0]), 16, 0, 0);

    f32x4 O[4][4];
    float m[4][4], s[4][4];
#pragma unroll
    for (int i = 0; i < 4; i++)
#pragma unroll
        for (int r = 0; r < 4; r++) { m[i][r] = -3.0e38f; s[i][r] = 0.f; }
#pragma unroll
    for (int i = 0; i < 4; i++)
#pragma unroll
        for (int j = 0; j < 4; j++) O[i][j] = (f32x4){0.f, 0.f, 0.f, 0.f};

    int k0g = ch * 512;
    for (int t = 0; t < 8; t++) {
        int kk0 = k0g + t * 64;
        for (int sl = wave; sl < 8; sl += 4)
            __builtin_amdgcn_global_load_lds(GLB_U32(kg + (i64)(kk0 + sl * 8 + srow) * Q3 + scol),
                                             LDS_U32(&ks[sl * 8][0]), 16, 0, 0);
        for (int sl = wave; sl < 8; sl += 4)
            __builtin_amdgcn_global_load_lds(GLB_U32(vg + (i64)(sl * 8 + srow) * SEQ + kk0 + scol),
                                             LDS_U32(&vs[sl * 8][0]), 16, 0, 0);
        __syncthreads();

        f32x4 S[4][4];
#pragma unroll
        for (int i = 0; i < 4; i++)
#pragma unroll
            for (int j = 0; j < 4; j++) S[i][j] = (f32x4){0.f, 0.f, 0.f, 0.f};
        {
            short8 af[4], bk[4];
#pragma unroll
            for (int i = 0; i < 4; i++) af[i] = *(const short8*)&qs[qb + i * 16 + lr][c0];
#pragma unroll
            for (int j = 0; j < 4; j++) bk[j] = *(const short8*)&ks[j * 16 + lr][c0];
#pragma unroll
            for (int i = 0; i < 4; i++)
#pragma unroll
                for (int j = 0; j < 4; j++)
                    S[i][j] = __builtin_amdgcn_mfma_f32_16x16x32_bf16(af[i], bk[j], S[i][j], 0, 0, 0);
#pragma unroll
            for (int i = 0; i < 4; i++) af[i] = *(const short8*)&qs[qb + i * 16 + lr][c1];
#pragma unroll
            for (int j = 0; j < 4; j++) bk[j] = *(const short8*)&ks[j * 16 + lr][c1];
#pragma unroll
            for (int i = 0; i < 4; i++)
#pragma unroll
                for (int j = 0; j < 4; j++)
                    S[i][j] = __builtin_amdgcn_mfma_f32_16x16x32_bf16(af[i], bk[j], S[i][j], 0, 0, 0);
        }

#pragma unroll
        for (int i = 0; i < 4; i++)
#pragma unroll
            for (int r = 0; r < 4; r++) {
                float tm = -3.0e38f;
#pragma unroll
                for (int j = 0; j < 4; j++) {
                    S[i][j][r] *= 0.125f;
                    tm = fmaxf(tm, S[i][j][r]);
                }
                tm = fmaxf(tm, __shfl_xor(tm, 1)); tm = fmaxf(tm, __shfl_xor(tm, 2));
                tm = fmaxf(tm, __shfl_xor(tm, 4)); tm = fmaxf(tm, __shfl_xor(tm, 8));
                float mn = fmaxf(m[i][r], tm);
                float f = __expf(m[i][r] - mn);
                float ss = 0.f;
#pragma unroll
                for (int j = 0; j < 4; j++) {
                    float e = __expf(S[i][j][r] - mn);
                    S[i][j][r] = e;
                    ss += e;
                }
                ss += __shfl_xor(ss, 1); ss += __shfl_xor(ss, 2);
                ss += __shfl_xor(ss, 4); ss += __shfl_xor(ss, 8);
                s[i][r] = s[i][r] * f + ss;
                m[i][r] = mn;
#pragma unroll
                for (int j2 = 0; j2 < 4; j2++) O[i][j2][r] *= f;
            }

#pragma unroll
        for (int i = 0; i < 4; i++)
#pragma unroll
            for (int j = 0; j < 4; j++)
#pragma unroll
                for (int r = 0; r < 4; r++) {
                    int row = i * 16 + lq * 4 + r;
                    int col = j * 16 + lr;
                    Ps[wave][row][(((col >> 3) ^ (row & 7)) << 3) | (col & 7)] =
                        __float2bfloat16(S[i][j][r]);
                }
        __syncthreads();

        {
            short8 a2[4], b2[4];
#pragma unroll
            for (int i = 0; i < 4; i++) a2[i] = *(const short8*)&Ps[wave][i * 16 + lr][c0];
#pragma unroll
            for (int j = 0; j < 4; j++) b2[j] = *(const short8*)&vs[j * 16 + lr][c0];
#pragma unroll
            for (int i = 0; i < 4; i++)
#pragma unroll
                for (int j = 0; j < 4; j++)
                    O[i][j] = __builtin_amdgcn_mfma_f32_16x16x32_bf16(a2[i], b2[j], O[i][j], 0, 0, 0);
#pragma unroll
            for (int i = 0; i < 4; i++) a2[i] = *(const short8*)&Ps[wave][i * 16 + lr][c1];
#pragma unroll
            for (int j = 0; j < 4; j++) b2[j] = *(const short8*)&vs[j * 16 + lr][c1];
#pragma unroll
            for (int i = 0; i < 4; i++)
#pragma unroll
                for (int j = 0; j < 4; j++)
                    O[i][j] = __builtin_amdgcn_mfma_f32_16x16x32_bf16(a2[i], b2[j], O[i][j], 0, 0, 0);
        }
        __syncthreads();
    }

    i64 base = (i64)(bh * 32 + ch) * 256 * 64;
#pragma unroll
    for (int i = 0; i < 4; i++)
#pragma unroll
        for (int j2 = 0; j2 < 4; j2++)
#pragma unroll
            for (int r = 0; r < 4; r++) {
                int row = qb + i * 16 + lq * 4 + r;
                int d = j2 * 16 + lr;
                obuf[base + (i64)row * 64 + d] = __float2bfloat16(O[i][j2][r]);
            }
    if (lr == 0) {
#pragma unroll
        for (int i = 0; i < 4; i++)
#pragma unroll
            for (int r = 0; r < 4; r++) {
                int idx = (bh * 32 + ch) * 256 + qb + i * 16 + lq * 4 + r;
                mbuf[idx] = m[i][r];
                sbuf2[idx] = s[i][r];
            }
    }
}

// combine 32 split-KV partials -> a3v^T (bf16, [bh][d][row]) for the yT MFMA
__global__ __launch_bounds__(256)
void attn3_combine_kernel(const bf16* __restrict__ obuf, const float* __restrict__ mbuf,
                          const float* __restrict__ sbuf2, bf16* __restrict__ a3vT)
{
    int gid = blockIdx.x * 4 + (threadIdx.x >> 6);   // 4096 rows
    int lane = threadIdx.x & 63;
    int bh = gid >> 8, row = gid & 255;
    const float* mrow = mbuf + (i64)(bh * 32) * 256 + row;
    const float* srow = sbuf2 + (i64)(bh * 32) * 256 + row;
    float M = -3.0e38f;
#pragma unroll
    for (int c = 0; c < 32; c++) M = fmaxf(M, mrow[c * 256]);
    float denom = 0.f, acc = 0.f;
#pragma unroll
    for (int c = 0; c < 32; c++) {
        float w = __expf(mrow[c * 256] - M);
        denom += srow[c * 256] * w;
        acc += cvt(obuf[((i64)(bh * 32 + c) * 256 + row) * 64 + lane]) * w;
    }
    a3vT[(i64)bh * (DH * LMK) + lane * 256 + row] = __float2bfloat16(acc / denom);
}

// ============================ fused attn1 (QBLK=64): S=q@klb^T -> softmax(256) -> @y^T -> xn ============================
__global__ __launch_bounds__(256)
void attn1_fused_kernel(const bf16* __restrict__ qkv, const bf16* __restrict__ klb_all,
                        const bf16* __restrict__ yTb_all, bf16* __restrict__ xn)
{
    __shared__ bf16 stage[20480];          // qs=stage[0..4095] (64x64), ks=stage[4096..] (256x64)
    __shared__ bf16 Ps[64][256];
    __shared__ float maxb[2][64];
    __shared__ float sumb[2][64];
    bf16 (*qs)[64]  = (bf16(*)[64])&stage[0];
    bf16 (*ks)[64]  = (bf16(*)[64])&stage[4096];
    bf16 (*yts)[256]= (bf16(*)[256])&stage[0];   // aliases dead q/k after QK

    int hh = blockIdx.y;
    i64 g0 = (i64)blockIdx.x * 64;
    int b  = (int)(g0 >> 14);
    const bf16* qg = qkv + (i64)b * SEQ * Q3 + (g0 & (SEQ - 1)) * Q3 + hh * DH;
    const bf16* kg = klb_all + (i64)(b * NHEAD + hh) * (LMK * DH);
    const bf16* yg = yTb_all + (i64)(b * NHEAD + hh) * (DH * LMK);

    int tid = threadIdx.x;
    int wave = tid >> 6, lane = tid & 63;
    int lr = lane & 15, lq = lane >> 4;
    int srow = lane >> 3;
    int scol = ((lane & 7) ^ srow) * 8;

    for (int sl = wave; sl < 8; sl += 4)
        __builtin_amdgcn_global_load_lds(GLB_U32(qg + (i64)(sl * 8 + srow) * Q3 + scol),
                                         LDS_U32(&qs[sl * 8][0]), 16, 0, 0);
    for (int sl = wave; sl < 32; sl += 4)
        __builtin_amdgcn_global_load_lds(GLB_U32(kg + (i64)(sl * 8 + srow) * 64 + scol),
                                         LDS_U32(&ks[sl * 8][0]), 16, 0, 0);
    __syncthreads();

    int wm = (wave >> 1) * 32, wn = (wave & 1) * 128;
    f32x4 acc[2][8];
#pragma unroll
    for (int i = 0; i < 2; i++)
#pragma unroll
        for (int j = 0; j < 8; j++) acc[i][j] = (f32x4){0.f, 0.f, 0.f, 0.f};

    int c0 = (lq ^ (lr & 7)) * 8;
    int c1 = ((4 | lq) ^ (lr & 7)) * 8;
    {
        short8 af[2], bfr[8];
#pragma unroll
        for (int i = 0; i < 2; i++) af[i]  = *(const short8*)&qs[wm + i * 16 + lr][c0];
#pragma unroll
        for (int j = 0; j < 8; j++) bfr[j] = *(const short8*)&ks[wn + j * 16 + lr][c0];
#pragma unroll
        for (int i = 0; i < 2; i++)
#pragma unroll
            for (int j = 0; j < 8; j++)
                acc[i][j] = __builtin_amdgcn_mfma_f32_16x16x32_bf16(af[i], bfr[j], acc[i][j], 0, 0, 0);
    }
    {
        short8 af[2], bfr[8];
#pragma unroll
        for (int i = 0; i < 2; i++) af[i]  = *(const short8*)&qs[wm + i * 16 + lr][c1];
#pragma unroll
        for (int j = 0; j < 8; j++) bfr[j] = *(const short8*)&ks[wn + j * 16 + lr][c1];
#pragma unroll
        for (int i = 0; i < 2; i++)
#pragma unroll
            for (int j = 0; j < 8; j++)
                acc[i][j] = __builtin_amdgcn_mfma_f32_16x16x32_bf16(af[i], bfr[j], acc[i][j], 0, 0, 0);
    }

#pragma unroll
    for (int i = 0; i < 2; i++)
#pragma unroll
        for (int j = 0; j < 8; j++)
#pragma unroll
            for (int r = 0; r < 4; r++) acc[i][j][r] *= 0.125f;
#pragma unroll
    for (int i = 0; i < 2; i++)
#pragma unroll
        for (int r = 0; r < 4; r++) {
            float m = acc[i][0][r];
#pragma unroll
            for (int j = 1; j < 8; j++) m = fmaxf(m, acc[i][j][r]);
            m = fmaxf(m, __shfl_xor(m, 1)); m = fmaxf(m, __shfl_xor(m, 2));
            m = fmaxf(m, __shfl_xor(m, 4)); m = fmaxf(m, __shfl_xor(m, 8));
            if (lr == 0) maxb[wave & 1][wm + i * 16 + lq * 4 + r] = m;
        }
    __syncthreads();

    // stage yts into the dead q/k region
    {
        int r2 = lane >> 5, c32 = lane & 31;
        for (int sl = wave; sl < 32; sl += 4) {
            int row = sl * 2 + r2;
            const bf16* g = yg + (i64)row * 256 + ((c32 ^ (row & 7)) * 8);
            __builtin_amdgcn_global_load_lds(GLB_U32(g), LDS_U32(&yts[sl * 2][0]), 16, 0, 0);
        }
    }

#pragma unroll
    for (int i = 0; i < 2; i++)
#pragma unroll
        for (int r = 0; r < 4; r++) {
            int row = wm + i * 16 + lq * 4 + r;
            float fm = fmaxf(maxb[0][row], maxb[1][row]);
            float ss = 0.f;
#pragma unroll
            for (int j = 0; j < 8; j++) {
                float e = __expf(acc[i][j][r] - fm);
                acc[i][j][r] = e;
                ss += e;
            }
            ss += __shfl_xor(ss, 1); ss += __shfl_xor(ss, 2);
            ss += __shfl_xor(ss, 4); ss += __shfl_xor(ss, 8);
            if (lr == 0) sumb[wave & 1][row] = ss;
        }
#pragma unroll
    for (int i = 0; i < 2; i++)
#pragma unroll
        for (int j = 0; j < 8; j++)
#pragma unroll
            for (int r = 0; r < 4; r++) {
                int row = wm + i * 16 + lq * 4 + r;
                int col = wn + j * 16 + lr;
                Ps[row][(((col >> 3) ^ (row & 7)) << 3) | (col & 7)] = __float2bfloat16(acc[i][j][r]);
            }
    __syncthreads();

    float s[2][4];
#pragma unroll
    for (int i = 0; i < 2; i++)
#pragma unroll
        for (int r = 0; r < 4; r++) {
            int row = wm + i * 16 + lq * 4 + r;
            s[i][r] = sumb[0][row] + sumb[1][row];
        }

    // PV: P[64][256] @ y[256][64]; per wave 32x32 tile
    int wn2 = (wave & 1) * 32;
    f32x4 acc2[2][2];
#pragma unroll
    for (int i = 0; i < 2; i++)
#pragma unroll
        for (int j = 0; j < 2; j++) acc2[i][j] = (f32x4){0.f, 0.f, 0.f, 0.f};
#pragma unroll
    for (int kk = 0; kk < 8; kk++) {
        int cc = ((kk * 4 + lq) ^ (lr & 7)) * 8;
        short8 a2[2], b2[2];
#pragma unroll
        for (int i = 0; i < 2; i++) a2[i] = *(const short8*)&Ps[wm + i * 16 + lr][cc];
#pragma unroll
        for (int j = 0; j < 2; j++) b2[j] = *(const short8*)&yts[wn2 + j * 16 + lr][cc];
#pragma unroll
        for (int i = 0; i < 2; i++)
#pragma unroll
            for (int j = 0; j < 2; j++)
                acc2[i][j] = __builtin_amdgcn_mfma_f32_16x16x32_bf16(a2[i], b2[j], acc2[i][j], 0, 0, 0);
    }

#pragma unroll
    for (int i = 0; i < 2; i++)
#pragma unroll
        for (int j = 0; j < 2; j++)
#pragma unroll
            for (int r = 0; r < 4; r++) {
                int row = wm + i * 16 + lq * 4 + r;
                int d = wn2 + j * 16 + lr;
                xn[(g0 + row) * DM + hh * DH + d] = __float2bfloat16(acc2[i][j][r] / s[i][r]);
            }
}

// ===================== weight transpose+convert: fp32 [K][N] -> bf16 [N][K] =====================
__global__ __launch_bounds__(256)
void transpose_w_kernel(const float* __restrict__ in, bf16* __restrict__ out, int K, int N)
{
    __shared__ float t[64][65];
    int k0 = blockIdx.y * 64, n0 = blockIdx.x * 64;
    int c = threadIdx.x & 63, r4 = threadIdx.x >> 6;
#pragma unroll
    for (int p = 0; p < 64; p += 4)
        t[p + r4][c] = in[(i64)(k0 + p + r4) * N + n0 + c];
    __syncthreads();
#pragma unroll
    for (int p = 0; p < 64; p += 4)
        out[(i64)(n0 + p + r4) * K + k0 + c] = __float2bfloat16(t[c][p + r4]);
}

// ===================== generic 64-col transpose -> bf16 (batched over b,h) =====================
__global__ __launch_bounds__(256)
void t64_kernel(const bf16* __restrict__ in, bf16* __restrict__ out, int ldin, int ldout,
                i64 sIb, i64 sIh, i64 sOb, i64 sOh, int nh)
{
    __shared__ bf16 t[64][72];
    int zz = blockIdx.y;
    int bb = zz / nh, hh = zz % nh;
    const bf16* ip = in + bb * sIb + hh * sIh;
    bf16* op = out + bb * sOb + hh * sOh;
    int r0 = blockIdx.x * 64;
    int c = threadIdx.x & 63, r4 = threadIdx.x >> 6;
#pragma unroll
    for (int p = 0; p < 64; p += 4)
        t[p + r4][c] = ip[(i64)(r0 + p + r4) * ldin + c];
    __syncthreads();
#pragma unroll
    for (int p = 0; p < 64; p += 4)
        op[(i64)(p + r4) * ldout + r0 + c] = t[c][p + r4];
}

// ===================== fp32 -> bf16 convert =====================
__global__ void cvt_bf16_kernel(const float* __restrict__ in, bf16* __restrict__ out, i64 n)
{
    i64 i = ((i64)blockIdx.x * 256 + threadIdx.x) * 4;
    if (i >= n) return;
    float4 v = *(const float4*)&in[i];
    out[i + 0] = __float2bfloat16(v.x);
    out[i + 1] = __float2bfloat16(v.y);
    out[i + 2] = __float2bfloat16(v.z);
    out[i + 3] = __float2bfloat16(v.w);
}

// ============================ LayerNorm (rows of 512), bf16 in -> bf16 out ============================
__global__ __launch_bounds__(256)
void ln_kernel(const bf16* __restrict__ in, bf16* __restrict__ out,
               const float* __restrict__ g, const float* __restrict__ b, int nrows)
{
    int row = blockIdx.x * 4 + (threadIdx.x >> 6);
    int lane = threadIdx.x & 63;
    if (row >= nrows) return;
    const bf16* x = in + (i64)row * DM;
    float vv[8];
    ld8f(&x[lane * 8], vv);
    float s = 0.f;
#pragma unroll
    for (int j = 0; j < 8; j++) s += vv[j];
    for (int o = 32; o > 0; o >>= 1) s += __shfl_xor(s, o);
    float mu = s * (1.f / DM);
    float dd[8];
#pragma unroll
    for (int j = 0; j < 8; j++) dd[j] = vv[j] - mu;
    float vs = 0.f;
#pragma unroll
    for (int j = 0; j < 8; j++) vs += dd[j] * dd[j];
    for (int o = 32; o > 0; o >>= 1) vs += __shfl_xor(vs, o);
    float rstd = rsqrtf(vs * (1.f / DM) + 1e-5f);
    int c = lane * 8;
    bf16* y = out + (i64)row * DM;
#pragma unroll
    for (int j = 0; j < 8; j++)
        y[c + j] = __float2bfloat16(dd[j] * rstd * g[c + j] + b[c + j]);
}

// ============================ landmark means (q and k in one launch) ============================
__global__ void landmark_kernel(const bf16* __restrict__ qkv, bf16* __restrict__ q_lb,
                                bf16* __restrict__ klb)
{
    int blk = blockIdx.x;               // [0, 2*16*LMK)
    int which = blk >> 12;              // 0 = q, 1 = k
    int blk2 = blk & 4095;
    int im = blk2 & (LMK - 1);
    int bh = blk2 >> 8;
    int b = bh >> 3, h = bh & 7;
    int d = threadIdx.x;
    int off = which ? DM : 0;
    const bf16* p = qkv + (i64)(b * SEQ + im * LSUB) * Q3 + off + h * DH + d;
    float s = 0.f;
#pragma unroll 8
    for (int il = 0; il < LSUB; il++) s += cvt(p[(i64)il * Q3]);
    bf16* out = which ? klb : q_lb;
    out[((i64)bh * LMK + im) * DH + d] = __float2bfloat16(s * (1.f / LSUB));
}

// ============================ softmax rows of 256, fp32 -> bf16 ============================
__global__ __launch_bounds__(256)
void softmax256_fb_kernel(const float* __restrict__ in, bf16* __restrict__ out, i64 nrows)
{
    i64 row = (i64)blockIdx.x * 4 + (threadIdx.x >> 6);
    int lane = threadIdx.x & 63;
    if (row >= nrows) return;
    const float* p = in + row * 256;
    float4 v = *(const float4*)&p[lane * 4];
    float mx = fmaxf(fmaxf(v.x, v.y), fmaxf(v.z, v.w));
    for (int o = 32; o > 0; o >>= 1) mx = fmaxf(mx, __shfl_xor(mx, o));
    v.x = __expf(v.x - mx); v.y = __expf(v.y - mx);
    v.z = __expf(v.z - mx); v.w = __expf(v.w - mx);
    float s = v.x + v.y + v.z + v.w;
    for (int o = 32; o > 0; o >>= 1) s += __shfl_xor(s, o);
    float inv = 1.f / s;
    bf16* q = out + row * 256;
    q[lane * 4 + 0] = __float2bfloat16(v.x * inv);
    q[lane * 4 + 1] = __float2bfloat16(v.y * inv);
    q[lane * 4 + 2] = __float2bfloat16(v.z * inv);
    q[lane * 4 + 3] = __float2bfloat16(v.w * inv);
}

// ============================ softmax rows of 16384 (block per row) ============================
__global__ __launch_bounds__(256)
void softmax_big_kernel(const float* __restrict__ in, float* __restrict__ out)
{
    __shared__ float buf[SEQ];
    __shared__ float red[256];
    int t = threadIdx.x;
    const float* src = in + (i64)blockIdx.x * SEQ;
    float mx = -3.0e38f;
#pragma unroll
    for (int j = 0; j < 16; j++) {
        float4 v = *(const float4*)&src[(j * 256 + t) * 4];
        *(float4*)&buf[(j * 256 + t) * 4] = v;
        mx = fmaxf(mx, fmaxf(fmaxf(v.x, v.y), fmaxf(v.z, v.w)));
    }
    red[t] = mx; __syncthreads();
    for (int s = 128; s > 0; s >>= 1) { if (t < s) red[t] = fmaxf(red[t], red[t + s]); __syncthreads(); }
    mx = red[0];
    __syncthreads();
    float sum = 0.f;
#pragma unroll
    for (int j = 0; j < 16; j++) {
        float4 v = *(float4*)&buf[(j * 256 + t) * 4];
        v.x = __expf(v.x - mx); v.y = __expf(v.y - mx);
        v.z = __expf(v.z - mx); v.w = __expf(v.w - mx);
        *(float4*)&buf[(j * 256 + t) * 4] = v;
        sum += v.x + v.y + v.z + v.w;
    }
    red[t] = sum; __syncthreads();
    for (int s = 128; s > 0; s >>= 1) { if (t < s) red[t] += red[t + s]; __syncthreads(); }
    float inv = 1.f / red[0];
    float* dst = out + (i64)blockIdx.x * SEQ;
#pragma unroll
    for (int j = 0; j < 16; j++) {
        float4 v = *(float4*)&buf[(j * 256 + t) * 4];
        v.x *= inv; v.y *= inv; v.z *= inv; v.w *= inv;
        *(float4*)&dst[(j * 256 + t) * 4] = v;
    }
}

// ============================ pinv helpers (bf16) ============================
__global__ void pinv_sums_kernel(const bf16* __restrict__ x, float* __restrict__ scal)
{
    int bh = blockIdx.x;
    const bf16* p = x + (i64)bh * 65536;
    int t = threadIdx.x;
    float cs = 0.f, rs = 0.f;
    for (int i = 0; i < 256; i++) cs += fabsf(cvt(p[i * 256 + t]));
    for (int j = 0; j < 256; j++) rs += fabsf(cvt(p[t * 256 + j]));
    __shared__ float rc[256], rr[256];
    rc[t] = cs; rr[t] = rs; __syncthreads();
    for (int s = 128; s > 0; s >>= 1) {
        if (t < s) { rc[t] = fmaxf(rc[t], rc[t + s]); rr[t] = fmaxf(rr[t], rr[t + s]); }
        __syncthreads();
    }
    if (t == 0) {
        atomicMax(reinterpret_cast<int*>(&scal[0]), __float_as_int(rc[0]));
        atomicMax(reinterpret_cast<int*>(&scal[1]), __float_as_int(rr[0]));
    }
}

__global__ void pinv_init_kernel(const bf16* __restrict__ x, const float* __restrict__ scal,
                                 bf16* __restrict__ z, bf16* __restrict__ zT)
{
    i64 idx = (i64)blockIdx.x * 256 + threadIdx.x;
    int j = (int)(idx & 255); int i = (int)((idx >> 8) & 255); i64 bh = idx >> 16;
    float inv = 1.f / (scal[0] * scal[1]);
    float xv = cvt(x[idx]) * inv;
    zT[idx] = __float2bfloat16(xv);
    z[(bh << 16) + ((i64)j << 8) + i] = __float2bfloat16(xv);
}

// ============================ depthwise conv residual added onto xn (bf16, 8-wide vectorized) ============================
__global__ __launch_bounds__(256)
void conv_add_kernel(const bf16* __restrict__ qkv, const float* __restrict__ w,
                     bf16* __restrict__ xn)
{
    union U8 { short8 v; bf16 e[8]; };
    i64 idx = (i64)blockIdx.x * 256 + threadIdx.x;
    int cg = (int)(idx & 63);
    i64 bn = idx >> 6;
    int n = (int)(bn & (SEQ - 1));
    int b = (int)(bn >> 14);
    int c = cg * 8;
    int h = c >> 6;

    U8 xin; xin.v = *(const short8*)&xn[(bn << 9) + c];
    float acc[8];
#pragma unroll
    for (int j = 0; j < 8; j++) acc[j] = cvt(xin.e[j]);

    const float* wk = w + h * 33;
    const bf16* vb = qkv + (i64)b * SEQ * Q3 + 2 * DM + c;
    if (n >= 16 && n < SEQ - 16) {
        const bf16* vb0 = vb + (i64)(n - 16) * Q3;
#pragma unroll
        for (int t = 0; t < 33; t++) {
            U8 vv; vv.v = *(const short8*)&vb0[(i64)t * Q3];
            float wt = wk[t];
#pragma unroll
            for (int j = 0; j < 8; j++) acc[j] = fmaf(wt, cvt(vv.e[j]), acc[j]);
        }
    } else {
#pragma unroll
        for (int t = 0; t < 33; t++) {
            int nn = n + t - 16;
            if (nn >= 0 && nn < SEQ) {
                U8 vv; vv.v = *(const short8*)&vb[(i64)nn * Q3];
                float wt = wk[t];
#pragma unroll
                for (int j = 0; j < 8; j++) acc[j] = fmaf(wt, cvt(vv.e[j]), acc[j]);
            }
        }
    }
    U8 o;
#pragma unroll
    for (int j = 0; j < 8; j++) o.e[j] = __float2bfloat16(acc[j]);
    *(short8*)&xn[(bn << 9) + c] = o.v;
}

// ============================ pooling ============================
__global__ void pool_score_kernel(const float* __restrict__ t, const float* __restrict__ w,
                                  const float* __restrict__ b2, float* __restrict__ s)
{
    int row = blockIdx.x * 4 + (threadIdx.x >> 6);
    int lane = threadIdx.x & 63;
    float acc = t[(i64)row * 128 + lane] * w[lane] + t[(i64)row * 128 + 64 + lane] * w[64 + lane];
    for (int o = 32; o > 0; o >>= 1) acc += __shfl_xor(acc, o);
    if (lane == 0) s[row] = acc + b2[0];
}

__global__ __launch_bounds__(256)
void pool_z_kernel(const float* __restrict__ a, const bf16* __restrict__ h, float* __restrict__ z)
{
    int bb = blockIdx.x >> 7, cg = blockIdx.x & 127;
    int c4 = cg * 4;
    int t = threadIdx.x;
    const float* ab = a + (i64)bb * SEQ;
    const bf16* hb = h + (i64)bb * SEQ * DM;
    float4 acc = {0.f, 0.f, 0.f, 0.f};
    for (int r = t; r < SEQ; r += 256) {
        float av = ab[r];
        float4 hv = ld4(&hb[(i64)r * DM + c4]);
        acc.x += av * hv.x; acc.y += av * hv.y; acc.z += av * hv.z; acc.w += av * hv.w;
    }
    __shared__ float4 red[256];
    red[t] = acc; __syncthreads();
    for (int s = 128; s > 0; s >>= 1) {
        if (t < s) {
            float4 o = red[t + s];
            red[t].x += o.x; red[t].y += o.y; red[t].z += o.z; red[t].w += o.w;
        }
        __syncthreads();
    }
    if (t == 0) *(float4*)&z[bb * DM + c4] = red[0];
}

__global__ void head_kernel(const float* __restrict__ z, const float* __restrict__ w,
                            const float* __restrict__ b, float* __restrict__ out)
{
    int t = threadIdx.x;
    int wv = t >> 6, lane = t & 63;
    int bb = wv >> 1, cls = wv & 1;
    float acc = 0.f;
#pragma unroll
    for (int j = 0; j < 8; j++) { int k = lane * 8 + j; acc += z[bb * DM + k] * w[k * 2 + cls]; }
    for (int o = 32; o > 0; o >>= 1) acc += __shfl_xor(acc, o);
    __shared__ float lg[4];
    if (lane == 0) lg[wv] = acc + b[cls];
    __syncthreads();
    if (t == 0) {
        for (int bi = 0; bi < 2; bi++) {
            float l0 = lg[bi * 2], l1 = lg[bi * 2 + 1];
            out[bi * 2 + 0] = l0; out[bi * 2 + 1] = l1;
            float m = fmaxf(l0, l1);
            float e0 = expf(l0 - m), e1 = expf(l1 - m);
            float inv = 1.f / (e0 + e1);
            out[4 + bi * 2 + 0] = e0 * inv; out[4 + bi * 2 + 1] = e1 * inv;
        }
    }
}

// ============================ host orchestration ============================
extern "C" void kernel_launch(void* const* d_in, const int* in_sizes, int n_in,
                              void* d_out, int out_size, void* d_ws, size_t ws_size,
                              hipStream_t stream)
{
    const float* x      = (const float*)d_in[0];
    const float* fc1_w  = (const float*)d_in[1];
    const float* fc1_b  = (const float*)d_in[2];
    const float* ln1_g  = (const float*)d_in[3];
    const float* ln1_b  = (const float*)d_in[4];
    const float* qkv_w  = (const float*)d_in[5];
    const float* out_w  = (const float*)d_in[6];
    const float* out_b  = (const float*)d_in[7];
    const float* conv_w = (const float*)d_in[8];
    const float* ln2_g  = (const float*)d_in[9];
    const float* ln2_b  = (const float*)d_in[10];
    const float* ff1_w  = (const float*)d_in[11];
    const float* ff1_b  = (const float*)d_in[12];
    const float* ff2_w  = (const float*)d_in[13];
    const float* ff2_b  = (const float*)d_in[14];
    const float* att1_w = (const float*)d_in[15];
    const float* att1_b = (const float*)d_in[16];
    const float* att2_w = (const float*)d_in[17];
    const float* att2_b = (const float*)d_in[18];
    const float* fc2_w  = (const float*)d_in[19];
    const float* fc2_b  = (const float*)d_in[20];
    float* out = (float*)d_out;
    float* ws  = (float*)d_ws;

    // ---- workspace layout (float units), same region sizes as passing round-16 layout ----
    i64 off = 0;
    bf16*  h    = (bf16*)(ws + off); off += (i64)ROWS * DM;      // A: bf16 residual
    bf16*  xn   = (bf16*)(ws + off); off += (i64)ROWS * DM / 2;  // B: bf16 act / attn-out
    bf16*  qkv  = (bf16*)(ws + off); off += (i64)ROWS * Q3 / 2;  // C: bf16 qkv / xb / ffc(+D)
    float* sbuf = ws + off; off += (i64)2 * LMK * SEQ;           // D: wT / vTall / MIL scores / ffc tail
    float* attn2= ws + off; off += 16 * 65536;                   // E: attn2f -> wTf1
    float* zA   = ws + off; off += 16 * 65536;                   // F: attn2b+XZ -> zF -> wTf2
    float* zB   = ws + off; off += 16 * 65536;                   // G┐
    float* xz   = ws + off; off += 16 * 65536;                   // H│ pinv pings | attn3 obuf (bf16)
    float* wbuf = ws + off; off += 16 * 65536;                   // I│
    float* tbuf = ws + off; off += 16 * 65536;                   // J┘
    float* regK = ws + off; off += 16 * LMK * DH;                // K: q_lb + klb (bf16)
    float* regL = ws + off; off += 16 * LMK * DH;                // L: yTb + wTa (bf16)
    float* a3v  = ws + off; off += 16 * LMK * DH;                // M: a3vTb (bf16)
    float* ybuf = ws + off; off += 16 * LMK * DH;                // N: mbuf + sbuf2
    float* scor = ws + off; off += ROWS;
    float* zpool= ws + off; off += BATCH * DM;
    float* scal = ws + off; off += 16;
    if (ws_size < (size_t)off * sizeof(float)) return;

    bf16*  wT   = (bf16*)sbuf;
    bf16*  xb   = qkv;
    float* attn2f = attn2;
    bf16*  attn2b = (bf16*)zA;                 // F.0
    bf16*  XZ     = (bf16*)(zA + 524288);      // F.1
    bf16*  zG     = (bf16*)zB;
    bf16*  zGT    = (bf16*)(zB + 524288);
    bf16*  zH     = (bf16*)xz;
    bf16*  zHT    = (bf16*)(xz + 524288);
    bf16*  W1     = (bf16*)wbuf;               // I.0
    bf16*  W2     = (bf16*)(wbuf + 524288);    // I.1
    bf16*  zF     = attn2b;
    bf16*  vTall = (bf16*)sbuf;                // [2][8][64][16384] bf16 = D exactly
    bf16*  obufb = (bf16*)zB;                  // attn3 O partials bf16 [16][32][256][64] = G..J exactly
    float* mbuf  = ybuf;                       // [16*32*256] = 0.5MB
    float* sbuf2 = ybuf + 131072;              // [16*32*256] = 0.5MB (N region = 1MB exactly)
    bf16*  a3vTb = (bf16*)a3v;                 // [16][64][256] bf16
    bf16*  q_lb = (bf16*)regK;
    bf16*  klb  = (bf16*)(regK + 131072);
    bf16*  yTb  = (bf16*)regL;
    bf16*  wTa  = (bf16*)(regL + 131072);
    bf16*  wTf1 = (bf16*)attn2;
    bf16*  wTf2 = (bf16*)zA;
    bf16*  ffc  = qkv;

    const i64 sQKVb = (i64)SEQ * Q3;
    const i64 sLMh  = (i64)LMK * DH;

    // fc1 + ReLU via MFMA (h bf16)
    cvt_bf16_kernel<<<(ROWS * 1024 / 4 + 255) / 256, 256, 0, stream>>>(x, xb, (i64)ROWS * 1024);
    transpose_w_kernel<<<dim3(DM / 64, 1024 / 64), 256, 0, stream>>>(fc1_w, wT, 1024, DM);
    ml<4, 2, 1, false>(stream, xb, wT, h, fc1_b, ROWS, DM, 1024, 1024, 1024, DM);

    for (int L = 0; L < 2; L++) {
        const float* qw  = qkv_w + (i64)L * DM * Q3;
        const float* ow  = out_w + (i64)L * DM * DM;
        const float* ob  = out_b + (i64)L * DM;
        const float* cw  = conv_w + (i64)L * NHEAD * 33;
        const float* f1w = ff1_w + (i64)L * DM * FFD;
        const float* f1b = ff1_b + (i64)L * FFD;
        const float* f2w = ff2_w + (i64)L * FFD * DM;
        const float* f2b = ff2_b + (i64)L * DM;

        // LN1 -> xn (bf16); qkv = xn @ qw (MFMA)
        ln_kernel<<<ROWS/4, 256, 0, stream>>>(h, xn, ln1_g + L*DM, ln1_b + L*DM, ROWS);
        transpose_w_kernel<<<dim3(Q3 / 64, DM / 64), 256, 0, stream>>>(qw, wT, DM, Q3);
        ml<4, 2, 0, false>(stream, xn, wT, qkv, nullptr, ROWS, Q3, DM, DM, DM, Q3);

        // landmarks (q and k in one launch)
        landmark_kernel<<<2*16*LMK, 64, 0, stream>>>(qkv, q_lb, klb);

        // attn2 = softmax(0.125 * q_l @ k_l^T) via MFMA -> bf16
        ml<2, 2, 0, false>(stream, q_lb, klb, attn2f, nullptr,
            LMK, LMK, DH, DH, DH, LMK, 0, sLMh, 0, sLMh, 0, 65536, 1, 16, 0.125f);
        softmax256_fb_kernel<<<16*LMK/4, 256, 0, stream>>>(attn2f, attn2b, (i64)16*LMK);

        // pinv (Newton-Schulz, 6 iters, 4 MFMA launches/iter via dual-output epilogue)
        hipMemsetAsync(scal, 0, 2*sizeof(float), stream);
        pinv_sums_kernel<<<16, 256, 0, stream>>>(attn2b, scal);
        pinv_init_kernel<<<16*65536/256, 256, 0, stream>>>(attn2b, scal, zG, zGT);
        {
            bf16 *zp = zG, *zpT = zGT, *zq = zH, *zqT = zHT;
            for (int it = 0; it < 6; it++) {
                bool last = (it == 5);
                mlp2<2, false>(stream, XZ, W1, attn2b, zpT, 1.f, 0.f, 7.f);
                mlp2<0, true >(stream, W2, nullptr, W1, XZ, 1.f, 15.f);
                mlp2<0, true >(stream, W1, nullptr, W2, XZ, 1.f, 13.f);
                if (!last) {
                    mlp2<1, false>(stream, zq, zqT, zp, W1, 0.25f);
                    bf16* t1 = zp; zp = zq; zq = t1;
                    bf16* t2 = zpT; zpT = zqT; zqT = t2;
                } else {
                    mlp2<0, false>(stream, zF, nullptr, zp, W1, 0.25f);
                }
            }
        }
        // final pinv z at zF. D and G..J free now.

        // attn3: batched vT -> fused flash split-KV (32 chunks) -> combine (writes a3v^T bf16)
        t64_kernel<<<dim3(SEQ/64, BATCH*NHEAD), 256, 0, stream>>>(
            qkv + 2*DM, vTall, Q3, SEQ,
            sQKVb, (i64)DH, (i64)NHEAD*DH*SEQ, (i64)DH*SEQ, NHEAD);
        attn3_fused_kernel<<<dim3(32, 16), 256, 0, stream>>>(qkv, q_lb, vTall, obufb, mbuf, sbuf2);
        attn3_combine_kernel<<<16*LMK/4, 256, 0, stream>>>(obufb, mbuf, sbuf2, a3vTb);

        // yT = a3v^T @ z^T  (one MFMA launch -> yTb bf16)
        ml<2, 4, 0, false>(stream, a3vTb, zF, yTb, nullptr,
            DH, LMK, LMK, LMK, LMK, LMK, 0, (i64)DH*LMK, 0, 65536, 0, (i64)DH*LMK, 1, 16, 1.f);

        // attn1: fused QK + softmax + PV (QBLK=64), one launch -> xn
        attn1_fused_kernel<<<dim3(ROWS/64, NHEAD), 256, 0, stream>>>(qkv, klb, yTb, xn);

        // xn += depthwise conv(v); h += xn @ out_w + out_b (MFMA, bf16 resid)
        conv_add_kernel<<<(i64)ROWS*64/256, 256, 0, stream>>>(qkv, cw, xn);
        transpose_w_kernel<<<dim3(DM / 64, DM / 64), 256, 0, stream>>>(ow, wT, DM, DM);
        ml<4, 2, 0, true>(stream, xn, wT, h, ob, ROWS, DM, DM, DM, DM, DM);

        // FF block (MFMA; single pass, ffc spans C+D)
        ln_kernel<<<ROWS/4, 256, 0, stream>>>(h, xn, ln2_g + L*DM, ln2_b + L*DM, ROWS);
        transpose_w_kernel<<<dim3(FFD / 64, DM / 64), 256, 0, stream>>>(f1w, wTf1, DM, FFD);
        transpose_w_kernel<<<dim3(DM / 64, FFD / 64), 256, 0, stream>>>(f2w, wTf2, FFD, DM);
        ml<4, 2, 2, false>(stream, xn, wTf1, ffc, f1b, ROWS, FFD, DM, DM, DM, FFD);
        ml<4, 2, 0, true >(stream, ffc, wTf2, h, f2b, ROWS, DM, FFD, FFD, FFD, DM);
    }

    // gated-attention MIL pooling: tanh(h @ att1_w + b) via MFMA (h bf16)
    transpose_w_kernel<<<dim3(128 / 64, DM / 64), 256, 0, stream>>>(att1_w, wTa, DM, 128);
    ml<4, 2, 3, false>(stream, h, wTa, sbuf, att1_b, ROWS, 128, DM, DM, DM, 128);
    pool_score_kernel<<<ROWS/4, 256, 0, stream>>>(sbuf, att2_w, att2_b, scor);
    softmax_big_kernel<<<BATCH, 256, 0, stream>>>(scor, out + 8);
    pool_z_kernel<<<BATCH * 128, 256, 0, stream>>>(out + 8, h, zpool);
    head_kernel<<<1, 256, 0, stream>>>(zpool, fc2_w, fc2_b, out);
}